// Round 7
// baseline (1095.098 us; speedup 1.0000x reference)
//
#include <hip/hip_runtime.h>
#include <hip/hip_cooperative_groups.h>
#include <math.h>

namespace cg = cooperative_groups;

#define NGRID 40
#define NT    1600
#define T2    3200
#define F     128
#define NB    8
#define EPS   1e-5f

__device__ __constant__ const float kINV39 = 1.0f/39.0f;
constexpr float DXDY  = (1.0f/39.0f)*(1.0f/39.0f);
constexpr float SCALE = DXDY * 0.125f;   // DXDY / sqrt(64)

typedef __attribute__((ext_vector_type(8))) short bf16x8;
typedef __attribute__((ext_vector_type(4))) float f32x4;
typedef __attribute__((ext_vector_type(4))) unsigned uint4v;

__device__ __forceinline__ unsigned bitu(float f){ return __builtin_bit_cast(unsigned,f); }
__device__ __forceinline__ float bitf(unsigned u){ return __builtin_bit_cast(float,u); }
__device__ __forceinline__ unsigned short f2bf(float f) {
    unsigned u = bitu(f);
    unsigned r = u + 0x7FFFu + ((u >> 16) & 1u);
    return (unsigned short)(r >> 16);
}
__device__ __forceinline__ float bf2f(unsigned short h) { return bitf(((unsigned)h) << 16); }

__device__ __forceinline__ void pack_hl(float a, float b, unsigned &h, unsigned &l) {
    unsigned ua = bitu(a), ub = bitu(b);
    h = __builtin_amdgcn_perm(ub, ua, 0x07060302u);
    float ra = a - bitf(ua & 0xffff0000u);
    float rb = b - bitf(ub & 0xffff0000u);
    l = __builtin_amdgcn_perm(bitu(rb), bitu(ra), 0x07060302u);
}
__device__ __forceinline__ void store8u(short* dst, const unsigned* p) {
    uint4v v0 = {p[0], p[1], p[2], p[3]};
    uint4v v1 = {p[4], p[5], p[6], p[7]};
    *(uint4v*)dst = v0;
    *(uint4v*)(dst + 8) = v1;
}
__device__ __forceinline__ void store16u(short* dst, const unsigned* p) {
    store8u(dst, p);
    store8u(dst + 16, p + 8);
}

// =================== fused prep: uv | ln0_part | P | frag ==================
__global__ __launch_bounds__(256) void k_prep(
    const float* __restrict__ kW2, const float* __restrict__ fW2,
    short* __restrict__ Ah, short* __restrict__ Al,
    const float* __restrict__ kW1, const float* __restrict__ kb1,
    const float* __restrict__ fW1, const float* __restrict__ fb1,
    float* __restrict__ uv,
    const float* __restrict__ xy, float* __restrict__ lnpart,
    const float* __restrict__ Wq, const float* __restrict__ bq,
    const float* __restrict__ Wk, const float* __restrict__ bk,
    short* __restrict__ Pnh, short* __restrict__ Pnl,
    float* __restrict__ uB, float* __restrict__ wB, float* __restrict__ cB)
{
    __shared__ float ss[4], qs[4];
    int job = blockIdx.x;
    int tid = threadIdx.x;
    if (job < 200) {                       // ---- uv tables
        int idx = job * 256 + tid;
        int node = idx >> 5, o = idx & 31;
        float x0 = (float)(node / NGRID) * kINV39;
        float x1 = (float)(node % NGRID) * kINV39;
        uv[idx]          = fmaf(kW1[o], x0, fmaf(kW1[32+o], x1, kb1[o]));
        uv[51200 + idx]  = fmaf(kW1[64+o], x0, kW1[96+o]*x1);
        uv[102400 + idx] = fmaf(fW1[o], x0, fmaf(fW1[32+o], x1, fb1[o]));
        uv[153600 + idx] = fmaf(fW1[64+o], x0, fW1[96+o]*x1);
        return;
    }
    if (job < 400) {                       // ---- ln0 partial sums
        int t = job - 200;
        int b = t & 7, blk = t >> 3;
        const float4* p = (const float4*)xy + (size_t)b*102400 + blk*4096 + tid;
        float s = 0.f, q = 0.f;
        #pragma unroll
        for (int i = 0; i < 16; ++i) {
            float4 v = p[i*256];
            s += (v.x + v.y) + (v.z + v.w);
            q += (v.x*v.x + v.y*v.y) + (v.z*v.z + v.w*v.w);
        }
        #pragma unroll
        for (int off = 32; off >= 1; off >>= 1) {
            s += __shfl_xor(s, off);
            q += __shfl_xor(q, off);
        }
        int wid = tid >> 6;
        if ((tid & 63) == 0) { ss[wid] = s; qs[wid] = q; }
        __syncthreads();
        if (tid == 0) {
            lnpart[((size_t)b*25 + blk)*2 + 0] = ss[0]+ss[1]+ss[2]+ss[3];
            lnpart[((size_t)b*25 + blk)*2 + 1] = qs[0]+qs[1]+qs[2]+qs[3];
        }
        return;
    }
    if (job < 436) {                       // ---- P (h/l), u, w, c
        int t = job - 400;
        int j = t & 3, part = t >> 2;
        const float* wq = Wq + (size_t)j*8*F*64;
        const float* wk = Wk + (size_t)j*8*F*64;
        if (part == 8) {
            const float* bqj = bq + j*512;
            const float* bkj = bk + j*512;
            if (tid < 128) {
                int k = tid; float a = 0.f;
                for (int h = 0; h < 8; ++h)
                    for (int d = 0; d < 64; ++d)
                        a = fmaf(wq[((size_t)h*F + k)*64 + d], bkj[h*64 + d], a);
                uB[j*128 + k] = a;
            } else {
                int k = tid - 128; float a = 0.f;
                for (int h = 0; h < 8; ++h)
                    for (int d = 0; d < 64; ++d)
                        a = fmaf(wk[((size_t)h*F + k)*64 + d], bqj[h*64 + d], a);
                wB[j*128 + k] = a;
            }
            if (tid == 0) {
                float a = 0.f;
                for (int i = 0; i < 512; ++i) a = fmaf(bqj[i], bkj[i], a);
                cB[j] = a;
            }
            return;
        }
        int kp = part*16 + (tid >> 4);
        int k0 = (tid & 15) * 8;
        float acc[8] = {0,0,0,0,0,0,0,0};
        for (int h = 0; h < 8; ++h) {
            const float* wkrow = wk + ((size_t)h*F + kp)*64;
            for (int d = 0; d < 64; ++d) {
                float bv = wkrow[d];
                #pragma unroll
                for (int i = 0; i < 8; ++i)
                    acc[i] = fmaf(wq[((size_t)h*F + k0 + i)*64 + d], bv, acc[i]);
            }
        }
        #pragma unroll
        for (int i = 0; i < 8; ++i) {
            float val = acc[i];
            short hs = (short)(bitu(val) >> 16);
            float rem = val - bitf(bitu(val) & 0xffff0000u);
            short ls = (short)(bitu(rem) >> 16);
            Pnh[((size_t)j*128 + k0 + i)*128 + kp] = hs;
            Pnl[((size_t)j*128 + k0 + i)*128 + kp] = ls;
        }
        return;
    }
    {                                      // ---- MLP W2-layer fragments
        int oc = tid >> 6, lane = tid & 63;
        int row = lane & 15;
        int k0 = (lane >> 4) * 8;
        #pragma unroll
        for (int mlp = 0; mlp < 2; ++mlp) {
            const float* W2 = mlp ? fW2 : kW2;
            #pragma unroll
            for (int i = 0; i < 8; ++i) {
                float w = W2[(size_t)(k0 + i) * 64 + oc * 16 + row];
                unsigned short h = f2bf(w);
                Ah[((mlp*4 + oc)*64 + lane)*8 + i] = (short)h;
                Al[((mlp*4 + oc)*64 + lane)*8 + i] = (short)f2bf(w - bf2f(h));
            }
        }
    }
}

// ================== MFMA edge-MLP (unchanged, proven) ======================
#define MLPGRID 1536
__global__ __launch_bounds__(256, 2) void k_mlp_mfma(
    const float* __restrict__ uv,
    const float* __restrict__ kb2, const float* __restrict__ kW3,
    const float* __restrict__ kb3,
    const float* __restrict__ fb2, const float* __restrict__ fW3,
    const float* __restrict__ fb3,
    const short* __restrict__ Ah, const short* __restrict__ Al,
    short* __restrict__ W2h)
{
    int tid = threadIdx.x;
    int wid = tid >> 6, lane = tid & 63;
    int c = lane & 15, kg = lane >> 4;
    int k0 = kg * 8;

    bf16x8 AHf[2][4], ALf[2][4];
    float4 B2f[2][4], W3f[2][4];
    #pragma unroll
    for (int mlp = 0; mlp < 2; ++mlp) {
        const float* b2p = mlp ? fb2 : kb2;
        const float* w3p = mlp ? fW3 : kW3;
        #pragma unroll
        for (int oc = 0; oc < 4; ++oc) {
            AHf[mlp][oc] = *(const bf16x8*)&Ah[((mlp*4 + oc)*64 + lane)*8];
            ALf[mlp][oc] = *(const bf16x8*)&Al[((mlp*4 + oc)*64 + lane)*8];
            B2f[mlp][oc] = *(const float4*)&b2p[oc*16 + kg*4];
            W3f[mlp][oc] = *(const float4*)&w3p[oc*16 + kg*4];
        }
    }
    float bias0 = kb3[0], bias1 = fb3[0];

    int tile = blockIdx.x*4 + wid;
    int n = tile / 100;
    int mt = tile - n*100;
    while (tile < 160000) {
        int m = mt*16 + c;
        float res0, res1;
        #pragma unroll
        for (int mlp = 0; mlp < 2; ++mlp) {
            const float* up = uv + mlp*102400 + n*32 + k0;
            const float* vp = uv + mlp*102400 + 51200 + m*32 + k0;
            float4 ua = *(const float4*)up;
            float4 ub = *(const float4*)(up + 4);
            float4 va = *(const float4*)vp;
            float4 vb = *(const float4*)(vp + 4);
            float h[8] = {ua.x+va.x, ua.y+va.y, ua.z+va.z, ua.w+va.w,
                          ub.x+vb.x, ub.y+vb.y, ub.z+vb.z, ub.w+vb.w};
            #pragma unroll
            for (int i = 0; i < 8; ++i) h[i] = fmaxf(h[i], 0.01f*h[i]);
            unsigned bhp[4], blp[4];
            #pragma unroll
            for (int p = 0; p < 4; ++p)
                pack_hl(h[2*p], h[2*p+1], bhp[p], blp[p]);
            uint4v bhv = {bhp[0], bhp[1], bhp[2], bhp[3]};
            uint4v blv = {blp[0], blp[1], blp[2], blp[3]};
            bf16x8 bh = __builtin_bit_cast(bf16x8, bhv);
            bf16x8 bl = __builtin_bit_cast(bf16x8, blv);
            float acc = 0.f;
            #pragma unroll
            for (int oc = 0; oc < 4; ++oc) {
                f32x4 d = {B2f[mlp][oc].x, B2f[mlp][oc].y,
                           B2f[mlp][oc].z, B2f[mlp][oc].w};
                d = __builtin_amdgcn_mfma_f32_16x16x32_bf16(AHf[mlp][oc], bh, d, 0, 0, 0);
                d = __builtin_amdgcn_mfma_f32_16x16x32_bf16(ALf[mlp][oc], bh, d, 0, 0, 0);
                d = __builtin_amdgcn_mfma_f32_16x16x32_bf16(AHf[mlp][oc], bl, d, 0, 0, 0);
                float w3v[4] = {W3f[mlp][oc].x, W3f[mlp][oc].y,
                                W3f[mlp][oc].z, W3f[mlp][oc].w};
                #pragma unroll
                for (int r = 0; r < 4; ++r)
                    acc = fmaf(fmaxf(d[r], 0.01f*d[r]), w3v[r], acc);
            }
            if (mlp == 0) res0 = acc; else res1 = acc;
        }
        res0 += __shfl_xor(res0, 16); res0 += __shfl_xor(res0, 32);
        res1 += __shfl_xor(res1, 16); res1 += __shfl_xor(res1, 32);
        if (lane < 16) {
            W2h[(size_t)n*T2 + m]      = (short)f2bf(res0 + bias0);
            W2h[(size_t)n*T2 + NT + m] = (short)f2bf(res1 + bias1);
        }
        tile += MLPGRID*4;
        n += 61; mt += 44;
        if (mt >= 100) { mt -= 100; ++n; }
    }
}

// ====================== shared phase bodies ================================
struct SMem {
    __align__(16) char buf[61440];
    float sv[128];
};
struct GSymS  { short Sh[2][128][40], Sl[2][128][40]; };
struct GAsymS { short Ahs[128][40], Als[128][40], Bhs[128][40], Bls[128][40]; };
struct CMS    { short Psh[2][64][40], Psl[2][64][40], Bsh[2][128][40], Bsl[2][128][40]; };
struct MidS   { short Ash[2][64][40], Asl[2][64][40], Bsh[2][128][40], Bsl[2][128][40]; };
struct GOutS  { short As[2][64][40], Bh[2][128][40], Bl[2][128][40]; };

__device__ void body_apply(int job,
    const float* __restrict__ xy, const float* __restrict__ g0,
    const float* __restrict__ b0, const float* __restrict__ lnpart,
    short* __restrict__ Vbh, short* __restrict__ Vbl,
    short* __restrict__ Vbth, short* __restrict__ Vbtl,
    float* __restrict__ spartV, SMem& S)
{
    int tgrp = job % 25, b = job / 25;
    float s = 0.f, q = 0.f;
    for (int i = 0; i < 25; ++i) {
        s += lnpart[((size_t)b*25 + i)*2 + 0];
        q += lnpart[((size_t)b*25 + i)*2 + 1];
    }
    float mu = s * (1.0f/409600.0f);
    float rs = rsqrtf(q * (1.0f/409600.0f) - mu*mu + EPS);
    float (*T)[132] = (float(*)[132])S.buf;
    int tid = threadIdx.x;
    int r = tid >> 2, qd = tid & 3;
    int f2 = tid >> 1, half = tid & 1;
    #pragma unroll
    for (int p = 0; p < 2; ++p) {
        int t0 = tgrp*128 + p*64;
        {
            int t = t0 + r;
            const float* xp = xy + ((size_t)b*T2 + t)*F + qd*32;
            const float* gp = g0 + (size_t)t*F + qd*32;
            const float* bp = b0 + (size_t)t*F + qd*32;
            unsigned ph[16], pl[16];
            #pragma unroll
            for (int i = 0; i < 32; i += 4) {
                float4 x = *(const float4*)&xp[i];
                float4 g = *(const float4*)&gp[i];
                float4 bb = *(const float4*)&bp[i];
                float o0 = (x.x - mu)*rs*g.x + bb.x;
                float o1 = (x.y - mu)*rs*g.y + bb.y;
                float o2 = (x.z - mu)*rs*g.z + bb.z;
                float o3 = (x.w - mu)*rs*g.w + bb.w;
                T[r][qd*32+i] = o0; T[r][qd*32+i+1] = o1;
                T[r][qd*32+i+2] = o2; T[r][qd*32+i+3] = o3;
                pack_hl(o0, o1, ph[i>>1], pl[i>>1]);
                pack_hl(o2, o3, ph[(i>>1)+1], pl[(i>>1)+1]);
            }
            size_t ob = ((size_t)b*T2 + t)*F + qd*32;
            store16u(&Vbh[ob], ph);
            store16u(&Vbl[ob], pl);
        }
        __syncthreads();
        {
            float sacc = 0.f;
            unsigned ph[16], pl[16];
            #pragma unroll
            for (int i = 0; i < 32; i += 2) {
                float v0 = T[half*32 + i][f2];
                float v1 = T[half*32 + i + 1][f2];
                sacc += v0 + v1;
                pack_hl(v0, v1, ph[i>>1], pl[i>>1]);
            }
            size_t ob = ((size_t)b*F + f2)*T2 + t0 + half*32;
            store16u(&Vbth[ob], ph);
            store16u(&Vbtl[ob], pl);
            spartV[((size_t)b*100 + (tgrp*2+p)*2 + half)*128 + f2] = sacc;
        }
        __syncthreads();
    }
}

__device__ void body_xyt(int job,
    const float* __restrict__ xy,
    short* __restrict__ xyTh, short* __restrict__ xyTl,
    float* __restrict__ s2part, SMem& S)
{
    int tgrp = job % 25, b = job / 25;
    float (*T)[132] = (float(*)[132])S.buf;
    int tid = threadIdx.x;
    int r = tid >> 2, qd = tid & 3;
    int f2 = tid >> 1, half = tid & 1;
    int t0 = tgrp*64;
    {
        const float* xp = xy + ((size_t)b*T2 + t0 + r)*F + qd*32;
        #pragma unroll
        for (int i = 0; i < 32; i += 4)
            *(float4*)&T[r][qd*32+i] = *(const float4*)&xp[i];
    }
    __syncthreads();
    {
        float sacc = 0.f;
        unsigned ph[16], pl[16];
        #pragma unroll
        for (int i = 0; i < 32; i += 2) {
            float v0 = T[half*32 + i][f2];
            float v1 = T[half*32 + i + 1][f2];
            sacc += v0 + v1;
            pack_hl(v0, v1, ph[i>>1], pl[i>>1]);
        }
        size_t ob = ((size_t)b*F + f2)*1600 + t0 + half*32;
        store16u(&xyTh[ob], ph);
        store16u(&xyTl[ob], pl);
        s2part[((size_t)b*50 + tgrp*2 + half)*128 + f2] = sacc;
    }
}

__device__ void body_gsym(int job,
    const short* __restrict__ Xh, const short* __restrict__ Xl,
    float* __restrict__ Gpart, SMem& Smem)
{
    int split = job % 25, b = job / 25;
    int t0 = split*128;
    GSymS& S = *(GSymS*)Smem.buf;
    int tid = threadIdx.x;
    int lane = tid & 63, wid = tid >> 6;
    int wr = wid >> 1, wc = wid & 1;
    int r16 = lane & 15, kg = lane >> 4;
    int sf = tid >> 1, th = tid & 1;

    const short* ph_ = Xh + ((size_t)b*F + sf)*T2 + t0 + th*16;
    const short* pl_ = Xl + ((size_t)b*F + sf)*T2 + t0 + th*16;

    f32x4 acc[4][4];
    #pragma unroll
    for (int i = 0; i < 4; ++i)
        #pragma unroll
        for (int j2 = 0; j2 < 4; ++j2)
            acc[i][j2] = (f32x4){0.f,0.f,0.f,0.f};

    {
        uint4v h0 = *(const uint4v*)ph_,      h1 = *(const uint4v*)(ph_ + 8);
        uint4v l0 = *(const uint4v*)pl_,      l1 = *(const uint4v*)(pl_ + 8);
        *(uint4v*)&S.Sh[0][sf][th*16]     = h0; *(uint4v*)&S.Sh[0][sf][th*16+8] = h1;
        *(uint4v*)&S.Sl[0][sf][th*16]     = l0; *(uint4v*)&S.Sl[0][sf][th*16+8] = l1;
    }
    #pragma unroll
    for (int ks = 0; ks < 4; ++ks) {
        int cur = ks & 1;
        uint4v h0, h1, l0, l1;
        if (ks < 3) {
            int ko = (ks+1)*32;
            h0 = *(const uint4v*)(ph_ + ko); h1 = *(const uint4v*)(ph_ + ko + 8);
            l0 = *(const uint4v*)(pl_ + ko); l1 = *(const uint4v*)(pl_ + ko + 8);
        }
        __syncthreads();
        bf16x8 ah[4], al[4], bh[4], bl[4];
        #pragma unroll
        for (int i = 0; i < 4; ++i) {
            ah[i] = *(const bf16x8*)&S.Sh[cur][wr*64 + i*16 + r16][kg*8];
            al[i] = *(const bf16x8*)&S.Sl[cur][wr*64 + i*16 + r16][kg*8];
            bh[i] = *(const bf16x8*)&S.Sh[cur][wc*64 + i*16 + r16][kg*8];
            bl[i] = *(const bf16x8*)&S.Sl[cur][wc*64 + i*16 + r16][kg*8];
        }
        #pragma unroll
        for (int i = 0; i < 4; ++i)
            #pragma unroll
            for (int j2 = 0; j2 < 4; ++j2) {
                acc[i][j2] = __builtin_amdgcn_mfma_f32_16x16x32_bf16(ah[i], bh[j2], acc[i][j2], 0,0,0);
                acc[i][j2] = __builtin_amdgcn_mfma_f32_16x16x32_bf16(al[i], bh[j2], acc[i][j2], 0,0,0);
                acc[i][j2] = __builtin_amdgcn_mfma_f32_16x16x32_bf16(ah[i], bl[j2], acc[i][j2], 0,0,0);
            }
        if (ks < 3) {
            int nb = cur ^ 1;
            *(uint4v*)&S.Sh[nb][sf][th*16]     = h0; *(uint4v*)&S.Sh[nb][sf][th*16+8] = h1;
            *(uint4v*)&S.Sl[nb][sf][th*16]     = l0; *(uint4v*)&S.Sl[nb][sf][th*16+8] = l1;
        }
    }
    __syncthreads();
    size_t gb = ((size_t)b*25 + split)*16384;
    #pragma unroll
    for (int i = 0; i < 4; ++i)
        #pragma unroll
        for (int j2 = 0; j2 < 4; ++j2)
            #pragma unroll
            for (int reg = 0; reg < 4; ++reg)
                Gpart[gb + (size_t)(wr*64 + i*16 + kg*4 + reg)*128 + wc*64 + j2*16 + r16]
                    = acc[i][j2][reg];
}

__device__ void body_gasym(int job,
    const short* __restrict__ Ah_, const short* __restrict__ Al_,
    const short* __restrict__ Bh_, const short* __restrict__ Bl_,
    float* __restrict__ Gpart, SMem& Smem)
{
    int split = job % 25, b = job / 25;
    int t0 = split*64;
    GAsymS& S = *(GAsymS*)Smem.buf;
    int tid = threadIdx.x;
    int lane = tid & 63, wid = tid >> 6;
    int wr = wid >> 1, wc = wid & 1;
    int r16 = lane & 15, kg = lane >> 4;
    int sf = tid >> 1, th = tid & 1;

    const short* pah = Ah_ + ((size_t)b*F + sf)*1600 + t0 + th*16;
    const short* pal = Al_ + ((size_t)b*F + sf)*1600 + t0 + th*16;
    const short* pbh = Bh_ + ((size_t)b*F + sf)*T2   + t0 + th*16;
    const short* pbl = Bl_ + ((size_t)b*F + sf)*T2   + t0 + th*16;

    f32x4 acc[4][4];
    #pragma unroll
    for (int i = 0; i < 4; ++i)
        #pragma unroll
        for (int j2 = 0; j2 < 4; ++j2)
            acc[i][j2] = (f32x4){0.f,0.f,0.f,0.f};

    #pragma unroll
    for (int ks = 0; ks < 2; ++ks) {
        int ko = ks*32;
        __syncthreads();
        *(uint4v*)&S.Ahs[sf][th*16]   = *(const uint4v*)(pah + ko);
        *(uint4v*)&S.Ahs[sf][th*16+8] = *(const uint4v*)(pah + ko + 8);
        *(uint4v*)&S.Als[sf][th*16]   = *(const uint4v*)(pal + ko);
        *(uint4v*)&S.Als[sf][th*16+8] = *(const uint4v*)(pal + ko + 8);
        *(uint4v*)&S.Bhs[sf][th*16]   = *(const uint4v*)(pbh + ko);
        *(uint4v*)&S.Bhs[sf][th*16+8] = *(const uint4v*)(pbh + ko + 8);
        *(uint4v*)&S.Bls[sf][th*16]   = *(const uint4v*)(pbl + ko);
        *(uint4v*)&S.Bls[sf][th*16+8] = *(const uint4v*)(pbl + ko + 8);
        __syncthreads();
        bf16x8 ah[4], al[4], bh[4], bl[4];
        #pragma unroll
        for (int i = 0; i < 4; ++i) {
            ah[i] = *(const bf16x8*)&S.Ahs[wr*64 + i*16 + r16][kg*8];
            al[i] = *(const bf16x8*)&S.Als[wr*64 + i*16 + r16][kg*8];
            bh[i] = *(const bf16x8*)&S.Bhs[wc*64 + i*16 + r16][kg*8];
            bl[i] = *(const bf16x8*)&S.Bls[wc*64 + i*16 + r16][kg*8];
        }
        #pragma unroll
        for (int i = 0; i < 4; ++i)
            #pragma unroll
            for (int j2 = 0; j2 < 4; ++j2) {
                acc[i][j2] = __builtin_amdgcn_mfma_f32_16x16x32_bf16(ah[i], bh[j2], acc[i][j2], 0,0,0);
                acc[i][j2] = __builtin_amdgcn_mfma_f32_16x16x32_bf16(al[i], bh[j2], acc[i][j2], 0,0,0);
                acc[i][j2] = __builtin_amdgcn_mfma_f32_16x16x32_bf16(ah[i], bl[j2], acc[i][j2], 0,0,0);
            }
    }
    __syncthreads();
    size_t gb = ((size_t)b*25 + split)*16384;
    #pragma unroll
    for (int i = 0; i < 4; ++i)
        #pragma unroll
        for (int j2 = 0; j2 < 4; ++j2)
            #pragma unroll
            for (int reg = 0; reg < 4; ++reg)
                Gpart[gb + (size_t)(wr*64 + i*16 + kg*4 + reg)*128 + wc*64 + j2*16 + r16]
                    = acc[i][j2][reg];
}

__device__ void body_gred(int job,
    const float* __restrict__ Gpart, const float* __restrict__ wj,
    short* __restrict__ Gbh, short* __restrict__ Gbl, float* __restrict__ rpart)
{
    int part = job % 8, b = job / 8;
    int tid = threadIdx.x;
    int e0 = part*2048 + tid*8;
    float a[8] = {0,0,0,0,0,0,0,0};
    for (int i = 0; i < 25; ++i) {
        const float* p = Gpart + ((size_t)b*25 + i)*16384 + e0;
        float4 x0 = *(const float4*)p;
        float4 x1 = *(const float4*)(p + 4);
        a[0] += x0.x; a[1] += x0.y; a[2] += x0.z; a[3] += x0.w;
        a[4] += x1.x; a[5] += x1.y; a[6] += x1.z; a[7] += x1.w;
    }
    unsigned ph[4], pl[4];
    #pragma unroll
    for (int i = 0; i < 8; i += 2) pack_hl(a[i], a[i+1], ph[i>>1], pl[i>>1]);
    uint4v vh = {ph[0],ph[1],ph[2],ph[3]};
    uint4v vl = {pl[0],pl[1],pl[2],pl[3]};
    *(uint4v*)&Gbh[(size_t)b*16384 + e0] = vh;
    *(uint4v*)&Gbl[(size_t)b*16384 + e0] = vl;

    int c0 = e0 & 127;
    float4 w0 = *(const float4*)&wj[c0];
    float4 w1 = *(const float4*)&wj[c0 + 4];
    float pr = a[0]*w0.x + a[1]*w0.y + a[2]*w0.z + a[3]*w0.w
             + a[4]*w1.x + a[5]*w1.y + a[6]*w1.z + a[7]*w1.w;
    pr += __shfl_xor(pr, 1); pr += __shfl_xor(pr, 2);
    pr += __shfl_xor(pr, 4); pr += __shfl_xor(pr, 8);
    if ((tid & 15) == 0) rpart[b*128 + (e0 >> 7)] = pr;
}

__device__ void body_computeM(int job,
    const short* __restrict__ Gbh, const short* __restrict__ Gbl,
    const float* __restrict__ spart, int np,
    const short* __restrict__ Pjh, const short* __restrict__ Pjl,
    const float* __restrict__ uj, const float* __restrict__ cj,
    const float* __restrict__ rpart,
    short* __restrict__ Mth, short* __restrict__ Mtl, float* __restrict__ rm,
    SMem& Smem)
{
    int kh = job % 2, b = job / 2;
    CMS& S = *(CMS*)Smem.buf;
    float (*T)[132] = (float(*)[132])Smem.buf;
    float* sv = Smem.sv;

    int tid = threadIdx.x;
    int lane = tid & 63, wid = tid >> 6;
    int wr = wid >> 1, wc = wid & 1;
    int r16 = lane & 15, kg = lane >> 4;
    int st = tid >> 2, sq = tid & 3;
    int sf = tid >> 1, sh2 = tid & 1;

    if (tid < 128) {
        float s = 0.f;
        for (int i = 0; i < np; ++i) s += spart[((size_t)b*np + i)*128 + tid];
        sv[tid] = s;
        if (kh == 0) rm[b*128 + tid] = SCALE*(rpart[b*128 + tid] + cj[0]*s);
    }

    const short* pah = Pjh + (size_t)(kh*64 + st)*128 + sq*8;
    const short* pal = Pjl + (size_t)(kh*64 + st)*128 + sq*8;
    const short* pbh = Gbh + ((size_t)b*F + sf)*128 + sh2*16;
    const short* pbl = Gbl + ((size_t)b*F + sf)*128 + sh2*16;

    f32x4 acc[2][4];
    #pragma unroll
    for (int i = 0; i < 2; ++i)
        #pragma unroll
        for (int j2 = 0; j2 < 4; ++j2)
            acc[i][j2] = (f32x4){0.f,0.f,0.f,0.f};

    {
        *(uint4v*)&S.Psh[0][st][sq*8]      = *(const uint4v*)pah;
        *(uint4v*)&S.Psl[0][st][sq*8]      = *(const uint4v*)pal;
        *(uint4v*)&S.Bsh[0][sf][sh2*16]    = *(const uint4v*)pbh;
        *(uint4v*)&S.Bsh[0][sf][sh2*16+8]  = *(const uint4v*)(pbh + 8);
        *(uint4v*)&S.Bsl[0][sf][sh2*16]    = *(const uint4v*)pbl;
        *(uint4v*)&S.Bsl[0][sf][sh2*16+8]  = *(const uint4v*)(pbl + 8);
    }
    #pragma unroll
    for (int ks = 0; ks < 4; ++ks) {
        int cur = ks & 1;
        uint4v a0, a1, b0, b1, b2, b3;
        if (ks < 3) {
            int ko = (ks+1)*32;
            a0 = *(const uint4v*)(pah + ko); a1 = *(const uint4v*)(pal + ko);
            b0 = *(const uint4v*)(pbh + ko); b1 = *(const uint4v*)(pbh + ko + 8);
            b2 = *(const uint4v*)(pbl + ko); b3 = *(const uint4v*)(pbl + ko + 8);
        }
        __syncthreads();
        bf16x8 ah[2], al[2], bh[4], bl[4];
        #pragma unroll
        for (int i = 0; i < 2; ++i) {
            ah[i] = *(const bf16x8*)&S.Psh[cur][wr*32 + i*16 + r16][kg*8];
            al[i] = *(const bf16x8*)&S.Psl[cur][wr*32 + i*16 + r16][kg*8];
        }
        #pragma unroll
        for (int j2 = 0; j2 < 4; ++j2) {
            bh[j2] = *(const bf16x8*)&S.Bsh[cur][wc*64 + j2*16 + r16][kg*8];
            bl[j2] = *(const bf16x8*)&S.Bsl[cur][wc*64 + j2*16 + r16][kg*8];
        }
        #pragma unroll
        for (int i = 0; i < 2; ++i)
            #pragma unroll
            for (int j2 = 0; j2 < 4; ++j2) {
                acc[i][j2] = __builtin_amdgcn_mfma_f32_16x16x32_bf16(ah[i], bh[j2], acc[i][j2], 0,0,0);
                acc[i][j2] = __builtin_amdgcn_mfma_f32_16x16x32_bf16(al[i], bh[j2], acc[i][j2], 0,0,0);
                acc[i][j2] = __builtin_amdgcn_mfma_f32_16x16x32_bf16(ah[i], bl[j2], acc[i][j2], 0,0,0);
            }
        if (ks < 3) {
            int nb = cur ^ 1;
            *(uint4v*)&S.Psh[nb][st][sq*8]     = a0;
            *(uint4v*)&S.Psl[nb][st][sq*8]     = a1;
            *(uint4v*)&S.Bsh[nb][sf][sh2*16]   = b0;
            *(uint4v*)&S.Bsh[nb][sf][sh2*16+8] = b1;
            *(uint4v*)&S.Bsl[nb][sf][sh2*16]   = b2;
            *(uint4v*)&S.Bsl[nb][sf][sh2*16+8] = b3;
        }
    }
    float uval[2][4], svv[4];
    #pragma unroll
    for (int i = 0; i < 2; ++i)
        #pragma unroll
        for (int reg = 0; reg < 4; ++reg)
            uval[i][reg] = uj[kh*64 + wr*32 + i*16 + kg*4 + reg];
    #pragma unroll
    for (int j2 = 0; j2 < 4; ++j2) svv[j2] = sv[wc*64 + j2*16 + r16];
    __syncthreads();
    #pragma unroll
    for (int i = 0; i < 2; ++i)
        #pragma unroll
        for (int j2 = 0; j2 < 4; ++j2)
            #pragma unroll
            for (int reg = 0; reg < 4; ++reg)
                T[wr*32 + i*16 + kg*4 + reg][wc*64 + j2*16 + r16]
                    = SCALE*(acc[i][j2][reg] + uval[i][reg]*svv[j2]);
    __syncthreads();
    {
        int f2 = tid >> 1, half = tid & 1;
        unsigned ph[16], pl[16];
        #pragma unroll
        for (int i = 0; i < 32; i += 2) {
            float v0 = T[half*32 + i][f2];
            float v1 = T[half*32 + i + 1][f2];
            pack_hl(v0, v1, ph[i>>1], pl[i>>1]);
        }
        size_t ob = ((size_t)b*F + f2)*F + kh*64 + half*32;
        store16u(&Mth[ob], ph);
        store16u(&Mtl[ob], pl);
    }
}

__device__ void body_mid(int job,
    short* __restrict__ Vbh, short* __restrict__ Vbl,
    const short* __restrict__ Mth, const short* __restrict__ Mtl,
    const float* __restrict__ rm,
    const float* __restrict__ glj, const float* __restrict__ blj, int doLN,
    short* __restrict__ OTh, short* __restrict__ OTl,
    float* __restrict__ spartN, SMem& Smem)
{
    int tblk = job % 50, b = job / 50;
    int t0 = tblk * 64;
    MidS& S = *(MidS*)Smem.buf;
    float (*T)[132] = (float(*)[132])Smem.buf;

    int tid = threadIdx.x;
    int lane = tid & 63, wid = tid >> 6;
    int wr = wid >> 1, wc = wid & 1;
    int r16 = lane & 15, kg = lane >> 4;
    int st = tid >> 2, sq = tid & 3;
    int sf = tid >> 1, sh2 = tid & 1;

    const short* pah = Vbh + ((size_t)b*T2 + t0 + st)*F + sq*8;
    const short* pal = Vbl + ((size_t)b*T2 + t0 + st)*F + sq*8;
    const short* pbh = Mth + ((size_t)b*F + sf)*F + sh2*16;
    const short* pbl = Mtl + ((size_t)b*F + sf)*F + sh2*16;

    f32x4 acc[2][4];
    #pragma unroll
    for (int i = 0; i < 2; ++i)
        #pragma unroll
        for (int j2 = 0; j2 < 4; ++j2)
            acc[i][j2] = (f32x4){0.f,0.f,0.f,0.f};

    {
        *(uint4v*)&S.Ash[0][st][sq*8]      = *(const uint4v*)pah;
        *(uint4v*)&S.Asl[0][st][sq*8]      = *(const uint4v*)pal;
        *(uint4v*)&S.Bsh[0][sf][sh2*16]    = *(const uint4v*)pbh;
        *(uint4v*)&S.Bsh[0][sf][sh2*16+8]  = *(const uint4v*)(pbh + 8);
        *(uint4v*)&S.Bsl[0][sf][sh2*16]    = *(const uint4v*)pbl;
        *(uint4v*)&S.Bsl[0][sf][sh2*16+8]  = *(const uint4v*)(pbl + 8);
    }
    #pragma unroll
    for (int ks = 0; ks < 4; ++ks) {
        int cur = ks & 1;
        uint4v a0, a1, b0, b1, b2, b3;
        if (ks < 3) {
            int ko = (ks+1)*32;
            a0 = *(const uint4v*)(pah + ko); a1 = *(const uint4v*)(pal + ko);
            b0 = *(const uint4v*)(pbh + ko); b1 = *(const uint4v*)(pbh + ko + 8);
            b2 = *(const uint4v*)(pbl + ko); b3 = *(const uint4v*)(pbl + ko + 8);
        }
        __syncthreads();
        bf16x8 ah[2], al[2], bh[4], bl[4];
        #pragma unroll
        for (int i = 0; i < 2; ++i) {
            ah[i] = *(const bf16x8*)&S.Ash[cur][wr*32 + i*16 + r16][kg*8];
            al[i] = *(const bf16x8*)&S.Asl[cur][wr*32 + i*16 + r16][kg*8];
        }
        #pragma unroll
        for (int j2 = 0; j2 < 4; ++j2) {
            bh[j2] = *(const bf16x8*)&S.Bsh[cur][wc*64 + j2*16 + r16][kg*8];
            bl[j2] = *(const bf16x8*)&S.Bsl[cur][wc*64 + j2*16 + r16][kg*8];
        }
        #pragma unroll
        for (int i = 0; i < 2; ++i)
            #pragma unroll
            for (int j2 = 0; j2 < 4; ++j2) {
                acc[i][j2] = __builtin_amdgcn_mfma_f32_16x16x32_bf16(ah[i], bh[j2], acc[i][j2], 0,0,0);
                acc[i][j2] = __builtin_amdgcn_mfma_f32_16x16x32_bf16(al[i], bh[j2], acc[i][j2], 0,0,0);
                acc[i][j2] = __builtin_amdgcn_mfma_f32_16x16x32_bf16(ah[i], bl[j2], acc[i][j2], 0,0,0);
            }
        if (ks < 3) {
            int nb = cur ^ 1;
            *(uint4v*)&S.Ash[nb][st][sq*8]     = a0;
            *(uint4v*)&S.Asl[nb][st][sq*8]     = a1;
            *(uint4v*)&S.Bsh[nb][sf][sh2*16]   = b0;
            *(uint4v*)&S.Bsh[nb][sf][sh2*16+8] = b1;
            *(uint4v*)&S.Bsl[nb][sf][sh2*16]   = b2;
            *(uint4v*)&S.Bsl[nb][sf][sh2*16+8] = b3;
        }
    }
    float rv[4];
    #pragma unroll
    for (int j2 = 0; j2 < 4; ++j2) rv[j2] = rm[b*F + wc*64 + j2*16 + r16];
    __syncthreads();
    #pragma unroll
    for (int i = 0; i < 2; ++i)
        #pragma unroll
        for (int j2 = 0; j2 < 4; ++j2)
            #pragma unroll
            for (int reg = 0; reg < 4; ++reg)
                T[wr*32 + i*16 + kg*4 + reg][wc*64 + j2*16 + r16]
                    = acc[i][j2][reg] + rv[j2];
    __syncthreads();

    if (doLN) {
        int r = tid >> 2, qd = tid & 3;
        float v[32];
        #pragma unroll
        for (int i = 0; i < 32; i += 4)
            *(float4*)&v[i] = *(const float4*)&T[r][qd*32 + i];
        float s = 0.f;
        #pragma unroll
        for (int i = 0; i < 32; ++i) s += v[i];
        s += __shfl_xor(s, 1); s += __shfl_xor(s, 2);
        float mu = s * (1.0f/128.0f);
        float dv = 0.f;
        #pragma unroll
        for (int i = 0; i < 32; ++i) { float d = v[i] - mu; dv = fmaf(d, d, dv); }
        dv += __shfl_xor(dv, 1); dv += __shfl_xor(dv, 2);
        float rs = rsqrtf(dv * (1.0f/128.0f) + EPS);

        short hb[32], lb[32];
        {
            const short* rh = Vbh + ((size_t)b*T2 + t0 + r)*F + qd*32;
            const short* rl = Vbl + ((size_t)b*T2 + t0 + r)*F + qd*32;
            #pragma unroll
            for (int i = 0; i < 32; i += 8) {
                *(uint4v*)&hb[i] = *(const uint4v*)(rh + i);
                *(uint4v*)&lb[i] = *(const uint4v*)(rl + i);
            }
        }
        float gv[32], bv2[32];
        #pragma unroll
        for (int i = 0; i < 32; i += 4) {
            *(float4*)&gv[i]  = *(const float4*)&glj[qd*32 + i];
            *(float4*)&bv2[i] = *(const float4*)&blj[qd*32 + i];
        }
        unsigned ph[16], pl[16];
        #pragma unroll
        for (int i = 0; i < 32; i += 2) {
            float res0 = bf2f((unsigned short)hb[i])   + bf2f((unsigned short)lb[i]);
            float res1 = bf2f((unsigned short)hb[i+1]) + bf2f((unsigned short)lb[i+1]);
            float o0 = (v[i]   - mu)*rs*gv[i]   + bv2[i]   + res0;
            float o1 = (v[i+1] - mu)*rs*gv[i+1] + bv2[i+1] + res1;
            T[r][qd*32+i] = o0; T[r][qd*32+i+1] = o1;
            pack_hl(o0, o1, ph[i>>1], pl[i>>1]);
        }
        size_t ob = ((size_t)b*T2 + t0 + r)*F + qd*32;
        store16u(&Vbh[ob], ph);
        store16u(&Vbl[ob], pl);
        __syncthreads();
    }
    {
        int f2 = tid >> 1, half = tid & 1;
        float sacc = 0.f;
        unsigned ph[16], pl[16];
        #pragma unroll
        for (int i = 0; i < 32; i += 2) {
            float v0 = T[half*32 + i][f2];
            float v1 = T[half*32 + i + 1][f2];
            sacc += v0 + v1;
            pack_hl(v0, v1, ph[i>>1], pl[i>>1]);
        }
        size_t ob = ((size_t)b*F + f2)*T2 + t0 + half*32;
        store16u(&OTh[ob], ph);
        store16u(&OTl[ob], pl);
        if (doLN)
            spartN[((size_t)b*100 + tblk*2 + half)*128 + f2] = sacc;
    }
}

__device__ void body_gout(int job,
    const short* __restrict__ W2h,
    const short* __restrict__ Uth, const short* __restrict__ Utl,
    float* __restrict__ out, SMem& Smem)
{
    int nt = job % 25, b = job / 25;
    int n0 = nt * 64;
    GOutS& S = *(GOutS*)Smem.buf;

    int tid = threadIdx.x;
    int lane = tid & 63, wid = tid >> 6;
    int wr = wid >> 1, wc = wid & 1;
    int r16 = lane & 15, kg = lane >> 4;
    int srow = tid >> 2, sq2 = tid & 3;
    int sf = tid >> 1, sh2 = tid & 1;

    const short* ap  = W2h + (size_t)(n0 + srow)*T2 + sq2*8;
    const short* bhp = Uth + ((size_t)b*F + sf)*T2 + sh2*16;
    const short* blp = Utl + ((size_t)b*F + sf)*T2 + sh2*16;

    f32x4 acc[2][4];
    #pragma unroll
    for (int i = 0; i < 2; ++i)
        #pragma unroll
        for (int j2 = 0; j2 < 4; ++j2)
            acc[i][j2] = (f32x4){0.f,0.f,0.f,0.f};

    {
        *(uint4v*)&S.As[0][srow][sq2*8]  = *(const uint4v*)ap;
        *(uint4v*)&S.Bh[0][sf][sh2*16]   = *(const uint4v*)bhp;
        *(uint4v*)&S.Bh[0][sf][sh2*16+8] = *(const uint4v*)(bhp + 8);
        *(uint4v*)&S.Bl[0][sf][sh2*16]   = *(const uint4v*)blp;
        *(uint4v*)&S.Bl[0][sf][sh2*16+8] = *(const uint4v*)(blp + 8);
    }
    for (int it = 0; it < 100; ++it) {
        int cur = it & 1;
        uint4v ra, b0, b1, b2, b3;
        if (it < 99) {
            int ko = (it + 1) * 32;
            ra = *(const uint4v*)(ap + ko);
            b0 = *(const uint4v*)(bhp + ko); b1 = *(const uint4v*)(bhp + ko + 8);
            b2 = *(const uint4v*)(blp + ko); b3 = *(const uint4v*)(blp + ko + 8);
        }
        __syncthreads();
        bf16x8 ah[2], bh[4], bl[4];
        #pragma unroll
        for (int i = 0; i < 2; ++i)
            ah[i] = *(const bf16x8*)&S.As[cur][wr*32 + i*16 + r16][kg*8];
        #pragma unroll
        for (int j2 = 0; j2 < 4; ++j2) {
            bh[j2] = *(const bf16x8*)&S.Bh[cur][wc*64 + j2*16 + r16][kg*8];
            bl[j2] = *(const bf16x8*)&S.Bl[cur][wc*64 + j2*16 + r16][kg*8];
        }
        #pragma unroll
        for (int i = 0; i < 2; ++i)
            #pragma unroll
            for (int j2 = 0; j2 < 4; ++j2) {
                acc[i][j2] = __builtin_amdgcn_mfma_f32_16x16x32_bf16(ah[i], bh[j2], acc[i][j2], 0,0,0);
                acc[i][j2] = __builtin_amdgcn_mfma_f32_16x16x32_bf16(ah[i], bl[j2], acc[i][j2], 0,0,0);
            }
        if (it < 99) {
            int nb = cur ^ 1;
            *(uint4v*)&S.As[nb][srow][sq2*8]  = ra;
            *(uint4v*)&S.Bh[nb][sf][sh2*16]   = b0;
            *(uint4v*)&S.Bh[nb][sf][sh2*16+8] = b1;
            *(uint4v*)&S.Bl[nb][sf][sh2*16]   = b2;
            *(uint4v*)&S.Bl[nb][sf][sh2*16+8] = b3;
        }
    }
    __syncthreads();
    #pragma unroll
    for (int i = 0; i < 2; ++i)
        #pragma unroll
        for (int j2 = 0; j2 < 4; ++j2)
            #pragma unroll
            for (int reg = 0; reg < 4; ++reg) {
                int n_out = n0 + wr*32 + i*16 + kg*4 + reg;
                int f_out = wc*64 + j2*16 + r16;
                out[((size_t)b*NT + n_out)*F + f_out] = DXDY * acc[i][j2][reg];
            }
}

// ====================== cooperative mega-kernel (grid 256) =================
__global__ __launch_bounds__(256) void k_coop(
    const float* xy, const float* g0, const float* b0,
    const float* gl, const float* bl, const float* lnpart,
    short* Vbh, short* Vbl, short* Vbth, short* Vbtl,
    short* xyTh, short* xyTl, short* Uth, short* Utl,
    float* spartV, float* s2part, float* Gpart,
    short* Gbh, short* Gbl, float* rpart, float* rm,
    short* Mth, short* Mtl, const short* Pnh, const short* Pnl,
    const float* uB, const float* wB, const float* cB,
    const short* W2h, float* out)
{
    __shared__ SMem S;
    cg::grid_group grid = cg::this_grid();
    int bid = blockIdx.x;

    // phase 0: LN0 apply (dual-layout V) + xy transpose  (400 jobs)
    for (int j2 = bid; j2 < 400; j2 += 256) {
        if (j2 < 200) body_apply(j2, xy, g0, b0, lnpart, Vbh, Vbl, Vbth, Vbtl, spartV, S);
        else          body_xyt(j2 - 200, xy, xyTh, xyTl, s2part, S);
        __syncthreads();
    }
    grid.sync();

    for (int j = 0; j < 4; ++j) {
        if (bid < 200) {
            if (j < 3) body_gsym(bid, Vbth, Vbtl, Gpart, S);
            else       body_gasym(bid, xyTh, xyTl, Vbth, Vbtl, Gpart, S);
        }
        grid.sync();
        if (bid < 64) body_gred(bid, Gpart, wB + j*128, Gbh, Gbl, rpart);
        grid.sync();
        if (bid < 16) body_computeM(bid, Gbh, Gbl,
                                    (j < 3) ? spartV : s2part, (j < 3) ? 100 : 50,
                                    Pnh + (size_t)j*16384, Pnl + (size_t)j*16384,
                                    uB + j*128, cB + j, rpart, Mth, Mtl, rm, S);
        grid.sync();
        for (int j2 = bid; j2 < 400; j2 += 256) {
            if (j < 3) body_mid(j2, Vbh, Vbl, Mth, Mtl, rm, gl + j*128, bl + j*128, 1,
                                Vbth, Vbtl, spartV, S);
            else       body_mid(j2, Vbh, Vbl, Mth, Mtl, rm, gl, bl, 0,
                                Uth, Utl, spartV, S);
            __syncthreads();
        }
        grid.sync();
    }
    if (bid < 200) body_gout(bid, W2h, Uth, Utl, out, S);
}

// ====================== fallback standalone wrappers =======================
__global__ __launch_bounds__(256) void k_apply_w(
    const float* xy, const float* g0, const float* b0, const float* lnpart,
    short* Vbh, short* Vbl, short* Vbth, short* Vbtl,
    short* xyTh, short* xyTl, float* spartV, float* s2part)
{
    __shared__ SMem S;
    int jb = blockIdx.x;
    if (jb < 200) body_apply(jb, xy, g0, b0, lnpart, Vbh, Vbl, Vbth, Vbtl, spartV, S);
    else          body_xyt(jb - 200, xy, xyTh, xyTl, s2part, S);
}
__global__ __launch_bounds__(256) void k_gsym_w(
    const short* Xh, const short* Xl, float* Gpart)
{
    __shared__ SMem S;
    body_gsym(blockIdx.x, Xh, Xl, Gpart, S);
}
__global__ __launch_bounds__(256) void k_gasym_w(
    const short* Ah_, const short* Al_, const short* Bh_, const short* Bl_,
    float* Gpart)
{
    __shared__ SMem S;
    body_gasym(blockIdx.x, Ah_, Al_, Bh_, Bl_, Gpart, S);
}
__global__ __launch_bounds__(256) void k_gred_w(
    const float* Gpart, const float* wj, short* Gbh, short* Gbl, float* rpart)
{
    body_gred(blockIdx.x, Gpart, wj, Gbh, Gbl, rpart);
}
__global__ __launch_bounds__(256) void k_cm_w(
    const short* Gbh, const short* Gbl, const float* spart, int np,
    const short* Pjh, const short* Pjl, const float* uj, const float* cj,
    const float* rpart, short* Mth, short* Mtl, float* rm)
{
    __shared__ SMem S;
    body_computeM(blockIdx.x, Gbh, Gbl, spart, np, Pjh, Pjl, uj, cj, rpart,
                  Mth, Mtl, rm, S);
}
__global__ __launch_bounds__(256) void k_mid_w(
    short* Vbh, short* Vbl, const short* Mth, const short* Mtl,
    const float* rm, const float* glj, const float* blj, int doLN,
    short* OTh, short* OTl, float* spartN)
{
    __shared__ SMem S;
    body_mid(blockIdx.x, Vbh, Vbl, Mth, Mtl, rm, glj, blj, doLN, OTh, OTl,
             spartN, S);
}
__global__ __launch_bounds__(256) void k_gout_w(
    const short* W2h, const short* Uth, const short* Utl, float* out)
{
    __shared__ SMem S;
    body_gout(blockIdx.x, W2h, Uth, Utl, out, S);
}

// =============================== launcher ==================================
extern "C" void kernel_launch(void* const* d_in, const int* in_sizes, int n_in,
                              void* d_out, int out_size, void* d_ws, size_t ws_size,
                              hipStream_t stream)
{
    const float* xy  = (const float*)d_in[0];
    const float* kW1 = (const float*)d_in[1];
    const float* kb1 = (const float*)d_in[2];
    const float* kW2 = (const float*)d_in[3];
    const float* kb2 = (const float*)d_in[4];
    const float* kW3 = (const float*)d_in[5];
    const float* kb3 = (const float*)d_in[6];
    const float* fW1 = (const float*)d_in[7];
    const float* fb1 = (const float*)d_in[8];
    const float* fW2 = (const float*)d_in[9];
    const float* fb2 = (const float*)d_in[10];
    const float* fW3 = (const float*)d_in[11];
    const float* fb3 = (const float*)d_in[12];
    const float* Wq  = (const float*)d_in[13];
    const float* bq  = (const float*)d_in[14];
    const float* Wk  = (const float*)d_in[15];
    const float* bk  = (const float*)d_in[16];
    const float* g0  = (const float*)d_in[17];
    const float* b0  = (const float*)d_in[18];
    const float* gl  = (const float*)d_in[19];
    const float* bl  = (const float*)d_in[20];
    float* out = (float*)d_out;

    short* W2h  = (short*)d_ws;                 // 5,120,000
    short* Vbh  = W2h  + 5120000;               // 3,276,800
    short* Vbl  = Vbh  + 3276800;
    short* Vbth = Vbl  + 3276800;
    short* Vbtl = Vbth + 3276800;
    short* xyTh = Vbtl + 3276800;               // 1,638,400
    short* xyTl = xyTh + 1638400;
    short* Uth  = xyTl + 1638400;               // 3,276,800
    short* Utl  = Uth  + 3276800;
    short* Pnh  = Utl  + 3276800;               // 65,536
    short* Pnl  = Pnh  + 65536;
    short* Mth  = Pnl  + 65536;                 // 131,072
    short* Mtl  = Mth  + 131072;
    short* Gbh  = Mtl  + 131072;                // 131,072
    short* Gbl  = Gbh  + 131072;
    short* AhF  = Gbl  + 131072;                // 4,096
    short* AlF  = AhF  + 4096;
    float* Gpart  = (float*)(AlF + 4096);       // 3,276,800 f
    float* uB     = Gpart + 3276800;            // 512
    float* wB     = uB + 512;                   // 512
    float* cB     = wB + 512;                   // 4
    float* lnpart = cB + 4;                     // 400
    float* rpart  = lnpart + 400;               // 1024
    float* rm     = rpart + 1024;               // 1024
    float* spartV = rm + 1024;                  // 102,400
    float* s2part = spartV + 102400;            // 51,200
    float* uvT    = s2part + 51200;             // 204,800

    k_prep<<<dim3(437), 256, 0, stream>>>(kW2, fW2, AhF, AlF,
                                          kW1, kb1, fW1, fb1, uvT,
                                          xy, lnpart,
                                          Wq, bq, Wk, bk, Pnh, Pnl, uB, wB, cB);

    k_mlp_mfma<<<dim3(MLPGRID), 256, 0, stream>>>(uvT, kb2, kW3, kb3,
                                                  fb2, fW3, fb3, AhF, AlF, W2h);

    void* kp[] = {
        (void*)&xy, (void*)&g0, (void*)&b0, (void*)&gl, (void*)&bl,
        (void*)&lnpart,
        (void*)&Vbh, (void*)&Vbl, (void*)&Vbth, (void*)&Vbtl,
        (void*)&xyTh, (void*)&xyTl, (void*)&Uth, (void*)&Utl,
        (void*)&spartV, (void*)&s2part, (void*)&Gpart,
        (void*)&Gbh, (void*)&Gbl, (void*)&rpart, (void*)&rm,
        (void*)&Mth, (void*)&Mtl, (void*)&Pnh, (void*)&Pnl,
        (void*)&uB, (void*)&wB, (void*)&cB,
        (void*)&W2h, (void*)&out
    };
    hipError_t ce = hipLaunchCooperativeKernel((const void*)k_coop, dim3(256),
                                               dim3(256), kp, 0, stream);
    if (ce != hipSuccess) {
        // deterministic fallback: round-5 proven dispatch sequence
        k_apply_w<<<dim3(400), 256, 0, stream>>>(xy, g0, b0, lnpart,
                                                 Vbh, Vbl, Vbth, Vbtl,
                                                 xyTh, xyTl, spartV, s2part);
        for (int j = 0; j < 4; ++j) {
            if (j < 3)
                k_gsym_w<<<dim3(200), 256, 0, stream>>>(Vbth, Vbtl, Gpart);
            else
                k_gasym_w<<<dim3(200), 256, 0, stream>>>(xyTh, xyTl, Vbth, Vbtl, Gpart);
            k_gred_w<<<dim3(64), 256, 0, stream>>>(Gpart, wB + j*128, Gbh, Gbl, rpart);
            k_cm_w<<<dim3(16), 256, 0, stream>>>(
                Gbh, Gbl,
                (j < 3) ? spartV : s2part, (j < 3) ? 100 : 50,
                Pnh + (size_t)j*16384, Pnl + (size_t)j*16384,
                uB + j*128, cB + j, rpart, Mth, Mtl, rm);
            if (j < 3)
                k_mid_w<<<dim3(400), 256, 0, stream>>>(Vbh, Vbl, Mth, Mtl, rm,
                                                       gl + j*128, bl + j*128, 1,
                                                       Vbth, Vbtl, spartV);
            else
                k_mid_w<<<dim3(400), 256, 0, stream>>>(Vbh, Vbl, Mth, Mtl, rm,
                                                       gl, bl, 0,
                                                       Uth, Utl, spartV);
        }
        k_gout_w<<<dim3(200), 256, 0, stream>>>(W2h, Uth, Utl, out);
    }
}

// Round 8
// 660.673 us; speedup vs baseline: 1.6575x; 1.6575x over previous
//
#include <hip/hip_runtime.h>
#include <math.h>

#define NGRID 40
#define NT    1600
#define T2    3200
#define F     128
#define NB    8
#define EPS   1e-5f

__device__ __constant__ const float kINV39 = 1.0f/39.0f;
constexpr float DXDY  = (1.0f/39.0f)*(1.0f/39.0f);
constexpr float SCALE = DXDY * 0.125f;   // DXDY / sqrt(64)

typedef __attribute__((ext_vector_type(8))) short bf16x8;
typedef __attribute__((ext_vector_type(4))) float f32x4;
typedef __attribute__((ext_vector_type(4))) unsigned uint4v;

__device__ __forceinline__ unsigned bitu(float f){ return __builtin_bit_cast(unsigned,f); }
__device__ __forceinline__ float bitf(unsigned u){ return __builtin_bit_cast(float,u); }
__device__ __forceinline__ unsigned short f2bf(float f) {
    unsigned u = bitu(f);
    unsigned r = u + 0x7FFFu + ((u >> 16) & 1u);
    return (unsigned short)(r >> 16);
}
__device__ __forceinline__ float bf2f(unsigned short h) { return bitf(((unsigned)h) << 16); }

__device__ __forceinline__ void pack_hl(float a, float b, unsigned &h, unsigned &l) {
    unsigned ua = bitu(a), ub = bitu(b);
    h = __builtin_amdgcn_perm(ub, ua, 0x07060302u);
    float ra = a - bitf(ua & 0xffff0000u);
    float rb = b - bitf(ub & 0xffff0000u);
    l = __builtin_amdgcn_perm(bitu(rb), bitu(ra), 0x07060302u);
}
__device__ __forceinline__ void store8u(short* dst, const unsigned* p) {
    uint4v v0 = {p[0], p[1], p[2], p[3]};
    uint4v v1 = {p[4], p[5], p[6], p[7]};
    *(uint4v*)dst = v0;
    *(uint4v*)(dst + 8) = v1;
}
__device__ __forceinline__ void store16u(short* dst, const unsigned* p) {
    store8u(dst, p);
    store8u(dst + 16, p + 8);
}

// shared-memory union: 61440B buffer + sv
struct SMem {
    __align__(16) char buf[61440];
    float sv[128];
};
struct GSymS  { short Sh[2][128][40], Sl[2][128][40]; };                 // 60KB... 40960B
struct GAs2S  { short Ahs[128][40], Als[128][40], Bhs[128][40], Bls[128][40]; }; // 40960
struct CMS2   { short Gsh[2][128][40], Gsl[2][128][40], Psh[2][64][40], Psl[2][64][40]; }; // 61440
struct MidS   { short Ash[2][64][40], Asl[2][64][40], Bsh[2][128][40], Bsl[2][128][40]; }; // 61440
struct GOutS  { short As[2][64][40], Bh[2][128][40], Bl[2][128][40]; };  // 51200

// =================== fused prep: uv | ln0_part | P | frag ==================
__global__ __launch_bounds__(256) void k_prep(
    const float* __restrict__ kW2, const float* __restrict__ fW2,
    short* __restrict__ Ah, short* __restrict__ Al,
    const float* __restrict__ kW1, const float* __restrict__ kb1,
    const float* __restrict__ fW1, const float* __restrict__ fb1,
    float* __restrict__ uv,
    const float* __restrict__ xy, float* __restrict__ lnpart,
    const float* __restrict__ Wq, const float* __restrict__ bq,
    const float* __restrict__ Wk, const float* __restrict__ bk,
    short* __restrict__ Pnh, short* __restrict__ Pnl,
    float* __restrict__ uB, float* __restrict__ wB, float* __restrict__ cB)
{
    __shared__ float ss[4], qs[4];
    int job = blockIdx.x;
    int tid = threadIdx.x;
    if (job < 200) {
        int idx = job * 256 + tid;
        int node = idx >> 5, o = idx & 31;
        float x0 = (float)(node / NGRID) * kINV39;
        float x1 = (float)(node % NGRID) * kINV39;
        uv[idx]          = fmaf(kW1[o], x0, fmaf(kW1[32+o], x1, kb1[o]));
        uv[51200 + idx]  = fmaf(kW1[64+o], x0, kW1[96+o]*x1);
        uv[102400 + idx] = fmaf(fW1[o], x0, fmaf(fW1[32+o], x1, fb1[o]));
        uv[153600 + idx] = fmaf(fW1[64+o], x0, fW1[96+o]*x1);
        return;
    }
    if (job < 400) {
        int t = job - 200;
        int b = t & 7, blk = t >> 3;
        const float4* p = (const float4*)xy + (size_t)b*102400 + blk*4096 + tid;
        float s = 0.f, q = 0.f;
        #pragma unroll
        for (int i = 0; i < 16; ++i) {
            float4 v = p[i*256];
            s += (v.x + v.y) + (v.z + v.w);
            q += (v.x*v.x + v.y*v.y) + (v.z*v.z + v.w*v.w);
        }
        #pragma unroll
        for (int off = 32; off >= 1; off >>= 1) {
            s += __shfl_xor(s, off);
            q += __shfl_xor(q, off);
        }
        int wid = tid >> 6;
        if ((tid & 63) == 0) { ss[wid] = s; qs[wid] = q; }
        __syncthreads();
        if (tid == 0) {
            lnpart[((size_t)b*25 + blk)*2 + 0] = ss[0]+ss[1]+ss[2]+ss[3];
            lnpart[((size_t)b*25 + blk)*2 + 1] = qs[0]+qs[1]+qs[2]+qs[3];
        }
        return;
    }
    if (job < 436) {
        int t = job - 400;
        int j = t & 3, part = t >> 2;
        const float* wq = Wq + (size_t)j*8*F*64;
        const float* wk = Wk + (size_t)j*8*F*64;
        if (part == 8) {
            const float* bqj = bq + j*512;
            const float* bkj = bk + j*512;
            if (tid < 128) {
                int k = tid; float a = 0.f;
                for (int h = 0; h < 8; ++h)
                    for (int d = 0; d < 64; ++d)
                        a = fmaf(wq[((size_t)h*F + k)*64 + d], bkj[h*64 + d], a);
                uB[j*128 + k] = a;
            } else {
                int k = tid - 128; float a = 0.f;
                for (int h = 0; h < 8; ++h)
                    for (int d = 0; d < 64; ++d)
                        a = fmaf(wk[((size_t)h*F + k)*64 + d], bqj[h*64 + d], a);
                wB[j*128 + k] = a;
            }
            if (tid == 0) {
                float a = 0.f;
                for (int i = 0; i < 512; ++i) a = fmaf(bqj[i], bkj[i], a);
                cB[j] = a;
            }
            return;
        }
        int kp = part*16 + (tid >> 4);
        int k0 = (tid & 15) * 8;
        float acc[8] = {0,0,0,0,0,0,0,0};
        for (int h = 0; h < 8; ++h) {
            const float* wkrow = wk + ((size_t)h*F + kp)*64;
            for (int d = 0; d < 64; ++d) {
                float bv = wkrow[d];
                #pragma unroll
                for (int i = 0; i < 8; ++i)
                    acc[i] = fmaf(wq[((size_t)h*F + k0 + i)*64 + d], bv, acc[i]);
            }
        }
        #pragma unroll
        for (int i = 0; i < 8; ++i) {
            float val = acc[i];
            short hs = (short)(bitu(val) >> 16);
            float rem = val - bitf(bitu(val) & 0xffff0000u);
            short ls = (short)(bitu(rem) >> 16);
            Pnh[((size_t)j*128 + k0 + i)*128 + kp] = hs;
            Pnl[((size_t)j*128 + k0 + i)*128 + kp] = ls;
        }
        return;
    }
    {
        int oc = tid >> 6, lane = tid & 63;
        int row = lane & 15;
        int k0 = (lane >> 4) * 8;
        #pragma unroll
        for (int mlp = 0; mlp < 2; ++mlp) {
            const float* W2 = mlp ? fW2 : kW2;
            #pragma unroll
            for (int i = 0; i < 8; ++i) {
                float w = W2[(size_t)(k0 + i) * 64 + oc * 16 + row];
                unsigned short h = f2bf(w);
                Ah[((mlp*4 + oc)*64 + lane)*8 + i] = (short)h;
                Al[((mlp*4 + oc)*64 + lane)*8 + i] = (short)f2bf(w - bf2f(h));
            }
        }
    }
}

// ============ MFMA edge-MLP: block owns n, wave owns 25 m-tiles ============
__global__ __launch_bounds__(256, 2) void k_mlp_mfma(
    const float* __restrict__ uv,
    const float* __restrict__ kb2, const float* __restrict__ kW3,
    const float* __restrict__ kb3,
    const float* __restrict__ fb2, const float* __restrict__ fW3,
    const float* __restrict__ fb3,
    const short* __restrict__ Ah, const short* __restrict__ Al,
    short* __restrict__ W2h)
{
    int tid = threadIdx.x;
    int wid = tid >> 6, lane = tid & 63;
    int c = lane & 15, kg = lane >> 4;
    int k0 = kg * 8;
    int n = blockIdx.x;                // 0..1599

    bf16x8 AHf[2][4], ALf[2][4];
    float4 B2f[2][4], W3f[2][4];
    float4 uA[2][2];
    #pragma unroll
    for (int mlp = 0; mlp < 2; ++mlp) {
        const float* b2p = mlp ? fb2 : kb2;
        const float* w3p = mlp ? fW3 : kW3;
        #pragma unroll
        for (int oc = 0; oc < 4; ++oc) {
            AHf[mlp][oc] = *(const bf16x8*)&Ah[((mlp*4 + oc)*64 + lane)*8];
            ALf[mlp][oc] = *(const bf16x8*)&Al[((mlp*4 + oc)*64 + lane)*8];
            B2f[mlp][oc] = *(const float4*)&b2p[oc*16 + kg*4];
            W3f[mlp][oc] = *(const float4*)&w3p[oc*16 + kg*4];
        }
        const float* up = uv + mlp*102400 + n*32 + k0;
        uA[mlp][0] = *(const float4*)up;
        uA[mlp][1] = *(const float4*)(up + 4);
    }
    float bias0 = kb3[0], bias1 = fb3[0];

    for (int mt = wid*25; mt < wid*25 + 25; ++mt) {
        int m = mt*16 + c;
        float res0, res1;
        #pragma unroll
        for (int mlp = 0; mlp < 2; ++mlp) {
            const float* vp = uv + mlp*102400 + 51200 + m*32 + k0;
            float4 va = *(const float4*)vp;
            float4 vb = *(const float4*)(vp + 4);
            float4 ua = uA[mlp][0], ub = uA[mlp][1];
            float h[8] = {ua.x+va.x, ua.y+va.y, ua.z+va.z, ua.w+va.w,
                          ub.x+vb.x, ub.y+vb.y, ub.z+vb.z, ub.w+vb.w};
            #pragma unroll
            for (int i = 0; i < 8; ++i) h[i] = fmaxf(h[i], 0.01f*h[i]);
            unsigned bhp[4], blp[4];
            #pragma unroll
            for (int p = 0; p < 4; ++p)
                pack_hl(h[2*p], h[2*p+1], bhp[p], blp[p]);
            uint4v bhv = {bhp[0], bhp[1], bhp[2], bhp[3]};
            uint4v blv = {blp[0], blp[1], blp[2], blp[3]};
            bf16x8 bh = __builtin_bit_cast(bf16x8, bhv);
            bf16x8 bl = __builtin_bit_cast(bf16x8, blv);
            float acc = 0.f;
            #pragma unroll
            for (int oc = 0; oc < 4; ++oc) {
                f32x4 d = {B2f[mlp][oc].x, B2f[mlp][oc].y,
                           B2f[mlp][oc].z, B2f[mlp][oc].w};
                d = __builtin_amdgcn_mfma_f32_16x16x32_bf16(AHf[mlp][oc], bh, d, 0, 0, 0);
                d = __builtin_amdgcn_mfma_f32_16x16x32_bf16(ALf[mlp][oc], bh, d, 0, 0, 0);
                d = __builtin_amdgcn_mfma_f32_16x16x32_bf16(AHf[mlp][oc], bl, d, 0, 0, 0);
                float w3v[4] = {W3f[mlp][oc].x, W3f[mlp][oc].y,
                                W3f[mlp][oc].z, W3f[mlp][oc].w};
                #pragma unroll
                for (int r = 0; r < 4; ++r)
                    acc = fmaf(fmaxf(d[r], 0.01f*d[r]), w3v[r], acc);
            }
            if (mlp == 0) res0 = acc; else res1 = acc;
        }
        res0 += __shfl_xor(res0, 16); res0 += __shfl_xor(res0, 32);
        res1 += __shfl_xor(res1, 16); res1 += __shfl_xor(res1, 32);
        if (lane < 16) {
            W2h[(size_t)n*T2 + m]      = (short)f2bf(res0 + bias0);
            W2h[(size_t)n*T2 + NT + m] = (short)f2bf(res1 + bias1);
        }
    }
}

// ====================== phase bodies (verified numerics) ====================
__device__ void body_apply(int tgrp, int b,
    const float* __restrict__ xy, const float* __restrict__ g0,
    const float* __restrict__ b0, const float* __restrict__ lnpart,
    short* __restrict__ Vbh, short* __restrict__ Vbl,
    short* __restrict__ Vbth, short* __restrict__ Vbtl,
    float* __restrict__ spartV, SMem& S)
{
    float s = 0.f, q = 0.f;
    for (int i = 0; i < 25; ++i) {
        s += lnpart[((size_t)b*25 + i)*2 + 0];
        q += lnpart[((size_t)b*25 + i)*2 + 1];
    }
    float mu = s * (1.0f/409600.0f);
    float rs = rsqrtf(q * (1.0f/409600.0f) - mu*mu + EPS);
    float (*T)[132] = (float(*)[132])S.buf;
    int tid = threadIdx.x;
    int r = tid >> 2, qd = tid & 3;
    int f2 = tid >> 1, half = tid & 1;
    #pragma unroll
    for (int p = 0; p < 2; ++p) {
        int t0 = tgrp*128 + p*64;
        {
            int t = t0 + r;
            const float* xp = xy + ((size_t)b*T2 + t)*F + qd*32;
            const float* gp = g0 + (size_t)t*F + qd*32;
            const float* bp = b0 + (size_t)t*F + qd*32;
            unsigned ph[16], pl[16];
            #pragma unroll
            for (int i = 0; i < 32; i += 4) {
                float4 x = *(const float4*)&xp[i];
                float4 g = *(const float4*)&gp[i];
                float4 bb = *(const float4*)&bp[i];
                float o0 = (x.x - mu)*rs*g.x + bb.x;
                float o1 = (x.y - mu)*rs*g.y + bb.y;
                float o2 = (x.z - mu)*rs*g.z + bb.z;
                float o3 = (x.w - mu)*rs*g.w + bb.w;
                T[r][qd*32+i] = o0; T[r][qd*32+i+1] = o1;
                T[r][qd*32+i+2] = o2; T[r][qd*32+i+3] = o3;
                pack_hl(o0, o1, ph[i>>1], pl[i>>1]);
                pack_hl(o2, o3, ph[(i>>1)+1], pl[(i>>1)+1]);
            }
            size_t ob = ((size_t)b*T2 + t)*F + qd*32;
            store16u(&Vbh[ob], ph);
            store16u(&Vbl[ob], pl);
        }
        __syncthreads();
        {
            float sacc = 0.f;
            unsigned ph[16], pl[16];
            #pragma unroll
            for (int i = 0; i < 32; i += 2) {
                float v0 = T[half*32 + i][f2];
                float v1 = T[half*32 + i + 1][f2];
                sacc += v0 + v1;
                pack_hl(v0, v1, ph[i>>1], pl[i>>1]);
            }
            size_t ob = ((size_t)b*F + f2)*T2 + t0 + half*32;
            store16u(&Vbth[ob], ph);
            store16u(&Vbtl[ob], pl);
            spartV[((size_t)b*100 + (tgrp*2+p)*2 + half)*128 + f2] = sacc;
        }
        __syncthreads();
    }
}

__device__ void body_xyt(int tgrp, int b,
    const float* __restrict__ xy,
    short* __restrict__ xyTh, short* __restrict__ xyTl,
    float* __restrict__ s2part, SMem& S)
{
    float (*T)[132] = (float(*)[132])S.buf;
    int tid = threadIdx.x;
    int r = tid >> 2, qd = tid & 3;
    int f2 = tid >> 1, half = tid & 1;
    int t0 = tgrp*64;
    {
        const float* xp = xy + ((size_t)b*T2 + t0 + r)*F + qd*32;
        #pragma unroll
        for (int i = 0; i < 32; i += 4)
            *(float4*)&T[r][qd*32+i] = *(const float4*)&xp[i];
    }
    __syncthreads();
    {
        float sacc = 0.f;
        unsigned ph[16], pl[16];
        #pragma unroll
        for (int i = 0; i < 32; i += 2) {
            float v0 = T[half*32 + i][f2];
            float v1 = T[half*32 + i + 1][f2];
            sacc += v0 + v1;
            pack_hl(v0, v1, ph[i>>1], pl[i>>1]);
        }
        size_t ob = ((size_t)b*F + f2)*1600 + t0 + half*32;
        store16u(&xyTh[ob], ph);
        store16u(&xyTl[ob], pl);
        s2part[((size_t)b*50 + tgrp*2 + half)*128 + f2] = sacc;
    }
}

__device__ void body_gsym(int split, int b,
    const short* __restrict__ Xh, const short* __restrict__ Xl,
    float* __restrict__ Gpart, SMem& Smem)
{
    int t0 = split*128;
    GSymS& S = *(GSymS*)Smem.buf;
    int tid = threadIdx.x;
    int lane = tid & 63, wid = tid >> 6;
    int wr = wid >> 1, wc = wid & 1;
    int r16 = lane & 15, kg = lane >> 4;
    int sf = tid >> 1, th = tid & 1;

    const short* ph_ = Xh + ((size_t)b*F + sf)*T2 + t0 + th*16;
    const short* pl_ = Xl + ((size_t)b*F + sf)*T2 + t0 + th*16;

    f32x4 acc[4][4];
    #pragma unroll
    for (int i = 0; i < 4; ++i)
        #pragma unroll
        for (int j2 = 0; j2 < 4; ++j2)
            acc[i][j2] = (f32x4){0.f,0.f,0.f,0.f};

    {
        uint4v h0 = *(const uint4v*)ph_,      h1 = *(const uint4v*)(ph_ + 8);
        uint4v l0 = *(const uint4v*)pl_,      l1 = *(const uint4v*)(pl_ + 8);
        *(uint4v*)&S.Sh[0][sf][th*16]     = h0; *(uint4v*)&S.Sh[0][sf][th*16+8] = h1;
        *(uint4v*)&S.Sl[0][sf][th*16]     = l0; *(uint4v*)&S.Sl[0][sf][th*16+8] = l1;
    }
    #pragma unroll
    for (int ks = 0; ks < 4; ++ks) {
        int cur = ks & 1;
        uint4v h0, h1, l0, l1;
        if (ks < 3) {
            int ko = (ks+1)*32;
            h0 = *(const uint4v*)(ph_ + ko); h1 = *(const uint4v*)(ph_ + ko + 8);
            l0 = *(const uint4v*)(pl_ + ko); l1 = *(const uint4v*)(pl_ + ko + 8);
        }
        __syncthreads();
        bf16x8 ah[4], al[4], bh[4], bl[4];
        #pragma unroll
        for (int i = 0; i < 4; ++i) {
            ah[i] = *(const bf16x8*)&S.Sh[cur][wr*64 + i*16 + r16][kg*8];
            al[i] = *(const bf16x8*)&S.Sl[cur][wr*64 + i*16 + r16][kg*8];
            bh[i] = *(const bf16x8*)&S.Sh[cur][wc*64 + i*16 + r16][kg*8];
            bl[i] = *(const bf16x8*)&S.Sl[cur][wc*64 + i*16 + r16][kg*8];
        }
        #pragma unroll
        for (int i = 0; i < 4; ++i)
            #pragma unroll
            for (int j2 = 0; j2 < 4; ++j2) {
                acc[i][j2] = __builtin_amdgcn_mfma_f32_16x16x32_bf16(ah[i], bh[j2], acc[i][j2], 0,0,0);
                acc[i][j2] = __builtin_amdgcn_mfma_f32_16x16x32_bf16(al[i], bh[j2], acc[i][j2], 0,0,0);
                acc[i][j2] = __builtin_amdgcn_mfma_f32_16x16x32_bf16(ah[i], bl[j2], acc[i][j2], 0,0,0);
            }
        if (ks < 3) {
            int nb = cur ^ 1;
            *(uint4v*)&S.Sh[nb][sf][th*16]     = h0; *(uint4v*)&S.Sh[nb][sf][th*16+8] = h1;
            *(uint4v*)&S.Sl[nb][sf][th*16]     = l0; *(uint4v*)&S.Sl[nb][sf][th*16+8] = l1;
        }
    }
    __syncthreads();
    size_t gb = ((size_t)b*25 + split)*16384;
    #pragma unroll
    for (int i = 0; i < 4; ++i)
        #pragma unroll
        for (int j2 = 0; j2 < 4; ++j2)
            #pragma unroll
            for (int reg = 0; reg < 4; ++reg)
                Gpart[gb + (size_t)(wr*64 + i*16 + kg*4 + reg)*128 + wc*64 + j2*16 + r16]
                    = acc[i][j2][reg];
}

// G2^T partials over up-to-128 t rows (nks ksteps of 32), single-buffered
__device__ void body_gasym2(int split, int b, int nks,
    const short* __restrict__ Ah_, const short* __restrict__ Al_,
    const short* __restrict__ Bh_, const short* __restrict__ Bl_,
    float* __restrict__ Gpart, SMem& Smem)
{
    int t0 = split*128;
    GAs2S& S = *(GAs2S*)Smem.buf;
    int tid = threadIdx.x;
    int lane = tid & 63, wid = tid >> 6;
    int wr = wid >> 1, wc = wid & 1;
    int r16 = lane & 15, kg = lane >> 4;
    int sf = tid >> 1, th = tid & 1;

    const short* pah = Ah_ + ((size_t)b*F + sf)*1600 + t0 + th*16;
    const short* pal = Al_ + ((size_t)b*F + sf)*1600 + t0 + th*16;
    const short* pbh = Bh_ + ((size_t)b*F + sf)*T2   + t0 + th*16;
    const short* pbl = Bl_ + ((size_t)b*F + sf)*T2   + t0 + th*16;

    f32x4 acc[4][4];
    #pragma unroll
    for (int i = 0; i < 4; ++i)
        #pragma unroll
        for (int j2 = 0; j2 < 4; ++j2)
            acc[i][j2] = (f32x4){0.f,0.f,0.f,0.f};

    for (int ks = 0; ks < nks; ++ks) {
        int ko = ks*32;
        __syncthreads();
        *(uint4v*)&S.Ahs[sf][th*16]   = *(const uint4v*)(pah + ko);
        *(uint4v*)&S.Ahs[sf][th*16+8] = *(const uint4v*)(pah + ko + 8);
        *(uint4v*)&S.Als[sf][th*16]   = *(const uint4v*)(pal + ko);
        *(uint4v*)&S.Als[sf][th*16+8] = *(const uint4v*)(pal + ko + 8);
        *(uint4v*)&S.Bhs[sf][th*16]   = *(const uint4v*)(pbh + ko);
        *(uint4v*)&S.Bhs[sf][th*16+8] = *(const uint4v*)(pbh + ko + 8);
        *(uint4v*)&S.Bls[sf][th*16]   = *(const uint4v*)(pbl + ko);
        *(uint4v*)&S.Bls[sf][th*16+8] = *(const uint4v*)(pbl + ko + 8);
        __syncthreads();
        bf16x8 ah[4], al[4], bh[4], bl[4];
        #pragma unroll
        for (int i = 0; i < 4; ++i) {
            ah[i] = *(const bf16x8*)&S.Ahs[wr*64 + i*16 + r16][kg*8];
            al[i] = *(const bf16x8*)&S.Als[wr*64 + i*16 + r16][kg*8];
            bh[i] = *(const bf16x8*)&S.Bhs[wc*64 + i*16 + r16][kg*8];
            bl[i] = *(const bf16x8*)&S.Bls[wc*64 + i*16 + r16][kg*8];
        }
        #pragma unroll
        for (int i = 0; i < 4; ++i)
            #pragma unroll
            for (int j2 = 0; j2 < 4; ++j2) {
                acc[i][j2] = __builtin_amdgcn_mfma_f32_16x16x32_bf16(ah[i], bh[j2], acc[i][j2], 0,0,0);
                acc[i][j2] = __builtin_amdgcn_mfma_f32_16x16x32_bf16(al[i], bh[j2], acc[i][j2], 0,0,0);
                acc[i][j2] = __builtin_amdgcn_mfma_f32_16x16x32_bf16(ah[i], bl[j2], acc[i][j2], 0,0,0);
            }
    }
    __syncthreads();
    size_t gb = ((size_t)b*25 + split)*16384;
    #pragma unroll
    for (int i = 0; i < 4; ++i)
        #pragma unroll
        for (int j2 = 0; j2 < 4; ++j2)
            #pragma unroll
            for (int reg = 0; reg < 4; ++reg)
                Gpart[gb + (size_t)(wr*64 + i*16 + kg*4 + reg)*128 + wc*64 + j2*16 + r16]
                    = acc[i][j2][reg];
}

__device__ void body_mid(int tblk, int b,
    short* __restrict__ Vbh, short* __restrict__ Vbl,
    const short* __restrict__ Mth, const short* __restrict__ Mtl,
    const float* __restrict__ rm,
    const float* __restrict__ glj, const float* __restrict__ blj, int doLN,
    short* __restrict__ OTh, short* __restrict__ OTl,
    float* __restrict__ spartN, SMem& Smem)
{
    int t0 = tblk * 64;
    MidS& S = *(MidS*)Smem.buf;
    float (*T)[132] = (float(*)[132])Smem.buf;

    int tid = threadIdx.x;
    int lane = tid & 63, wid = tid >> 6;
    int wr = wid >> 1, wc = wid & 1;
    int r16 = lane & 15, kg = lane >> 4;
    int st = tid >> 2, sq = tid & 3;
    int sf = tid >> 1, sh2 = tid & 1;

    const short* pah = Vbh + ((size_t)b*T2 + t0 + st)*F + sq*8;
    const short* pal = Vbl + ((size_t)b*T2 + t0 + st)*F + sq*8;
    const short* pbh = Mth + ((size_t)b*F + sf)*F + sh2*16;
    const short* pbl = Mtl + ((size_t)b*F + sf)*F + sh2*16;

    f32x4 acc[2][4];
    #pragma unroll
    for (int i = 0; i < 2; ++i)
        #pragma unroll
        for (int j2 = 0; j2 < 4; ++j2)
            acc[i][j2] = (f32x4){0.f,0.f,0.f,0.f};

    {
        *(uint4v*)&S.Ash[0][st][sq*8]      = *(const uint4v*)pah;
        *(uint4v*)&S.Asl[0][st][sq*8]      = *(const uint4v*)pal;
        *(uint4v*)&S.Bsh[0][sf][sh2*16]    = *(const uint4v*)pbh;
        *(uint4v*)&S.Bsh[0][sf][sh2*16+8]  = *(const uint4v*)(pbh + 8);
        *(uint4v*)&S.Bsl[0][sf][sh2*16]    = *(const uint4v*)pbl;
        *(uint4v*)&S.Bsl[0][sf][sh2*16+8]  = *(const uint4v*)(pbl + 8);
    }
    #pragma unroll
    for (int ks = 0; ks < 4; ++ks) {
        int cur = ks & 1;
        uint4v a0, a1, b0, b1, b2, b3;
        if (ks < 3) {
            int ko = (ks+1)*32;
            a0 = *(const uint4v*)(pah + ko); a1 = *(const uint4v*)(pal + ko);
            b0 = *(const uint4v*)(pbh + ko); b1 = *(const uint4v*)(pbh + ko + 8);
            b2 = *(const uint4v*)(pbl + ko); b3 = *(const uint4v*)(pbl + ko + 8);
        }
        __syncthreads();
        bf16x8 ah[2], al[2], bh[4], bl[4];
        #pragma unroll
        for (int i = 0; i < 2; ++i) {
            ah[i] = *(const bf16x8*)&S.Ash[cur][wr*32 + i*16 + r16][kg*8];
            al[i] = *(const bf16x8*)&S.Asl[cur][wr*32 + i*16 + r16][kg*8];
        }
        #pragma unroll
        for (int j2 = 0; j2 < 4; ++j2) {
            bh[j2] = *(const bf16x8*)&S.Bsh[cur][wc*64 + j2*16 + r16][kg*8];
            bl[j2] = *(const bf16x8*)&S.Bsl[cur][wc*64 + j2*16 + r16][kg*8];
        }
        #pragma unroll
        for (int i = 0; i < 2; ++i)
            #pragma unroll
            for (int j2 = 0; j2 < 4; ++j2) {
                acc[i][j2] = __builtin_amdgcn_mfma_f32_16x16x32_bf16(ah[i], bh[j2], acc[i][j2], 0,0,0);
                acc[i][j2] = __builtin_amdgcn_mfma_f32_16x16x32_bf16(al[i], bh[j2], acc[i][j2], 0,0,0);
                acc[i][j2] = __builtin_amdgcn_mfma_f32_16x16x32_bf16(ah[i], bl[j2], acc[i][j2], 0,0,0);
            }
        if (ks < 3) {
            int nb = cur ^ 1;
            *(uint4v*)&S.Ash[nb][st][sq*8]     = a0;
            *(uint4v*)&S.Asl[nb][st][sq*8]     = a1;
            *(uint4v*)&S.Bsh[nb][sf][sh2*16]   = b0;
            *(uint4v*)&S.Bsh[nb][sf][sh2*16+8] = b1;
            *(uint4v*)&S.Bsl[nb][sf][sh2*16]   = b2;
            *(uint4v*)&S.Bsl[nb][sf][sh2*16+8] = b3;
        }
    }
    float rv[4];
    #pragma unroll
    for (int j2 = 0; j2 < 4; ++j2) rv[j2] = rm[b*F + wc*64 + j2*16 + r16];
    __syncthreads();
    #pragma unroll
    for (int i = 0; i < 2; ++i)
        #pragma unroll
        for (int j2 = 0; j2 < 4; ++j2)
            #pragma unroll
            for (int reg = 0; reg < 4; ++reg)
                T[wr*32 + i*16 + kg*4 + reg][wc*64 + j2*16 + r16]
                    = acc[i][j2][reg] + rv[j2];
    __syncthreads();

    if (doLN) {
        int r = tid >> 2, qd = tid & 3;
        float v[32];
        #pragma unroll
        for (int i = 0; i < 32; i += 4)
            *(float4*)&v[i] = *(const float4*)&T[r][qd*32 + i];
        float s = 0.f;
        #pragma unroll
        for (int i = 0; i < 32; ++i) s += v[i];
        s += __shfl_xor(s, 1); s += __shfl_xor(s, 2);
        float mu = s * (1.0f/128.0f);
        float dv = 0.f;
        #pragma unroll
        for (int i = 0; i < 32; ++i) { float d = v[i] - mu; dv = fmaf(d, d, dv); }
        dv += __shfl_xor(dv, 1); dv += __shfl_xor(dv, 2);
        float rs = rsqrtf(dv * (1.0f/128.0f) + EPS);

        short hb[32], lb[32];
        {
            const short* rh = Vbh + ((size_t)b*T2 + t0 + r)*F + qd*32;
            const short* rl = Vbl + ((size_t)b*T2 + t0 + r)*F + qd*32;
            #pragma unroll
            for (int i = 0; i < 32; i += 8) {
                *(uint4v*)&hb[i] = *(const uint4v*)(rh + i);
                *(uint4v*)&lb[i] = *(const uint4v*)(rl + i);
            }
        }
        float gv[32], bv2[32];
        #pragma unroll
        for (int i = 0; i < 32; i += 4) {
            *(float4*)&gv[i]  = *(const float4*)&glj[qd*32 + i];
            *(float4*)&bv2[i] = *(const float4*)&blj[qd*32 + i];
        }
        unsigned ph[16], pl[16];
        #pragma unroll
        for (int i = 0; i < 32; i += 2) {
            float res0 = bf2f((unsigned short)hb[i])   + bf2f((unsigned short)lb[i]);
            float res1 = bf2f((unsigned short)hb[i+1]) + bf2f((unsigned short)lb[i+1]);
            float o0 = (v[i]   - mu)*rs*gv[i]   + bv2[i]   + res0;
            float o1 = (v[i+1] - mu)*rs*gv[i+1] + bv2[i+1] + res1;
            T[r][qd*32+i] = o0; T[r][qd*32+i+1] = o1;
            pack_hl(o0, o1, ph[i>>1], pl[i>>1]);
        }
        size_t ob = ((size_t)b*T2 + t0 + r)*F + qd*32;
        store16u(&Vbh[ob], ph);
        store16u(&Vbl[ob], pl);
        __syncthreads();
    }
    {
        int f2 = tid >> 1, half = tid & 1;
        float sacc = 0.f;
        unsigned ph[16], pl[16];
        #pragma unroll
        for (int i = 0; i < 32; i += 2) {
            float v0 = T[half*32 + i][f2];
            float v1 = T[half*32 + i + 1][f2];
            sacc += v0 + v1;
            pack_hl(v0, v1, ph[i>>1], pl[i>>1]);
        }
        size_t ob = ((size_t)b*F + f2)*T2 + t0 + half*32;
        store16u(&OTh[ob], ph);
        store16u(&OTl[ob], pl);
        if (doLN)
            spartN[((size_t)b*100 + tblk*2 + half)*128 + f2] = sacc;
    }
}

// ============ fused: reduce Gpart -> M = SCALE(P@G + u⊗s); rm ==============
__global__ __launch_bounds__(256) void k_cm2(
    const float* __restrict__ Gpart, int np2,
    const float* __restrict__ spart, int np_s,
    const short* __restrict__ Pjh, const short* __restrict__ Pjl,
    const float* __restrict__ uj, const float* __restrict__ wj,
    const float* __restrict__ cj,
    short* __restrict__ Mth, short* __restrict__ Mtl, float* __restrict__ rm)
{
    int kh = blockIdx.x, b = blockIdx.y;
    __shared__ SMem Smem;
    CMS2& S = *(CMS2*)Smem.buf;
    float (*T)[132] = (float(*)[132])Smem.buf;
    float* sv = Smem.sv;

    int tid = threadIdx.x;
    int lane = tid & 63, wid = tid >> 6;
    int wr = wid >> 1, wc = wid & 1;
    int r16 = lane & 15, kg = lane >> 4;
    int row = tid >> 1;

    if (tid < 128) {
        float s = 0.f;
        for (int i = 0; i < np_s; ++i) s += spart[((size_t)b*np_s + i)*128 + tid];
        sv[tid] = s;
    }

    f32x4 acc[2][4];
    #pragma unroll
    for (int i = 0; i < 2; ++i)
        #pragma unroll
        for (int j2 = 0; j2 < 4; ++j2)
            acc[i][j2] = (f32x4){0.f,0.f,0.f,0.f};
    float pr = 0.f;

    for (int p = 0; p < 2; ++p) {
        int c0 = p*64 + (tid & 1)*32;
        float a[32];
        #pragma unroll
        for (int v = 0; v < 32; ++v) a[v] = 0.f;
        for (int i = 0; i < np2; ++i) {
            const float* g = Gpart + ((size_t)b*25 + i)*16384 + (size_t)row*128 + c0;
            #pragma unroll
            for (int v = 0; v < 32; v += 4) {
                float4 x = *(const float4*)&g[v];
                a[v] += x.x; a[v+1] += x.y; a[v+2] += x.z; a[v+3] += x.w;
            }
        }
        #pragma unroll
        for (int v = 0; v < 32; v += 4) {
            float4 w4 = *(const float4*)&wj[c0 + v];
            pr = fmaf(a[v],   w4.x, pr);
            pr = fmaf(a[v+1], w4.y, pr);
            pr = fmaf(a[v+2], w4.z, pr);
            pr = fmaf(a[v+3], w4.w, pr);
        }
        __syncthreads();            // previous pass's LDS reads done; sv ready
        {
            unsigned ph[16], pl[16];
            #pragma unroll
            for (int v = 0; v < 32; v += 2)
                pack_hl(a[v], a[v+1], ph[v>>1], pl[v>>1]);
            int ck = tid & 1;
            store16u(&S.Gsh[ck][row][0], ph);
            store16u(&S.Gsl[ck][row][0], pl);
        }
        {
            int prow = tid >> 2, quad = tid & 3;
            const short* ph_ = Pjh + (size_t)(kh*64 + prow)*128 + p*64 + quad*16;
            const short* pl_ = Pjl + (size_t)(kh*64 + prow)*128 + p*64 + quad*16;
            int ck = quad >> 1, off = (quad & 1)*16;
            *(uint4v*)&S.Psh[ck][prow][off]     = *(const uint4v*)ph_;
            *(uint4v*)&S.Psh[ck][prow][off+8]   = *(const uint4v*)(ph_ + 8);
            *(uint4v*)&S.Psl[ck][prow][off]     = *(const uint4v*)pl_;
            *(uint4v*)&S.Psl[ck][prow][off+8]   = *(const uint4v*)(pl_ + 8);
        }
        __syncthreads();
        #pragma unroll
        for (int ks = 0; ks < 2; ++ks) {
            bf16x8 ah[2], al[2], bh[4], bl[4];
            #pragma unroll
            for (int i = 0; i < 2; ++i) {
                ah[i] = *(const bf16x8*)&S.Psh[ks][wr*32 + i*16 + r16][kg*8];
                al[i] = *(const bf16x8*)&S.Psl[ks][wr*32 + i*16 + r16][kg*8];
            }
            #pragma unroll
            for (int j2 = 0; j2 < 4; ++j2) {
                bh[j2] = *(const bf16x8*)&S.Gsh[ks][wc*64 + j2*16 + r16][kg*8];
                bl[j2] = *(const bf16x8*)&S.Gsl[ks][wc*64 + j2*16 + r16][kg*8];
            }
            #pragma unroll
            for (int i = 0; i < 2; ++i)
                #pragma unroll
                for (int j2 = 0; j2 < 4; ++j2) {
                    acc[i][j2] = __builtin_amdgcn_mfma_f32_16x16x32_bf16(ah[i], bh[j2], acc[i][j2], 0,0,0);
                    acc[i][j2] = __builtin_amdgcn_mfma_f32_16x16x32_bf16(al[i], bh[j2], acc[i][j2], 0,0,0);
                    acc[i][j2] = __builtin_amdgcn_mfma_f32_16x16x32_bf16(ah[i], bl[j2], acc[i][j2], 0,0,0);
                }
        }
    }
    // r (kh==0): pair-sum pr over (even,odd) threads of same row
    {
        float prt = pr + __shfl_xor(pr, 1);
        if (kh == 0 && (tid & 1) == 0)
            rm[b*128 + row] = SCALE*(prt + cj[0]*sv[row]);
    }
    float uval[2][4], svv[4];
    #pragma unroll
    for (int i = 0; i < 2; ++i)
        #pragma unroll
        for (int reg = 0; reg < 4; ++reg)
            uval[i][reg] = uj[kh*64 + wr*32 + i*16 + kg*4 + reg];
    #pragma unroll
    for (int j2 = 0; j2 < 4; ++j2) svv[j2] = sv[wc*64 + j2*16 + r16];
    __syncthreads();
    #pragma unroll
    for (int i = 0; i < 2; ++i)
        #pragma unroll
        for (int j2 = 0; j2 < 4; ++j2)
            #pragma unroll
            for (int reg = 0; reg < 4; ++reg)
                T[wr*32 + i*16 + kg*4 + reg][wc*64 + j2*16 + r16]
                    = SCALE*(acc[i][j2][reg] + uval[i][reg]*svv[j2]);
    __syncthreads();
    {
        int f2 = tid >> 1, half = tid & 1;
        unsigned ph[16], pl[16];
        #pragma unroll
        for (int i = 0; i < 32; i += 2) {
            float v0 = T[half*32 + i][f2];
            float v1 = T[half*32 + i + 1][f2];
            pack_hl(v0, v1, ph[i>>1], pl[i>>1]);
        }
        size_t ob = ((size_t)b*F + f2)*F + kh*64 + half*32;
        store16u(&Mth[ob], ph);
        store16u(&Mtl[ob], pl);
    }
}

// =================== fused kernels =========================================
__global__ __launch_bounds__(256) void k_apply_gsym(
    const float* xy, const float* g0, const float* b0, const float* lnpart,
    short* Vbh, short* Vbl, short* Vbth, short* Vbtl,
    short* xyTh, short* xyTl, float* spartV, float* s2part, float* Gpart)
{
    __shared__ SMem S;
    int jb = blockIdx.x;
    if (jb < 200) {
        int tgrp = jb % 25, b = jb / 25;
        body_apply(tgrp, b, xy, g0, b0, lnpart, Vbh, Vbl, Vbth, Vbtl, spartV, S);
        __syncthreads();
        body_gsym(tgrp, b, Vbth, Vbtl, Gpart, S);
    } else {
        int t = jb - 200;
        body_xyt(t % 25, t / 25, xy, xyTh, xyTl, s2part, S);
    }
}

// mode: 0 = gsym after mid, 1 = gasym (j==2->3), 2 = none (final mid)
__global__ __launch_bounds__(256) void k_mid_gsym(
    short* Vbh, short* Vbl, const short* Mth, const short* Mtl,
    const float* rm, const float* glj, const float* blj, int doLN,
    short* OTh, short* OTl, float* spartN,
    int mode, const short* xyTh, const short* xyTl, float* Gpart)
{
    __shared__ SMem S;
    int s = blockIdx.x, b = blockIdx.y;
    #pragma unroll
    for (int pass = 0; pass < 2; ++pass) {
        body_mid(s*2 + pass, b, Vbh, Vbl, Mth, Mtl, rm, glj, blj, doLN,
                 OTh, OTl, spartN, S);
        __syncthreads();
    }
    if (mode == 0) {
        body_gsym(s, b, OTh, OTl, Gpart, S);
    } else if (mode == 1) {
        int nks = (s < 12) ? 4 : ((s == 12) ? 2 : 0);
        if (nks) body_gasym2(s, b, nks, xyTh, xyTl, OTh, OTl, Gpart, S);
    }
}

// ------------- out = DXDY * W2(bf16) @ U(bf16 h/l), MFMA -------------------
__global__ __launch_bounds__(256) void k_gout(
    const short* __restrict__ W2h,
    const short* __restrict__ Uth, const short* __restrict__ Utl,
    float* __restrict__ out)
{
    int job = blockIdx.x;
    int nt = job % 25, b = job / 25;
    int n0 = nt * 64;
    __shared__ GOutS S;

    int tid = threadIdx.x;
    int lane = tid & 63, wid = tid >> 6;
    int wr = wid >> 1, wc = wid & 1;
    int r16 = lane & 15, kg = lane >> 4;
    int srow = tid >> 2, sq2 = tid & 3;
    int sf = tid >> 1, sh2 = tid & 1;

    const short* ap  = W2h + (size_t)(n0 + srow)*T2 + sq2*8;
    const short* bhp = Uth + ((size_t)b*F + sf)*T2 + sh2*16;
    const short* blp = Utl + ((size_t)b*F + sf)*T2 + sh2*16;

    f32x4 acc[2][4];
    #pragma unroll
    for (int i = 0; i < 2; ++i)
        #pragma unroll
        for (int j2 = 0; j2 < 4; ++j2)
            acc[i][j2] = (f32x4){0.f,0.f,0.f,0.f};

    {
        *(uint4v*)&S.As[0][srow][sq2*8]  = *(const uint4v*)ap;
        *(uint4v*)&S.Bh[0][sf][sh2*16]   = *(const uint4v*)bhp;
        *(uint4v*)&S.Bh[0][sf][sh2*16+8] = *(const uint4v*)(bhp + 8);
        *(uint4v*)&S.Bl[0][sf][sh2*16]   = *(const uint4v*)blp;
        *(uint4v*)&S.Bl[0][sf][sh2*16+8] = *(const uint4v*)(blp + 8);
    }
    for (int it = 0; it < 100; ++it) {
        int cur = it & 1;
        uint4v ra, b0, b1, b2, b3;
        if (it < 99) {
            int ko = (it + 1) * 32;
            ra = *(const uint4v*)(ap + ko);
            b0 = *(const uint4v*)(bhp + ko); b1 = *(const uint4v*)(bhp + ko + 8);
            b2 = *(const uint4v*)(blp + ko); b3 = *(const uint4v*)(blp + ko + 8);
        }
        __syncthreads();
        bf16x8 ah[2], bh[4], bl[4];
        #pragma unroll
        for (int i = 0; i < 2; ++i)
            ah[i] = *(const bf16x8*)&S.As[cur][wr*32 + i*16 + r16][kg*8];
        #pragma unroll
        for (int j2 = 0; j2 < 4; ++j2) {
            bh[j2] = *(const bf16x8*)&S.Bh[cur][wc*64 + j2*16 + r16][kg*8];
            bl[j2] = *(const bf16x8*)&S.Bl[cur][wc*64 + j2*16 + r16][kg*8];
        }
        #pragma unroll
        for (int i = 0; i < 2; ++i)
            #pragma unroll
            for (int j2 = 0; j2 < 4; ++j2) {
                acc[i][j2] = __builtin_amdgcn_mfma_f32_16x16x32_bf16(ah[i], bh[j2], acc[i][j2], 0,0,0);
                acc[i][j2] = __builtin_amdgcn_mfma_f32_16x16x32_bf16(ah[i], bl[j2], acc[i][j2], 0,0,0);
            }
        if (it < 99) {
            int nb = cur ^ 1;
            *(uint4v*)&S.As[nb][srow][sq2*8]  = ra;
            *(uint4v*)&S.Bh[nb][sf][sh2*16]   = b0;
            *(uint4v*)&S.Bh[nb][sf][sh2*16+8] = b1;
            *(uint4v*)&S.Bl[nb][sf][sh2*16]   = b2;
            *(uint4v*)&S.Bl[nb][sf][sh2*16+8] = b3;
        }
    }
    #pragma unroll
    for (int i = 0; i < 2; ++i)
        #pragma unroll
        for (int j2 = 0; j2 < 4; ++j2)
            #pragma unroll
            for (int reg = 0; reg < 4; ++reg) {
                int n_out = n0 + wr*32 + i*16 + kg*4 + reg;
                int f_out = wc*64 + j2*16 + r16;
                out[((size_t)b*NT + n_out)*F + f_out] = DXDY * acc[i][j2][reg];
            }
}

// =============================== launcher ==================================
extern "C" void kernel_launch(void* const* d_in, const int* in_sizes, int n_in,
                              void* d_out, int out_size, void* d_ws, size_t ws_size,
                              hipStream_t stream)
{
    const float* xy  = (const float*)d_in[0];
    const float* kW1 = (const float*)d_in[1];
    const float* kb1 = (const float*)d_in[2];
    const float* kW2 = (const float*)d_in[3];
    const float* kb2 = (const float*)d_in[4];
    const float* kW3 = (const float*)d_in[5];
    const float* kb3 = (const float*)d_in[6];
    const float* fW1 = (const float*)d_in[7];
    const float* fb1 = (const float*)d_in[8];
    const float* fW2 = (const float*)d_in[9];
    const float* fb2 = (const float*)d_in[10];
    const float* fW3 = (const float*)d_in[11];
    const float* fb3 = (const float*)d_in[12];
    const float* Wq  = (const float*)d_in[13];
    const float* bq  = (const float*)d_in[14];
    const float* Wk  = (const float*)d_in[15];
    const float* bk  = (const float*)d_in[16];
    const float* g0  = (const float*)d_in[17];
    const float* b0  = (const float*)d_in[18];
    const float* gl  = (const float*)d_in[19];
    const float* bl  = (const float*)d_in[20];
    float* out = (float*)d_out;

    short* W2h  = (short*)d_ws;                 // 5,120,000
    short* Vbh  = W2h  + 5120000;               // 3,276,800
    short* Vbl  = Vbh  + 3276800;
    short* Vbth = Vbl  + 3276800;
    short* Vbtl = Vbth + 3276800;
    short* xyTh = Vbtl + 3276800;               // 1,638,400
    short* xyTl = xyTh + 1638400;
    short* Uth  = xyTl + 1638400;               // 3,276,800
    short* Utl  = Uth  + 3276800;
    short* Pnh  = Utl  + 3276800;               // 65,536
    short* Pnl  = Pnh  + 65536;
    short* Mth  = Pnl  + 65536;                 // 131,072
    short* Mtl  = Mth  + 131072;
    short* AhF  = Mtl  + 131072;                // 4,096
    short* AlF  = AhF  + 4096;
    float* Gpart  = (float*)(AlF + 4096);       // 3,276,800 f
    float* uB     = Gpart + 3276800;            // 512
    float* wB     = uB + 512;                   // 512
    float* cB     = wB + 512;                   // 4
    float* lnpart = cB + 4;                     // 400
    float* rm     = lnpart + 400;               // 1024
    float* spartV = rm + 1024;                  // 102,400
    float* s2part = spartV + 102400;            // 51,200
    float* uvT    = s2part + 51200;             // 204,800

    k_prep<<<dim3(437), 256, 0, stream>>>(kW2, fW2, AhF, AlF,
                                          kW1, kb1, fW1, fb1, uvT,
                                          xy, lnpart,
                                          Wq, bq, Wk, bk, Pnh, Pnl, uB, wB, cB);

    k_mlp_mfma<<<dim3(1600), 256, 0, stream>>>(uvT, kb2, kW3, kb3,
                                               fb2, fW3, fb3, AhF, AlF, W2h);

    // phase 0: LN0 apply + xyT + gsym for layer 0
    k_apply_gsym<<<dim3(400), 256, 0, stream>>>(xy, g0, b0, lnpart,
                                                Vbh, Vbl, Vbth, Vbtl,
                                                xyTh, xyTl, spartV, s2part, Gpart);

    for (int j = 0; j < 4; ++j) {
        int np2  = (j < 3) ? 25 : 13;
        int np_s = (j < 3) ? 100 : 50;
        const float* sp = (j < 3) ? spartV : s2part;
        k_cm2<<<dim3(2, 8), 256, 0, stream>>>(
            Gpart, np2, sp, np_s,
            Pnh + (size_t)j*16384, Pnl + (size_t)j*16384,
            uB + j*128, wB + j*128, cB + j, Mth, Mtl, rm);

        if (j < 2) {        // mid_j + gsym_{j+1}
            k_mid_gsym<<<dim3(25, 8), 256, 0, stream>>>(
                Vbh, Vbl, Mth, Mtl, rm, gl + j*128, bl + j*128, 1,
                Vbth, Vbtl, spartV, 0, xyTh, xyTl, Gpart);
        } else if (j == 2) { // mid_2 + gasym_3 (13 partials)
            k_mid_gsym<<<dim3(25, 8), 256, 0, stream>>>(
                Vbh, Vbl, Mth, Mtl, rm, gl + j*128, bl + j*128, 1,
                Vbth, Vbtl, spartV, 1, xyTh, xyTl, Gpart);
        } else {             // mid_3 -> U, no LN, no gsym
            k_mid_gsym<<<dim3(25, 8), 256, 0, stream>>>(
                Vbh, Vbl, Mth, Mtl, rm, gl, bl, 0,
                Uth, Utl, spartV, 2, xyTh, xyTl, Gpart);
        }
    }

    k_gout<<<dim3(200), 256, 0, stream>>>(W2h, Uth, Utl, out);
}

// Round 9
// 526.034 us; speedup vs baseline: 2.0818x; 1.2560x over previous
//
#include <hip/hip_runtime.h>
#include <math.h>

#define NGRID 40
#define NT    1600
#define T2    3200
#define F     128
#define NB    8
#define EPS   1e-5f

__device__ __constant__ const float kINV39 = 1.0f/39.0f;
constexpr float DXDY  = (1.0f/39.0f)*(1.0f/39.0f);
constexpr float SCALE = DXDY * 0.125f;   // DXDY / sqrt(64)

typedef __attribute__((ext_vector_type(8))) short bf16x8;
typedef __attribute__((ext_vector_type(4))) float f32x4;
typedef __attribute__((ext_vector_type(4))) unsigned uint4v;

__device__ __forceinline__ unsigned bitu(float f){ return __builtin_bit_cast(unsigned,f); }
__device__ __forceinline__ float bitf(unsigned u){ return __builtin_bit_cast(float,u); }
__device__ __forceinline__ unsigned short f2bf(float f) {
    unsigned u = bitu(f);
    unsigned r = u + 0x7FFFu + ((u >> 16) & 1u);
    return (unsigned short)(r >> 16);
}
__device__ __forceinline__ float bf2f(unsigned short h) { return bitf(((unsigned)h) << 16); }

__device__ __forceinline__ void pack_hl(float a, float b, unsigned &h, unsigned &l) {
    unsigned ua = bitu(a), ub = bitu(b);
    h = __builtin_amdgcn_perm(ub, ua, 0x07060302u);
    float ra = a - bitf(ua & 0xffff0000u);
    float rb = b - bitf(ub & 0xffff0000u);
    l = __builtin_amdgcn_perm(bitu(rb), bitu(ra), 0x07060302u);
}
__device__ __forceinline__ void store8u(short* dst, const unsigned* p) {
    uint4v v0 = {p[0], p[1], p[2], p[3]};
    uint4v v1 = {p[4], p[5], p[6], p[7]};
    *(uint4v*)dst = v0;
    *(uint4v*)(dst + 8) = v1;
}
__device__ __forceinline__ void store16u(short* dst, const unsigned* p) {
    store8u(dst, p);
    store8u(dst + 16, p + 8);
}

// shared-memory union
struct SMem {
    __align__(16) char buf[61440];
    float sv[128];
};
struct GSymS  { short Sh[2][128][40], Sl[2][128][40]; };
struct GAs2S  { short Ahs[128][40], Als[128][40], Bhs[128][40], Bls[128][40]; };
struct CMS    { short Psh[2][64][40], Psl[2][64][40], Bsh[2][128][40], Bsl[2][128][40]; };
struct MidS   { short Ash[2][64][40], Asl[2][64][40], Bsh[2][128][40], Bsl[2][128][40]; };
struct GOutS  { short As[2][64][40], Bh[2][128][40], Bl[2][128][40]; };

// =================== fused prep: uv | ln0_part | P | frag ==================
__global__ __launch_bounds__(256) void k_prep(
    const float* __restrict__ kW2, const float* __restrict__ fW2,
    short* __restrict__ Ah, short* __restrict__ Al,
    const float* __restrict__ kW1, const float* __restrict__ kb1,
    const float* __restrict__ fW1, const float* __restrict__ fb1,
    float* __restrict__ uv,
    const float* __restrict__ xy, float* __restrict__ lnpart,
    const float* __restrict__ Wq, const float* __restrict__ bq,
    const float* __restrict__ Wk, const float* __restrict__ bk,
    short* __restrict__ Pnh, short* __restrict__ Pnl,
    float* __restrict__ uB, float* __restrict__ wB, float* __restrict__ cB)
{
    __shared__ float ss[4], qs[4];
    int job = blockIdx.x;
    int tid = threadIdx.x;
    if (job < 200) {
        int idx = job * 256 + tid;
        int node = idx >> 5, o = idx & 31;
        float x0 = (float)(node / NGRID) * kINV39;
        float x1 = (float)(node % NGRID) * kINV39;
        uv[idx]          = fmaf(kW1[o], x0, fmaf(kW1[32+o], x1, kb1[o]));
        uv[51200 + idx]  = fmaf(kW1[64+o], x0, kW1[96+o]*x1);
        uv[102400 + idx] = fmaf(fW1[o], x0, fmaf(fW1[32+o], x1, fb1[o]));
        uv[153600 + idx] = fmaf(fW1[64+o], x0, fW1[96+o]*x1);
        return;
    }
    if (job < 400) {
        int t = job - 200;
        int b = t & 7, blk = t >> 3;
        const float4* p = (const float4*)xy + (size_t)b*102400 + blk*4096 + tid;
        float s = 0.f, q = 0.f;
        #pragma unroll
        for (int i = 0; i < 16; ++i) {
            float4 v = p[i*256];
            s += (v.x + v.y) + (v.z + v.w);
            q += (v.x*v.x + v.y*v.y) + (v.z*v.z + v.w*v.w);
        }
        #pragma unroll
        for (int off = 32; off >= 1; off >>= 1) {
            s += __shfl_xor(s, off);
            q += __shfl_xor(q, off);
        }
        int wid = tid >> 6;
        if ((tid & 63) == 0) { ss[wid] = s; qs[wid] = q; }
        __syncthreads();
        if (tid == 0) {
            lnpart[((size_t)b*25 + blk)*2 + 0] = ss[0]+ss[1]+ss[2]+ss[3];
            lnpart[((size_t)b*25 + blk)*2 + 1] = qs[0]+qs[1]+qs[2]+qs[3];
        }
        return;
    }
    if (job < 436) {
        int t = job - 400;
        int j = t & 3, part = t >> 2;
        const float* wq = Wq + (size_t)j*8*F*64;
        const float* wk = Wk + (size_t)j*8*F*64;
        if (part == 8) {
            const float* bqj = bq + j*512;
            const float* bkj = bk + j*512;
            if (tid < 128) {
                int k = tid; float a = 0.f;
                for (int h = 0; h < 8; ++h)
                    for (int d = 0; d < 64; ++d)
                        a = fmaf(wq[((size_t)h*F + k)*64 + d], bkj[h*64 + d], a);
                uB[j*128 + k] = a;
            } else {
                int k = tid - 128; float a = 0.f;
                for (int h = 0; h < 8; ++h)
                    for (int d = 0; d < 64; ++d)
                        a = fmaf(wk[((size_t)h*F + k)*64 + d], bqj[h*64 + d], a);
                wB[j*128 + k] = a;
            }
            if (tid == 0) {
                float a = 0.f;
                for (int i = 0; i < 512; ++i) a = fmaf(bqj[i], bkj[i], a);
                cB[j] = a;
            }
            return;
        }
        int kp = part*16 + (tid >> 4);
        int k0 = (tid & 15) * 8;
        float acc[8] = {0,0,0,0,0,0,0,0};
        for (int h = 0; h < 8; ++h) {
            const float* wkrow = wk + ((size_t)h*F + kp)*64;
            for (int d = 0; d < 64; ++d) {
                float bv = wkrow[d];
                #pragma unroll
                for (int i = 0; i < 8; ++i)
                    acc[i] = fmaf(wq[((size_t)h*F + k0 + i)*64 + d], bv, acc[i]);
            }
        }
        #pragma unroll
        for (int i = 0; i < 8; ++i) {
            float val = acc[i];
            short hs = (short)(bitu(val) >> 16);
            float rem = val - bitf(bitu(val) & 0xffff0000u);
            short ls = (short)(bitu(rem) >> 16);
            Pnh[((size_t)j*128 + k0 + i)*128 + kp] = hs;
            Pnl[((size_t)j*128 + k0 + i)*128 + kp] = ls;
        }
        return;
    }
    {
        int oc = tid >> 6, lane = tid & 63;
        int row = lane & 15;
        int k0 = (lane >> 4) * 8;
        #pragma unroll
        for (int mlp = 0; mlp < 2; ++mlp) {
            const float* W2 = mlp ? fW2 : kW2;
            #pragma unroll
            for (int i = 0; i < 8; ++i) {
                float w = W2[(size_t)(k0 + i) * 64 + oc * 16 + row];
                unsigned short h = f2bf(w);
                Ah[((mlp*4 + oc)*64 + lane)*8 + i] = (short)h;
                Al[((mlp*4 + oc)*64 + lane)*8 + i] = (short)f2bf(w - bf2f(h));
            }
        }
    }
}

// ============ MLP helper body: 20 tiles per block (5 per wave) =============
__device__ void body_mlp(int tile0,
    const float* __restrict__ uv,
    const float* __restrict__ kb2, const float* __restrict__ kW3,
    const float* __restrict__ kb3,
    const float* __restrict__ fb2, const float* __restrict__ fW3,
    const float* __restrict__ fb3,
    const short* __restrict__ Ah, const short* __restrict__ Al,
    short* __restrict__ W2h)
{
    int tid = threadIdx.x;
    int wid = tid >> 6, lane = tid & 63;
    int c = lane & 15, kg = lane >> 4;
    int k0 = kg * 8;

    bf16x8 AHf[2][4], ALf[2][4];
    float4 B2f[2][4], W3f[2][4];
    #pragma unroll
    for (int mlp = 0; mlp < 2; ++mlp) {
        const float* b2p = mlp ? fb2 : kb2;
        const float* w3p = mlp ? fW3 : kW3;
        #pragma unroll
        for (int oc = 0; oc < 4; ++oc) {
            AHf[mlp][oc] = *(const bf16x8*)&Ah[((mlp*4 + oc)*64 + lane)*8];
            ALf[mlp][oc] = *(const bf16x8*)&Al[((mlp*4 + oc)*64 + lane)*8];
            B2f[mlp][oc] = *(const float4*)&b2p[oc*16 + kg*4];
            W3f[mlp][oc] = *(const float4*)&w3p[oc*16 + kg*4];
        }
    }
    float bias0 = kb3[0], bias1 = fb3[0];

    int t = tile0 + wid*5;
    for (int it = 0; it < 5; ++it, ++t) {
        int n = t / 100;
        int mt = t - n*100;
        int m = mt*16 + c;
        float res0, res1;
        #pragma unroll
        for (int mlp = 0; mlp < 2; ++mlp) {
            const float* up = uv + mlp*102400 + n*32 + k0;
            const float* vp = uv + mlp*102400 + 51200 + m*32 + k0;
            float4 ua = *(const float4*)up;
            float4 ub = *(const float4*)(up + 4);
            float4 va = *(const float4*)vp;
            float4 vb = *(const float4*)(vp + 4);
            float h[8] = {ua.x+va.x, ua.y+va.y, ua.z+va.z, ua.w+va.w,
                          ub.x+vb.x, ub.y+vb.y, ub.z+vb.z, ub.w+vb.w};
            #pragma unroll
            for (int i = 0; i < 8; ++i) h[i] = fmaxf(h[i], 0.01f*h[i]);
            unsigned bhp[4], blp[4];
            #pragma unroll
            for (int p = 0; p < 4; ++p)
                pack_hl(h[2*p], h[2*p+1], bhp[p], blp[p]);
            uint4v bhv = {bhp[0], bhp[1], bhp[2], bhp[3]};
            uint4v blv = {blp[0], blp[1], blp[2], blp[3]};
            bf16x8 bh = __builtin_bit_cast(bf16x8, bhv);
            bf16x8 bl = __builtin_bit_cast(bf16x8, blv);
            float acc = 0.f;
            #pragma unroll
            for (int oc = 0; oc < 4; ++oc) {
                f32x4 d = {B2f[mlp][oc].x, B2f[mlp][oc].y,
                           B2f[mlp][oc].z, B2f[mlp][oc].w};
                d = __builtin_amdgcn_mfma_f32_16x16x32_bf16(AHf[mlp][oc], bh, d, 0, 0, 0);
                d = __builtin_amdgcn_mfma_f32_16x16x32_bf16(ALf[mlp][oc], bh, d, 0, 0, 0);
                d = __builtin_amdgcn_mfma_f32_16x16x32_bf16(AHf[mlp][oc], bl, d, 0, 0, 0);
                float w3v[4] = {W3f[mlp][oc].x, W3f[mlp][oc].y,
                                W3f[mlp][oc].z, W3f[mlp][oc].w};
                #pragma unroll
                for (int r = 0; r < 4; ++r)
                    acc = fmaf(fmaxf(d[r], 0.01f*d[r]), w3v[r], acc);
            }
            if (mlp == 0) res0 = acc; else res1 = acc;
        }
        res0 += __shfl_xor(res0, 16); res0 += __shfl_xor(res0, 32);
        res1 += __shfl_xor(res1, 16); res1 += __shfl_xor(res1, 32);
        if (lane < 16) {
            W2h[(size_t)n*T2 + m]      = (short)f2bf(res0 + bias0);
            W2h[(size_t)n*T2 + NT + m] = (short)f2bf(res1 + bias1);
        }
    }
}

// ====================== phase bodies (verified numerics) ====================
__device__ void body_apply(int tgrp, int b,
    const float* __restrict__ xy, const float* __restrict__ g0,
    const float* __restrict__ b0, const float* __restrict__ lnpart,
    short* __restrict__ Vbh, short* __restrict__ Vbl,
    short* __restrict__ Vbth, short* __restrict__ Vbtl,
    float* __restrict__ spartV, SMem& S)
{
    float s = 0.f, q = 0.f;
    for (int i = 0; i < 25; ++i) {
        s += lnpart[((size_t)b*25 + i)*2 + 0];
        q += lnpart[((size_t)b*25 + i)*2 + 1];
    }
    float mu = s * (1.0f/409600.0f);
    float rs = rsqrtf(q * (1.0f/409600.0f) - mu*mu + EPS);
    float (*T)[132] = (float(*)[132])S.buf;
    int tid = threadIdx.x;
    int r = tid >> 2, qd = tid & 3;
    int f2 = tid >> 1, half = tid & 1;
    #pragma unroll
    for (int p = 0; p < 2; ++p) {
        int t0 = tgrp*128 + p*64;
        {
            int t = t0 + r;
            const float* xp = xy + ((size_t)b*T2 + t)*F + qd*32;
            const float* gp = g0 + (size_t)t*F + qd*32;
            const float* bp = b0 + (size_t)t*F + qd*32;
            unsigned ph[16], pl[16];
            #pragma unroll
            for (int i = 0; i < 32; i += 4) {
                float4 x = *(const float4*)&xp[i];
                float4 g = *(const float4*)&gp[i];
                float4 bb = *(const float4*)&bp[i];
                float o0 = (x.x - mu)*rs*g.x + bb.x;
                float o1 = (x.y - mu)*rs*g.y + bb.y;
                float o2 = (x.z - mu)*rs*g.z + bb.z;
                float o3 = (x.w - mu)*rs*g.w + bb.w;
                T[r][qd*32+i] = o0; T[r][qd*32+i+1] = o1;
                T[r][qd*32+i+2] = o2; T[r][qd*32+i+3] = o3;
                pack_hl(o0, o1, ph[i>>1], pl[i>>1]);
                pack_hl(o2, o3, ph[(i>>1)+1], pl[(i>>1)+1]);
            }
            size_t ob = ((size_t)b*T2 + t)*F + qd*32;
            store16u(&Vbh[ob], ph);
            store16u(&Vbl[ob], pl);
        }
        __syncthreads();
        {
            float sacc = 0.f;
            unsigned ph[16], pl[16];
            #pragma unroll
            for (int i = 0; i < 32; i += 2) {
                float v0 = T[half*32 + i][f2];
                float v1 = T[half*32 + i + 1][f2];
                sacc += v0 + v1;
                pack_hl(v0, v1, ph[i>>1], pl[i>>1]);
            }
            size_t ob = ((size_t)b*F + f2)*T2 + t0 + half*32;
            store16u(&Vbth[ob], ph);
            store16u(&Vbtl[ob], pl);
            spartV[((size_t)b*100 + (tgrp*2+p)*2 + half)*128 + f2] = sacc;
        }
        __syncthreads();
    }
}

__device__ void body_xyt(int tgrp, int b,
    const float* __restrict__ xy,
    short* __restrict__ xyTh, short* __restrict__ xyTl,
    float* __restrict__ s2part, SMem& S)
{
    float (*T)[132] = (float(*)[132])S.buf;
    int tid = threadIdx.x;
    int r = tid >> 2, qd = tid & 3;
    int f2 = tid >> 1, half = tid & 1;
    int t0 = tgrp*64;
    {
        const float* xp = xy + ((size_t)b*T2 + t0 + r)*F + qd*32;
        #pragma unroll
        for (int i = 0; i < 32; i += 4)
            *(float4*)&T[r][qd*32+i] = *(const float4*)&xp[i];
    }
    __syncthreads();
    {
        float sacc = 0.f;
        unsigned ph[16], pl[16];
        #pragma unroll
        for (int i = 0; i < 32; i += 2) {
            float v0 = T[half*32 + i][f2];
            float v1 = T[half*32 + i + 1][f2];
            sacc += v0 + v1;
            pack_hl(v0, v1, ph[i>>1], pl[i>>1]);
        }
        size_t ob = ((size_t)b*F + f2)*1600 + t0 + half*32;
        store16u(&xyTh[ob], ph);
        store16u(&xyTl[ob], pl);
        s2part[((size_t)b*50 + tgrp*2 + half)*128 + f2] = sacc;
    }
}

__device__ void body_gsym(int split, int b,
    const short* __restrict__ Xh, const short* __restrict__ Xl,
    float* __restrict__ Gpart, SMem& Smem)
{
    int t0 = split*128;
    GSymS& S = *(GSymS*)Smem.buf;
    int tid = threadIdx.x;
    int lane = tid & 63, wid = tid >> 6;
    int wr = wid >> 1, wc = wid & 1;
    int r16 = lane & 15, kg = lane >> 4;
    int sf = tid >> 1, th = tid & 1;

    const short* ph_ = Xh + ((size_t)b*F + sf)*T2 + t0 + th*16;
    const short* pl_ = Xl + ((size_t)b*F + sf)*T2 + t0 + th*16;

    f32x4 acc[4][4];
    #pragma unroll
    for (int i = 0; i < 4; ++i)
        #pragma unroll
        for (int j2 = 0; j2 < 4; ++j2)
            acc[i][j2] = (f32x4){0.f,0.f,0.f,0.f};

    {
        uint4v h0 = *(const uint4v*)ph_,      h1 = *(const uint4v*)(ph_ + 8);
        uint4v l0 = *(const uint4v*)pl_,      l1 = *(const uint4v*)(pl_ + 8);
        *(uint4v*)&S.Sh[0][sf][th*16]     = h0; *(uint4v*)&S.Sh[0][sf][th*16+8] = h1;
        *(uint4v*)&S.Sl[0][sf][th*16]     = l0; *(uint4v*)&S.Sl[0][sf][th*16+8] = l1;
    }
    #pragma unroll
    for (int ks = 0; ks < 4; ++ks) {
        int cur = ks & 1;
        uint4v h0, h1, l0, l1;
        if (ks < 3) {
            int ko = (ks+1)*32;
            h0 = *(const uint4v*)(ph_ + ko); h1 = *(const uint4v*)(ph_ + ko + 8);
            l0 = *(const uint4v*)(pl_ + ko); l1 = *(const uint4v*)(pl_ + ko + 8);
        }
        __syncthreads();
        bf16x8 ah[4], al[4], bh[4], bl[4];
        #pragma unroll
        for (int i = 0; i < 4; ++i) {
            ah[i] = *(const bf16x8*)&S.Sh[cur][wr*64 + i*16 + r16][kg*8];
            al[i] = *(const bf16x8*)&S.Sl[cur][wr*64 + i*16 + r16][kg*8];
            bh[i] = *(const bf16x8*)&S.Sh[cur][wc*64 + i*16 + r16][kg*8];
            bl[i] = *(const bf16x8*)&S.Sl[cur][wc*64 + i*16 + r16][kg*8];
        }
        #pragma unroll
        for (int i = 0; i < 4; ++i)
            #pragma unroll
            for (int j2 = 0; j2 < 4; ++j2) {
                acc[i][j2] = __builtin_amdgcn_mfma_f32_16x16x32_bf16(ah[i], bh[j2], acc[i][j2], 0,0,0);
                acc[i][j2] = __builtin_amdgcn_mfma_f32_16x16x32_bf16(al[i], bh[j2], acc[i][j2], 0,0,0);
                acc[i][j2] = __builtin_amdgcn_mfma_f32_16x16x32_bf16(ah[i], bl[j2], acc[i][j2], 0,0,0);
            }
        if (ks < 3) {
            int nb = cur ^ 1;
            *(uint4v*)&S.Sh[nb][sf][th*16]     = h0; *(uint4v*)&S.Sh[nb][sf][th*16+8] = h1;
            *(uint4v*)&S.Sl[nb][sf][th*16]     = l0; *(uint4v*)&S.Sl[nb][sf][th*16+8] = l1;
        }
    }
    __syncthreads();
    size_t gb = ((size_t)b*25 + split)*16384;
    #pragma unroll
    for (int i = 0; i < 4; ++i)
        #pragma unroll
        for (int j2 = 0; j2 < 4; ++j2)
            #pragma unroll
            for (int reg = 0; reg < 4; ++reg)
                Gpart[gb + (size_t)(wr*64 + i*16 + kg*4 + reg)*128 + wc*64 + j2*16 + r16]
                    = acc[i][j2][reg];
}

__device__ void body_gasym2(int split, int b, int nks,
    const short* __restrict__ Ah_, const short* __restrict__ Al_,
    const short* __restrict__ Bh_, const short* __restrict__ Bl_,
    float* __restrict__ Gpart, SMem& Smem)
{
    int t0 = split*128;
    GAs2S& S = *(GAs2S*)Smem.buf;
    int tid = threadIdx.x;
    int lane = tid & 63, wid = tid >> 6;
    int wr = wid >> 1, wc = wid & 1;
    int r16 = lane & 15, kg = lane >> 4;
    int sf = tid >> 1, th = tid & 1;

    const short* pah = Ah_ + ((size_t)b*F + sf)*1600 + t0 + th*16;
    const short* pal = Al_ + ((size_t)b*F + sf)*1600 + t0 + th*16;
    const short* pbh = Bh_ + ((size_t)b*F + sf)*T2   + t0 + th*16;
    const short* pbl = Bl_ + ((size_t)b*F + sf)*T2   + t0 + th*16;

    f32x4 acc[4][4];
    #pragma unroll
    for (int i = 0; i < 4; ++i)
        #pragma unroll
        for (int j2 = 0; j2 < 4; ++j2)
            acc[i][j2] = (f32x4){0.f,0.f,0.f,0.f};

    for (int ks = 0; ks < nks; ++ks) {
        int ko = ks*32;
        __syncthreads();
        *(uint4v*)&S.Ahs[sf][th*16]   = *(const uint4v*)(pah + ko);
        *(uint4v*)&S.Ahs[sf][th*16+8] = *(const uint4v*)(pah + ko + 8);
        *(uint4v*)&S.Als[sf][th*16]   = *(const uint4v*)(pal + ko);
        *(uint4v*)&S.Als[sf][th*16+8] = *(const uint4v*)(pal + ko + 8);
        *(uint4v*)&S.Bhs[sf][th*16]   = *(const uint4v*)(pbh + ko);
        *(uint4v*)&S.Bhs[sf][th*16+8] = *(const uint4v*)(pbh + ko + 8);
        *(uint4v*)&S.Bls[sf][th*16]   = *(const uint4v*)(pbl + ko);
        *(uint4v*)&S.Bls[sf][th*16+8] = *(const uint4v*)(pbl + ko + 8);
        __syncthreads();
        bf16x8 ah[4], al[4], bh[4], bl[4];
        #pragma unroll
        for (int i = 0; i < 4; ++i) {
            ah[i] = *(const bf16x8*)&S.Ahs[wr*64 + i*16 + r16][kg*8];
            al[i] = *(const bf16x8*)&S.Als[wr*64 + i*16 + r16][kg*8];
            bh[i] = *(const bf16x8*)&S.Bhs[wc*64 + i*16 + r16][kg*8];
            bl[i] = *(const bf16x8*)&S.Bls[wc*64 + i*16 + r16][kg*8];
        }
        #pragma unroll
        for (int i = 0; i < 4; ++i)
            #pragma unroll
            for (int j2 = 0; j2 < 4; ++j2) {
                acc[i][j2] = __builtin_amdgcn_mfma_f32_16x16x32_bf16(ah[i], bh[j2], acc[i][j2], 0,0,0);
                acc[i][j2] = __builtin_amdgcn_mfma_f32_16x16x32_bf16(al[i], bh[j2], acc[i][j2], 0,0,0);
                acc[i][j2] = __builtin_amdgcn_mfma_f32_16x16x32_bf16(ah[i], bl[j2], acc[i][j2], 0,0,0);
            }
    }
    __syncthreads();
    size_t gb = ((size_t)b*25 + split)*16384;
    #pragma unroll
    for (int i = 0; i < 4; ++i)
        #pragma unroll
        for (int j2 = 0; j2 < 4; ++j2)
            #pragma unroll
            for (int reg = 0; reg < 4; ++reg)
                Gpart[gb + (size_t)(wr*64 + i*16 + kg*4 + reg)*128 + wc*64 + j2*16 + r16]
                    = acc[i][j2][reg];
}

__device__ void body_gred(int job, int np2,
    const float* __restrict__ Gpart, const float* __restrict__ wj,
    short* __restrict__ Gbh, short* __restrict__ Gbl, float* __restrict__ rpart)
{
    int part = job % 8, b = job / 8;
    int tid = threadIdx.x;
    int e0 = part*2048 + tid*8;
    float a[8] = {0,0,0,0,0,0,0,0};
    for (int i = 0; i < np2; ++i) {
        const float* p = Gpart + ((size_t)b*25 + i)*16384 + e0;
        float4 x0 = *(const float4*)p;
        float4 x1 = *(const float4*)(p + 4);
        a[0] += x0.x; a[1] += x0.y; a[2] += x0.z; a[3] += x0.w;
        a[4] += x1.x; a[5] += x1.y; a[6] += x1.z; a[7] += x1.w;
    }
    unsigned ph[4], pl[4];
    #pragma unroll
    for (int i = 0; i < 8; i += 2) pack_hl(a[i], a[i+1], ph[i>>1], pl[i>>1]);
    uint4v vh = {ph[0],ph[1],ph[2],ph[3]};
    uint4v vl = {pl[0],pl[1],pl[2],pl[3]};
    *(uint4v*)&Gbh[(size_t)b*16384 + e0] = vh;
    *(uint4v*)&Gbl[(size_t)b*16384 + e0] = vl;

    int c0 = e0 & 127;
    float4 w0 = *(const float4*)&wj[c0];
    float4 w1 = *(const float4*)&wj[c0 + 4];
    float pr = a[0]*w0.x + a[1]*w0.y + a[2]*w0.z + a[3]*w0.w
             + a[4]*w1.x + a[5]*w1.y + a[6]*w1.z + a[7]*w1.w;
    pr += __shfl_xor(pr, 1); pr += __shfl_xor(pr, 2);
    pr += __shfl_xor(pr, 4); pr += __shfl_xor(pr, 8);
    if ((tid & 15) == 0) rpart[b*128 + (e0 >> 7)] = pr;
}

__device__ void body_computeM(int job,
    const short* __restrict__ Gbh, const short* __restrict__ Gbl,
    const float* __restrict__ spart, int np,
    const short* __restrict__ Pjh, const short* __restrict__ Pjl,
    const float* __restrict__ uj, const float* __restrict__ cj,
    const float* __restrict__ rpart,
    short* __restrict__ Mth, short* __restrict__ Mtl, float* __restrict__ rm,
    SMem& Smem)
{
    int kh = job % 2, b = job / 2;
    CMS& S = *(CMS*)Smem.buf;
    float (*T)[132] = (float(*)[132])Smem.buf;
    float* sv = Smem.sv;

    int tid = threadIdx.x;
    int lane = tid & 63, wid = tid >> 6;
    int wr = wid >> 1, wc = wid & 1;
    int r16 = lane & 15, kg = lane >> 4;
    int st = tid >> 2, sq = tid & 3;
    int sf = tid >> 1, sh2 = tid & 1;

    if (tid < 128) {
        float s = 0.f;
        for (int i = 0; i < np; ++i) s += spart[((size_t)b*np + i)*128 + tid];
        sv[tid] = s;
        if (kh == 0) rm[b*128 + tid] = SCALE*(rpart[b*128 + tid] + cj[0]*s);
    }

    const short* pah = Pjh + (size_t)(kh*64 + st)*128 + sq*8;
    const short* pal = Pjl + (size_t)(kh*64 + st)*128 + sq*8;
    const short* pbh = Gbh + ((size_t)b*F + sf)*128 + sh2*16;
    const short* pbl = Gbl + ((size_t)b*F + sf)*128 + sh2*16;

    f32x4 acc[2][4];
    #pragma unroll
    for (int i = 0; i < 2; ++i)
        #pragma unroll
        for (int j2 = 0; j2 < 4; ++j2)
            acc[i][j2] = (f32x4){0.f,0.f,0.f,0.f};

    {
        *(uint4v*)&S.Psh[0][st][sq*8]      = *(const uint4v*)pah;
        *(uint4v*)&S.Psl[0][st][sq*8]      = *(const uint4v*)pal;
        *(uint4v*)&S.Bsh[0][sf][sh2*16]    = *(const uint4v*)pbh;
        *(uint4v*)&S.Bsh[0][sf][sh2*16+8]  = *(const uint4v*)(pbh + 8);
        *(uint4v*)&S.Bsl[0][sf][sh2*16]    = *(const uint4v*)pbl;
        *(uint4v*)&S.Bsl[0][sf][sh2*16+8]  = *(const uint4v*)(pbl + 8);
    }
    #pragma unroll
    for (int ks = 0; ks < 4; ++ks) {
        int cur = ks & 1;
        uint4v a0, a1, b0, b1, b2, b3;
        if (ks < 3) {
            int ko = (ks+1)*32;
            a0 = *(const uint4v*)(pah + ko); a1 = *(const uint4v*)(pal + ko);
            b0 = *(const uint4v*)(pbh + ko); b1 = *(const uint4v*)(pbh + ko + 8);
            b2 = *(const uint4v*)(pbl + ko); b3 = *(const uint4v*)(pbl + ko + 8);
        }
        __syncthreads();
        bf16x8 ah[2], al[2], bh[4], bl[4];
        #pragma unroll
        for (int i = 0; i < 2; ++i) {
            ah[i] = *(const bf16x8*)&S.Psh[cur][wr*32 + i*16 + r16][kg*8];
            al[i] = *(const bf16x8*)&S.Psl[cur][wr*32 + i*16 + r16][kg*8];
        }
        #pragma unroll
        for (int j2 = 0; j2 < 4; ++j2) {
            bh[j2] = *(const bf16x8*)&S.Bsh[cur][wc*64 + j2*16 + r16][kg*8];
            bl[j2] = *(const bf16x8*)&S.Bsl[cur][wc*64 + j2*16 + r16][kg*8];
        }
        #pragma unroll
        for (int i = 0; i < 2; ++i)
            #pragma unroll
            for (int j2 = 0; j2 < 4; ++j2) {
                acc[i][j2] = __builtin_amdgcn_mfma_f32_16x16x32_bf16(ah[i], bh[j2], acc[i][j2], 0,0,0);
                acc[i][j2] = __builtin_amdgcn_mfma_f32_16x16x32_bf16(al[i], bh[j2], acc[i][j2], 0,0,0);
                acc[i][j2] = __builtin_amdgcn_mfma_f32_16x16x32_bf16(ah[i], bl[j2], acc[i][j2], 0,0,0);
            }
        if (ks < 3) {
            int nb = cur ^ 1;
            *(uint4v*)&S.Psh[nb][st][sq*8]     = a0;
            *(uint4v*)&S.Psl[nb][st][sq*8]     = a1;
            *(uint4v*)&S.Bsh[nb][sf][sh2*16]   = b0;
            *(uint4v*)&S.Bsh[nb][sf][sh2*16+8] = b1;
            *(uint4v*)&S.Bsl[nb][sf][sh2*16]   = b2;
            *(uint4v*)&S.Bsl[nb][sf][sh2*16+8] = b3;
        }
    }
    float uval[2][4], svv[4];
    #pragma unroll
    for (int i = 0; i < 2; ++i)
        #pragma unroll
        for (int reg = 0; reg < 4; ++reg)
            uval[i][reg] = uj[kh*64 + wr*32 + i*16 + kg*4 + reg];
    #pragma unroll
    for (int j2 = 0; j2 < 4; ++j2) svv[j2] = sv[wc*64 + j2*16 + r16];
    __syncthreads();
    #pragma unroll
    for (int i = 0; i < 2; ++i)
        #pragma unroll
        for (int j2 = 0; j2 < 4; ++j2)
            #pragma unroll
            for (int reg = 0; reg < 4; ++reg)
                T[wr*32 + i*16 + kg*4 + reg][wc*64 + j2*16 + r16]
                    = SCALE*(acc[i][j2][reg] + uval[i][reg]*svv[j2]);
    __syncthreads();
    {
        int f2 = tid >> 1, half = tid & 1;
        unsigned ph[16], pl[16];
        #pragma unroll
        for (int i = 0; i < 32; i += 2) {
            float v0 = T[half*32 + i][f2];
            float v1 = T[half*32 + i + 1][f2];
            pack_hl(v0, v1, ph[i>>1], pl[i>>1]);
        }
        size_t ob = ((size_t)b*F + f2)*F + kh*64 + half*32;
        store16u(&Mth[ob], ph);
        store16u(&Mtl[ob], pl);
    }
}

__device__ void body_mid(int tblk, int b,
    short* __restrict__ Vbh, short* __restrict__ Vbl,
    const short* __restrict__ Mth, const short* __restrict__ Mtl,
    const float* __restrict__ rm,
    const float* __restrict__ glj, const float* __restrict__ blj, int doLN,
    short* __restrict__ OTh, short* __restrict__ OTl,
    float* __restrict__ spartN, SMem& Smem)
{
    int t0 = tblk * 64;
    MidS& S = *(MidS*)Smem.buf;
    float (*T)[132] = (float(*)[132])Smem.buf;

    int tid = threadIdx.x;
    int lane = tid & 63, wid = tid >> 6;
    int wr = wid >> 1, wc = wid & 1;
    int r16 = lane & 15, kg = lane >> 4;
    int st = tid >> 2, sq = tid & 3;
    int sf = tid >> 1, sh2 = tid & 1;

    const short* pah = Vbh + ((size_t)b*T2 + t0 + st)*F + sq*8;
    const short* pal = Vbl + ((size_t)b*T2 + t0 + st)*F + sq*8;
    const short* pbh = Mth + ((size_t)b*F + sf)*F + sh2*16;
    const short* pbl = Mtl + ((size_t)b*F + sf)*F + sh2*16;

    f32x4 acc[2][4];
    #pragma unroll
    for (int i = 0; i < 2; ++i)
        #pragma unroll
        for (int j2 = 0; j2 < 4; ++j2)
            acc[i][j2] = (f32x4){0.f,0.f,0.f,0.f};

    {
        *(uint4v*)&S.Ash[0][st][sq*8]      = *(const uint4v*)pah;
        *(uint4v*)&S.Asl[0][st][sq*8]      = *(const uint4v*)pal;
        *(uint4v*)&S.Bsh[0][sf][sh2*16]    = *(const uint4v*)pbh;
        *(uint4v*)&S.Bsh[0][sf][sh2*16+8]  = *(const uint4v*)(pbh + 8);
        *(uint4v*)&S.Bsl[0][sf][sh2*16]    = *(const uint4v*)pbl;
        *(uint4v*)&S.Bsl[0][sf][sh2*16+8]  = *(const uint4v*)(pbl + 8);
    }
    #pragma unroll
    for (int ks = 0; ks < 4; ++ks) {
        int cur = ks & 1;
        uint4v a0, a1, b0, b1, b2, b3;
        if (ks < 3) {
            int ko = (ks+1)*32;
            a0 = *(const uint4v*)(pah + ko); a1 = *(const uint4v*)(pal + ko);
            b0 = *(const uint4v*)(pbh + ko); b1 = *(const uint4v*)(pbh + ko + 8);
            b2 = *(const uint4v*)(pbl + ko); b3 = *(const uint4v*)(pbl + ko + 8);
        }
        __syncthreads();
        bf16x8 ah[2], al[2], bh[4], bl[4];
        #pragma unroll
        for (int i = 0; i < 2; ++i) {
            ah[i] = *(const bf16x8*)&S.Ash[cur][wr*32 + i*16 + r16][kg*8];
            al[i] = *(const bf16x8*)&S.Asl[cur][wr*32 + i*16 + r16][kg*8];
        }
        #pragma unroll
        for (int j2 = 0; j2 < 4; ++j2) {
            bh[j2] = *(const bf16x8*)&S.Bsh[cur][wc*64 + j2*16 + r16][kg*8];
            bl[j2] = *(const bf16x8*)&S.Bsl[cur][wc*64 + j2*16 + r16][kg*8];
        }
        #pragma unroll
        for (int i = 0; i < 2; ++i)
            #pragma unroll
            for (int j2 = 0; j2 < 4; ++j2) {
                acc[i][j2] = __builtin_amdgcn_mfma_f32_16x16x32_bf16(ah[i], bh[j2], acc[i][j2], 0,0,0);
                acc[i][j2] = __builtin_amdgcn_mfma_f32_16x16x32_bf16(al[i], bh[j2], acc[i][j2], 0,0,0);
                acc[i][j2] = __builtin_amdgcn_mfma_f32_16x16x32_bf16(ah[i], bl[j2], acc[i][j2], 0,0,0);
            }
        if (ks < 3) {
            int nb = cur ^ 1;
            *(uint4v*)&S.Ash[nb][st][sq*8]     = a0;
            *(uint4v*)&S.Asl[nb][st][sq*8]     = a1;
            *(uint4v*)&S.Bsh[nb][sf][sh2*16]   = b0;
            *(uint4v*)&S.Bsh[nb][sf][sh2*16+8] = b1;
            *(uint4v*)&S.Bsl[nb][sf][sh2*16]   = b2;
            *(uint4v*)&S.Bsl[nb][sf][sh2*16+8] = b3;
        }
    }
    float rv[4];
    #pragma unroll
    for (int j2 = 0; j2 < 4; ++j2) rv[j2] = rm[b*F + wc*64 + j2*16 + r16];
    __syncthreads();
    #pragma unroll
    for (int i = 0; i < 2; ++i)
        #pragma unroll
        for (int j2 = 0; j2 < 4; ++j2)
            #pragma unroll
            for (int reg = 0; reg < 4; ++reg)
                T[wr*32 + i*16 + kg*4 + reg][wc*64 + j2*16 + r16]
                    = acc[i][j2][reg] + rv[j2];
    __syncthreads();

    if (doLN) {
        int r = tid >> 2, qd = tid & 3;
        float v[32];
        #pragma unroll
        for (int i = 0; i < 32; i += 4)
            *(float4*)&v[i] = *(const float4*)&T[r][qd*32 + i];
        float s = 0.f;
        #pragma unroll
        for (int i = 0; i < 32; ++i) s += v[i];
        s += __shfl_xor(s, 1); s += __shfl_xor(s, 2);
        float mu = s * (1.0f/128.0f);
        float dv = 0.f;
        #pragma unroll
        for (int i = 0; i < 32; ++i) { float d = v[i] - mu; dv = fmaf(d, d, dv); }
        dv += __shfl_xor(dv, 1); dv += __shfl_xor(dv, 2);
        float rs = rsqrtf(dv * (1.0f/128.0f) + EPS);

        short hb[32], lb[32];
        {
            const short* rh = Vbh + ((size_t)b*T2 + t0 + r)*F + qd*32;
            const short* rl = Vbl + ((size_t)b*T2 + t0 + r)*F + qd*32;
            #pragma unroll
            for (int i = 0; i < 32; i += 8) {
                *(uint4v*)&hb[i] = *(const uint4v*)(rh + i);
                *(uint4v*)&lb[i] = *(const uint4v*)(rl + i);
            }
        }
        float gv[32], bv2[32];
        #pragma unroll
        for (int i = 0; i < 32; i += 4) {
            *(float4*)&gv[i]  = *(const float4*)&glj[qd*32 + i];
            *(float4*)&bv2[i] = *(const float4*)&blj[qd*32 + i];
        }
        unsigned ph[16], pl[16];
        #pragma unroll
        for (int i = 0; i < 32; i += 2) {
            float res0 = bf2f((unsigned short)hb[i])   + bf2f((unsigned short)lb[i]);
            float res1 = bf2f((unsigned short)hb[i+1]) + bf2f((unsigned short)lb[i+1]);
            float o0 = (v[i]   - mu)*rs*gv[i]   + bv2[i]   + res0;
            float o1 = (v[i+1] - mu)*rs*gv[i+1] + bv2[i+1] + res1;
            T[r][qd*32+i] = o0; T[r][qd*32+i+1] = o1;
            pack_hl(o0, o1, ph[i>>1], pl[i>>1]);
        }
        size_t ob = ((size_t)b*T2 + t0 + r)*F + qd*32;
        store16u(&Vbh[ob], ph);
        store16u(&Vbl[ob], pl);
        __syncthreads();
    }
    {
        int f2 = tid >> 1, half = tid & 1;
        float sacc = 0.f;
        unsigned ph[16], pl[16];
        #pragma unroll
        for (int i = 0; i < 32; i += 2) {
            float v0 = T[half*32 + i][f2];
            float v1 = T[half*32 + i + 1][f2];
            sacc += v0 + v1;
            pack_hl(v0, v1, ph[i>>1], pl[i>>1]);
        }
        size_t ob = ((size_t)b*F + f2)*T2 + t0 + half*32;
        store16u(&OTh[ob], ph);
        store16u(&OTl[ob], pl);
        if (doLN)
            spartN[((size_t)b*100 + tblk*2 + half)*128 + f2] = sacc;
    }
}

// =================== merged kernels (real work + MLP helpers) ==============
__global__ __launch_bounds__(256, 2) void k_apply_gsym(
    const float* xy, const float* g0, const float* b0, const float* lnpart,
    short* Vbh, short* Vbl, short* Vbth, short* Vbtl,
    short* xyTh, short* xyTl, float* spartV, float* s2part, float* Gpart,
    int tile0,
    const float* uv, const float* kb2, const float* kW3, const float* kb3,
    const float* fb2, const float* fW3, const float* fb3,
    const short* AhF, const short* AlF, short* W2h)
{
    __shared__ SMem S;
    int jb = blockIdx.x;
    if (jb >= 400) {
        body_mlp(tile0 + (jb - 400)*20, uv, kb2, kW3, kb3, fb2, fW3, fb3,
                 AhF, AlF, W2h);
        return;
    }
    if (jb < 200) {
        int tgrp = jb % 25, b = jb / 25;
        body_apply(tgrp, b, xy, g0, b0, lnpart, Vbh, Vbl, Vbth, Vbtl, spartV, S);
        __syncthreads();
        body_gsym(tgrp, b, Vbth, Vbtl, Gpart, S);
    } else {
        int t = jb - 200;
        body_xyt(t % 25, t / 25, xy, xyTh, xyTl, s2part, S);
    }
}

__global__ __launch_bounds__(256, 2) void k_gred_m(
    const float* Gpart, int np2, const float* wj,
    short* Gbh, short* Gbl, float* rpart,
    int tile0,
    const float* uv, const float* kb2, const float* kW3, const float* kb3,
    const float* fb2, const float* fW3, const float* fb3,
    const short* AhF, const short* AlF, short* W2h)
{
    int bid = blockIdx.x;
    if (bid >= 64) {
        body_mlp(tile0 + (bid - 64)*20, uv, kb2, kW3, kb3, fb2, fW3, fb3,
                 AhF, AlF, W2h);
        return;
    }
    body_gred(bid, np2, Gpart, wj, Gbh, Gbl, rpart);
}

__global__ __launch_bounds__(256, 2) void k_cm_m(
    const short* Gbh, const short* Gbl, const float* spart, int np,
    const short* Pjh, const short* Pjl, const float* uj, const float* cj,
    const float* rpart, short* Mth, short* Mtl, float* rm,
    int tile0,
    const float* uv, const float* kb2, const float* kW3, const float* kb3,
    const float* fb2, const float* fW3, const float* fb3,
    const short* AhF, const short* AlF, short* W2h)
{
    __shared__ SMem S;
    int bid = blockIdx.x;
    if (bid >= 16) {
        body_mlp(tile0 + (bid - 16)*20, uv, kb2, kW3, kb3, fb2, fW3, fb3,
                 AhF, AlF, W2h);
        return;
    }
    body_computeM(bid, Gbh, Gbl, spart, np, Pjh, Pjl, uj, cj, rpart,
                  Mth, Mtl, rm, S);
}

// mode: 0 = gsym after mid, 1 = gasym (j==2->3), 2 = none (final mid)
__global__ __launch_bounds__(256, 2) void k_mid_gsym(
    short* Vbh, short* Vbl, const short* Mth, const short* Mtl,
    const float* rm, const float* glj, const float* blj, int doLN,
    short* OTh, short* OTl, float* spartN,
    int mode, const short* xyTh, const short* xyTl, float* Gpart,
    int tile0,
    const float* uv, const float* kb2, const float* kW3, const float* kb3,
    const float* fb2, const float* fW3, const float* fb3,
    const short* AhF, const short* AlF, short* W2h)
{
    __shared__ SMem S;
    int bid = blockIdx.x;
    if (bid >= 200) {
        body_mlp(tile0 + (bid - 200)*20, uv, kb2, kW3, kb3, fb2, fW3, fb3,
                 AhF, AlF, W2h);
        return;
    }
    int s = bid % 25, b = bid / 25;
    #pragma unroll
    for (int pass = 0; pass < 2; ++pass) {
        body_mid(s*2 + pass, b, Vbh, Vbl, Mth, Mtl, rm, glj, blj, doLN,
                 OTh, OTl, spartN, S);
        __syncthreads();
    }
    if (mode == 0) {
        body_gsym(s, b, OTh, OTl, Gpart, S);
    } else if (mode == 1) {
        int nks = (s < 12) ? 4 : ((s == 12) ? 2 : 0);
        if (nks) body_gasym2(s, b, nks, xyTh, xyTl, OTh, OTl, Gpart, S);
    }
}

// ------------- out = DXDY * W2(bf16) @ U(bf16 h/l), MFMA -------------------
__global__ __launch_bounds__(256) void k_gout(
    const short* __restrict__ W2h,
    const short* __restrict__ Uth, const short* __restrict__ Utl,
    float* __restrict__ out)
{
    int job = blockIdx.x;
    int nt = job % 25, b = job / 25;
    int n0 = nt * 64;
    __shared__ GOutS S;

    int tid = threadIdx.x;
    int lane = tid & 63, wid = tid >> 6;
    int wr = wid >> 1, wc = wid & 1;
    int r16 = lane & 15, kg = lane >> 4;
    int srow = tid >> 2, sq2 = tid & 3;
    int sf = tid >> 1, sh2 = tid & 1;

    const short* ap  = W2h + (size_t)(n0 + srow)*T2 + sq2*8;
    const short* bhp = Uth + ((size_t)b*F + sf)*T2 + sh2*16;
    const short* blp = Utl + ((size_t)b*F + sf)*T2 + sh2*16;

    f32x4 acc[2][4];
    #pragma unroll
    for (int i = 0; i < 2; ++i)
        #pragma unroll
        for (int j2 = 0; j2 < 4; ++j2)
            acc[i][j2] = (f32x4){0.f,0.f,0.f,0.f};

    {
        *(uint4v*)&S.As[0][srow][sq2*8]  = *(const uint4v*)ap;
        *(uint4v*)&S.Bh[0][sf][sh2*16]   = *(const uint4v*)bhp;
        *(uint4v*)&S.Bh[0][sf][sh2*16+8] = *(const uint4v*)(bhp + 8);
        *(uint4v*)&S.Bl[0][sf][sh2*16]   = *(const uint4v*)blp;
        *(uint4v*)&S.Bl[0][sf][sh2*16+8] = *(const uint4v*)(blp + 8);
    }
    for (int it = 0; it < 100; ++it) {
        int cur = it & 1;
        uint4v ra, b0, b1, b2, b3;
        if (it < 99) {
            int ko = (it + 1) * 32;
            ra = *(const uint4v*)(ap + ko);
            b0 = *(const uint4v*)(bhp + ko); b1 = *(const uint4v*)(bhp + ko + 8);
            b2 = *(const uint4v*)(blp + ko); b3 = *(const uint4v*)(blp + ko + 8);
        }
        __syncthreads();
        bf16x8 ah[2], bh[4], bl[4];
        #pragma unroll
        for (int i = 0; i < 2; ++i)
            ah[i] = *(const bf16x8*)&S.As[cur][wr*32 + i*16 + r16][kg*8];
        #pragma unroll
        for (int j2 = 0; j2 < 4; ++j2) {
            bh[j2] = *(const bf16x8*)&S.Bh[cur][wc*64 + j2*16 + r16][kg*8];
            bl[j2] = *(const bf16x8*)&S.Bl[cur][wc*64 + j2*16 + r16][kg*8];
        }
        #pragma unroll
        for (int i = 0; i < 2; ++i)
            #pragma unroll
            for (int j2 = 0; j2 < 4; ++j2) {
                acc[i][j2] = __builtin_amdgcn_mfma_f32_16x16x32_bf16(ah[i], bh[j2], acc[i][j2], 0,0,0);
                acc[i][j2] = __builtin_amdgcn_mfma_f32_16x16x32_bf16(ah[i], bl[j2], acc[i][j2], 0,0,0);
            }
        if (it < 99) {
            int nb = cur ^ 1;
            *(uint4v*)&S.As[nb][srow][sq2*8]  = ra;
            *(uint4v*)&S.Bh[nb][sf][sh2*16]   = b0;
            *(uint4v*)&S.Bh[nb][sf][sh2*16+8] = b1;
            *(uint4v*)&S.Bl[nb][sf][sh2*16]   = b2;
            *(uint4v*)&S.Bl[nb][sf][sh2*16+8] = b3;
        }
    }
    #pragma unroll
    for (int i = 0; i < 2; ++i)
        #pragma unroll
        for (int j2 = 0; j2 < 4; ++j2)
            #pragma unroll
            for (int reg = 0; reg < 4; ++reg) {
                int n_out = n0 + wr*32 + i*16 + kg*4 + reg;
                int f_out = wc*64 + j2*16 + r16;
                out[((size_t)b*NT + n_out)*F + f_out] = DXDY * acc[i][j2][reg];
            }
}

// =============================== launcher ==================================
extern "C" void kernel_launch(void* const* d_in, const int* in_sizes, int n_in,
                              void* d_out, int out_size, void* d_ws, size_t ws_size,
                              hipStream_t stream)
{
    const float* xy  = (const float*)d_in[0];
    const float* kW1 = (const float*)d_in[1];
    const float* kb1 = (const float*)d_in[2];
    const float* kW2 = (const float*)d_in[3];
    const float* kb2 = (const float*)d_in[4];
    const float* kW3 = (const float*)d_in[5];
    const float* kb3 = (const float*)d_in[6];
    const float* fW1 = (const float*)d_in[7];
    const float* fb1 = (const float*)d_in[8];
    const float* fW2 = (const float*)d_in[9];
    const float* fb2 = (const float*)d_in[10];
    const float* fW3 = (const float*)d_in[11];
    const float* fb3 = (const float*)d_in[12];
    const float* Wq  = (const float*)d_in[13];
    const float* bq  = (const float*)d_in[14];
    const float* Wk  = (const float*)d_in[15];
    const float* bk  = (const float*)d_in[16];
    const float* g0  = (const float*)d_in[17];
    const float* b0  = (const float*)d_in[18];
    const float* gl  = (const float*)d_in[19];
    const float* bl  = (const float*)d_in[20];
    float* out = (float*)d_out;

    short* W2h  = (short*)d_ws;                 // 5,120,000
    short* Vbh  = W2h  + 5120000;               // 3,276,800
    short* Vbl  = Vbh  + 3276800;
    short* Vbth = Vbl  + 3276800;
    short* Vbtl = Vbth + 3276800;
    short* xyTh = Vbtl + 3276800;               // 1,638,400
    short* xyTl = xyTh + 1638400;
    short* Uth  = xyTl + 1638400;               // 3,276,800
    short* Utl  = Uth  + 3276800;
    short* Pnh  = Utl  + 3276800;               // 65,536
    short* Pnl  = Pnh  + 65536;
    short* Mth  = Pnl  + 65536;                 // 131,072
    short* Mtl  = Mth  + 131072;
    short* Gbh  = Mtl  + 131072;                // 131,072
    short* Gbl  = Gbh  + 131072;
    short* AhF  = Gbl  + 131072;                // 4,096
    short* AlF  = AhF  + 4096;
    float* Gpart  = (float*)(AlF + 4096);       // 3,276,800 f
    float* uB     = Gpart + 3276800;            // 512
    float* wB     = uB + 512;                   // 512
    float* cB     = wB + 512;                   // 4
    float* lnpart = cB + 4;                     // 400
    float* rpart  = lnpart + 400;               // 1024
    float* rm     = rpart + 1024;               // 1024
    float* spartV = rm + 1024;                  // 102,400
    float* s2part = spartV + 102400;            // 51,200
    float* uvT    = s2part + 51200;             // 204,800

    k_prep<<<dim3(437), 256, 0, stream>>>(kW2, fW2, AhF, AlF,
                                          kW1, kb1, fW1, fb1, uvT,
                                          xy, lnpart,
                                          Wq, bq, Wk, bk, Pnh, Pnl, uB, wB, cB);

    // MLP tile budget: apply 800 blocks (16,000 tiles);
    // per layer: gred 400 (8,000), cm 400 (8,000), mid 1000 (20,000)
    k_apply_gsym<<<dim3(1200), 256, 0, stream>>>(
        xy, g0, b0, lnpart, Vbh, Vbl, Vbth, Vbtl,
        xyTh, xyTl, spartV, s2part, Gpart,
        /*tile0=*/0,
        uvT, kb2, kW3, kb3, fb2, fW3, fb3, AhF, AlF, W2h);

    for (int j = 0; j < 4; ++j) {
        int np2  = (j < 3) ? 25 : 13;
        int np_s = (j < 3) ? 100 : 50;
        const float* sp = (j < 3) ? spartV : s2part;
        int base = 16000 + j*36000;

        k_gred_m<<<dim3(464), 256, 0, stream>>>(
            Gpart, np2, wB + j*128, Gbh, Gbl, rpart,
            base,
            uvT, kb2, kW3, kb3, fb2, fW3, fb3, AhF, AlF, W2h);

        k_cm_m<<<dim3(416), 256, 0, stream>>>(
            Gbh, Gbl, sp, np_s,
            Pnh + (size_t)j*16384, Pnl + (size_t)j*16384,
            uB + j*128, cB + j, rpart, Mth, Mtl, rm,
            base + 8000,
            uvT, kb2, kW3, kb3, fb2, fW3, fb3, AhF, AlF, W2h);

        if (j < 2) {
            k_mid_gsym<<<dim3(1200), 256, 0, stream>>>(
                Vbh, Vbl, Mth, Mtl, rm, gl + j*128, bl + j*128, 1,
                Vbth, Vbtl, spartV, 0, xyTh, xyTl, Gpart,
                base + 16000,
                uvT, kb2, kW3, kb3, fb2, fW3, fb3, AhF, AlF, W2h);
        } else if (j == 2) {
            k_mid_gsym<<<dim3(1200), 256, 0, stream>>>(
                Vbh, Vbl, Mth, Mtl, rm, gl + j*128, bl + j*128, 1,
                Vbth, Vbtl, spartV, 1, xyTh, xyTl, Gpart,
                base + 16000,
                uvT, kb2, kW3, kb3, fb2, fW3, fb3, AhF, AlF, W2h);
        } else {
            k_mid_gsym<<<dim3(1200), 256, 0, stream>>>(
                Vbh, Vbl, Mth, Mtl, rm, gl, bl, 0,
                Uth, Utl, spartV, 2, xyTh, xyTl, Gpart,
                base + 16000,
                uvT, kb2, kW3, kb3, fb2, fW3, fb3, AhF, AlF, W2h);
        }
    }

    k_gout<<<dim3(200), 256, 0, stream>>>(W2h, Uth, Utl, out);
}

// Round 10
// 520.589 us; speedup vs baseline: 2.1036x; 1.0105x over previous
//
#include <hip/hip_runtime.h>
#include <math.h>

#define NGRID 40
#define NT    1600
#define T2    3200
#define F     128
#define NB    8
#define EPS   1e-5f

__device__ __constant__ const float kINV39 = 1.0f/39.0f;
constexpr float DXDY  = (1.0f/39.0f)*(1.0f/39.0f);
constexpr float SCALE = DXDY * 0.125f;   // DXDY / sqrt(64)

typedef __attribute__((ext_vector_type(8))) short bf16x8;
typedef __attribute__((ext_vector_type(4))) float f32x4;
typedef __attribute__((ext_vector_type(4))) unsigned uint4v;

__device__ __forceinline__ unsigned bitu(float f){ return __builtin_bit_cast(unsigned,f); }
__device__ __forceinline__ float bitf(unsigned u){ return __builtin_bit_cast(float,u); }
__device__ __forceinline__ unsigned short f2bf(float f) {
    unsigned u = bitu(f);
    unsigned r = u + 0x7FFFu + ((u >> 16) & 1u);
    return (unsigned short)(r >> 16);
}
__device__ __forceinline__ float bf2f(unsigned short h) { return bitf(((unsigned)h) << 16); }

__device__ __forceinline__ void pack_hl(float a, float b, unsigned &h, unsigned &l) {
    unsigned ua = bitu(a), ub = bitu(b);
    h = __builtin_amdgcn_perm(ub, ua, 0x07060302u);
    float ra = a - bitf(ua & 0xffff0000u);
    float rb = b - bitf(ub & 0xffff0000u);
    l = __builtin_amdgcn_perm(bitu(rb), bitu(ra), 0x07060302u);
}
__device__ __forceinline__ void store8u(short* dst, const unsigned* p) {
    uint4v v0 = {p[0], p[1], p[2], p[3]};
    uint4v v1 = {p[4], p[5], p[6], p[7]};
    *(uint4v*)dst = v0;
    *(uint4v*)(dst + 8) = v1;
}
__device__ __forceinline__ void store16u(short* dst, const unsigned* p) {
    store8u(dst, p);
    store8u(dst + 16, p + 8);
}

// shared-memory union
struct SMem {
    __align__(16) char buf[61440];
    float sv[128];
};
struct GSymS  { short Sh[2][128][40], Sl[2][128][40]; };
struct GAs2S  { short Ahs[128][40], Als[128][40], Bhs[128][40], Bls[128][40]; };
struct CMS    { short Psh[2][64][40], Psl[2][64][40], Bsh[2][128][40], Bsl[2][128][40]; };
struct MidS   { short Ash[2][64][40], Asl[2][64][40], Bsh[2][128][40], Bsl[2][128][40]; };
struct GOutS  { short As[2][64][40], Bh[2][128][40], Bl[2][128][40]; };

// =================== fused prep: uv | ln0_part | P | frag ==================
// P-part (jobs 400-431): LDS-staged, coalesced; FMA order identical to the
// original scattered-load version (h outer, d inner) -> bit-identical P/u/w/c.
__global__ __launch_bounds__(256) void k_prep(
    const float* __restrict__ kW2, const float* __restrict__ fW2,
    short* __restrict__ Ah, short* __restrict__ Al,
    const float* __restrict__ kW1, const float* __restrict__ kb1,
    const float* __restrict__ fW1, const float* __restrict__ fb1,
    float* __restrict__ uv,
    const float* __restrict__ xy, float* __restrict__ lnpart,
    const float* __restrict__ Wq, const float* __restrict__ bq,
    const float* __restrict__ Wk, const float* __restrict__ bk,
    short* __restrict__ Pnh, short* __restrict__ Pnl,
    float* __restrict__ uB, float* __restrict__ wB, float* __restrict__ cB)
{
    __shared__ float ss[4], qs[4];
    __shared__ __align__(16) float Wqs[64][132];   // [d][k] transposed
    __shared__ __align__(16) float Wks[16][68];    // [kp_local][d]
    __shared__ float bqs[512], bks[512];
    int job = blockIdx.x;
    int tid = threadIdx.x;
    if (job < 200) {                       // ---- uv tables
        int idx = job * 256 + tid;
        int node = idx >> 5, o = idx & 31;
        float x0 = (float)(node / NGRID) * kINV39;
        float x1 = (float)(node % NGRID) * kINV39;
        uv[idx]          = fmaf(kW1[o], x0, fmaf(kW1[32+o], x1, kb1[o]));
        uv[51200 + idx]  = fmaf(kW1[64+o], x0, kW1[96+o]*x1);
        uv[102400 + idx] = fmaf(fW1[o], x0, fmaf(fW1[32+o], x1, fb1[o]));
        uv[153600 + idx] = fmaf(fW1[64+o], x0, fW1[96+o]*x1);
        return;
    }
    if (job < 400) {                       // ---- ln0 partial sums
        int t = job - 200;
        int b = t & 7, blk = t >> 3;
        const float4* p = (const float4*)xy + (size_t)b*102400 + blk*4096 + tid;
        float s = 0.f, q = 0.f;
        #pragma unroll
        for (int i = 0; i < 16; ++i) {
            float4 v = p[i*256];
            s += (v.x + v.y) + (v.z + v.w);
            q += (v.x*v.x + v.y*v.y) + (v.z*v.z + v.w*v.w);
        }
        #pragma unroll
        for (int off = 32; off >= 1; off >>= 1) {
            s += __shfl_xor(s, off);
            q += __shfl_xor(q, off);
        }
        int wid = tid >> 6;
        if ((tid & 63) == 0) { ss[wid] = s; qs[wid] = q; }
        __syncthreads();
        if (tid == 0) {
            lnpart[((size_t)b*25 + blk)*2 + 0] = ss[0]+ss[1]+ss[2]+ss[3];
            lnpart[((size_t)b*25 + blk)*2 + 1] = qs[0]+qs[1]+qs[2]+qs[3];
        }
        return;
    }
    if (job < 432) {                       // ---- P (h/l), u, w, c  (LDS-staged)
        int t = job - 400;
        int j = t >> 3, part = t & 7;
        const float* wq = Wq + (size_t)j*8*F*64;
        const float* wk = Wk + (size_t)j*8*F*64;
        const float* bqj = bq + j*512;
        const float* bkj = bk + j*512;
        // stage biases once
        *(float2*)&bqs[tid*2] = *(const float2*)&bqj[tid*2];
        *(float2*)&bks[tid*2] = *(const float2*)&bkj[tid*2];

        int kp_l = tid >> 4, q = tid & 15;
        int k0 = q * 8;
        float acc[8] = {0,0,0,0,0,0,0,0};
        float ua = 0.f, wa = 0.f;

        for (int h = 0; h < 8; ++h) {
            __syncthreads();
            {   // stage Wq[j,h] transposed [d][k]; coalesced global float4 reads
                int k = tid >> 1, d0 = (tid & 1) * 32;
                const float* src = wq + ((size_t)h*F + k)*64 + d0;
                #pragma unroll
                for (int i = 0; i < 32; i += 4) {
                    float4 v = *(const float4*)&src[i];
                    Wqs[d0+i][k]   = v.x; Wqs[d0+i+1][k] = v.y;
                    Wqs[d0+i+2][k] = v.z; Wqs[d0+i+3][k] = v.w;
                }
            }
            {   // stage Wk[j,h] rows [part*16, part*16+16)
                int row = tid >> 4, d0 = (tid & 15) * 4;
                *(float4*)&Wks[row][d0] =
                    *(const float4*)&wk[((size_t)h*F + part*16 + row)*64 + d0];
            }
            __syncthreads();
            // P tile: same (h outer, d inner) order as original
            for (int d = 0; d < 64; d += 4) {
                float4 bv4 = *(const float4*)&Wks[kp_l][d];
                float bvs[4] = {bv4.x, bv4.y, bv4.z, bv4.w};
                #pragma unroll
                for (int dd = 0; dd < 4; ++dd) {
                    float bvv = bvs[dd];
                    float4 a0 = *(const float4*)&Wqs[d+dd][k0];
                    float4 a1 = *(const float4*)&Wqs[d+dd][k0+4];
                    acc[0] = fmaf(a0.x, bvv, acc[0]);
                    acc[1] = fmaf(a0.y, bvv, acc[1]);
                    acc[2] = fmaf(a0.z, bvv, acc[2]);
                    acc[3] = fmaf(a0.w, bvv, acc[3]);
                    acc[4] = fmaf(a1.x, bvv, acc[4]);
                    acc[5] = fmaf(a1.y, bvv, acc[5]);
                    acc[6] = fmaf(a1.z, bvv, acc[6]);
                    acc[7] = fmaf(a1.w, bvv, acc[7]);
                }
            }
            // u (lanes 0-15): k = part*16 + tid, same order
            if (tid < 16) {
                int k = part*16 + tid;
                for (int d = 0; d < 64; ++d)
                    ua = fmaf(Wqs[d][k], bks[h*64 + d], ua);
            } else if (tid < 32) {
                // w (lanes 16-31): kp = part*16 + (tid-16), same order
                int row = tid - 16;
                for (int d = 0; d < 64; ++d)
                    wa = fmaf(Wks[row][d], bqs[h*64 + d], wa);
            }
        }
        if (tid < 16) {
            uB[j*128 + part*16 + tid] = ua;
        } else if (tid < 32) {
            wB[j*128 + part*16 + (tid - 16)] = wa;
        } else if (tid == 32 && part == 0) {
            float a = 0.f;
            for (int i = 0; i < 512; ++i) a = fmaf(bqs[i], bks[i], a);
            cB[j] = a;
        }
        int kp = part*16 + kp_l;
        #pragma unroll
        for (int i = 0; i < 8; ++i) {
            float val = acc[i];
            short hs = (short)(bitu(val) >> 16);
            float rem = val - bitf(bitu(val) & 0xffff0000u);
            short ls = (short)(bitu(rem) >> 16);
            Pnh[((size_t)j*128 + k0 + i)*128 + kp] = hs;
            Pnl[((size_t)j*128 + k0 + i)*128 + kp] = ls;
        }
        return;
    }
    {                                      // ---- MLP W2-layer fragments
        int oc = tid >> 6, lane = tid & 63;
        int row = lane & 15;
        int k0 = (lane >> 4) * 8;
        #pragma unroll
        for (int mlp = 0; mlp < 2; ++mlp) {
            const float* W2 = mlp ? fW2 : kW2;
            #pragma unroll
            for (int i = 0; i < 8; ++i) {
                float w = W2[(size_t)(k0 + i) * 64 + oc * 16 + row];
                unsigned short h = f2bf(w);
                Ah[((mlp*4 + oc)*64 + lane)*8 + i] = (short)h;
                Al[((mlp*4 + oc)*64 + lane)*8 + i] = (short)f2bf(w - bf2f(h));
            }
        }
    }
}

// ============ MLP helper body: 20 tiles per block (5 per wave) =============
__device__ void body_mlp(int tile0,
    const float* __restrict__ uv,
    const float* __restrict__ kb2, const float* __restrict__ kW3,
    const float* __restrict__ kb3,
    const float* __restrict__ fb2, const float* __restrict__ fW3,
    const float* __restrict__ fb3,
    const short* __restrict__ Ah, const short* __restrict__ Al,
    short* __restrict__ W2h)
{
    int tid = threadIdx.x;
    int wid = tid >> 6, lane = tid & 63;
    int c = lane & 15, kg = lane >> 4;
    int k0 = kg * 8;

    bf16x8 AHf[2][4], ALf[2][4];
    float4 B2f[2][4], W3f[2][4];
    #pragma unroll
    for (int mlp = 0; mlp < 2; ++mlp) {
        const float* b2p = mlp ? fb2 : kb2;
        const float* w3p = mlp ? fW3 : kW3;
        #pragma unroll
        for (int oc = 0; oc < 4; ++oc) {
            AHf[mlp][oc] = *(const bf16x8*)&Ah[((mlp*4 + oc)*64 + lane)*8];
            ALf[mlp][oc] = *(const bf16x8*)&Al[((mlp*4 + oc)*64 + lane)*8];
            B2f[mlp][oc] = *(const float4*)&b2p[oc*16 + kg*4];
            W3f[mlp][oc] = *(const float4*)&w3p[oc*16 + kg*4];
        }
    }
    float bias0 = kb3[0], bias1 = fb3[0];

    int t = tile0 + wid*5;
    for (int it = 0; it < 5; ++it, ++t) {
        int n = t / 100;
        int mt = t - n*100;
        int m = mt*16 + c;
        float res0, res1;
        #pragma unroll
        for (int mlp = 0; mlp < 2; ++mlp) {
            const float* up = uv + mlp*102400 + n*32 + k0;
            const float* vp = uv + mlp*102400 + 51200 + m*32 + k0;
            float4 ua = *(const float4*)up;
            float4 ub = *(const float4*)(up + 4);
            float4 va = *(const float4*)vp;
            float4 vb = *(const float4*)(vp + 4);
            float h[8] = {ua.x+va.x, ua.y+va.y, ua.z+va.z, ua.w+va.w,
                          ub.x+vb.x, ub.y+vb.y, ub.z+vb.z, ub.w+vb.w};
            #pragma unroll
            for (int i = 0; i < 8; ++i) h[i] = fmaxf(h[i], 0.01f*h[i]);
            unsigned bhp[4], blp[4];
            #pragma unroll
            for (int p = 0; p < 4; ++p)
                pack_hl(h[2*p], h[2*p+1], bhp[p], blp[p]);
            uint4v bhv = {bhp[0], bhp[1], bhp[2], bhp[3]};
            uint4v blv = {blp[0], blp[1], blp[2], blp[3]};
            bf16x8 bh = __builtin_bit_cast(bf16x8, bhv);
            bf16x8 bl = __builtin_bit_cast(bf16x8, blv);
            float acc = 0.f;
            #pragma unroll
            for (int oc = 0; oc < 4; ++oc) {
                f32x4 d = {B2f[mlp][oc].x, B2f[mlp][oc].y,
                           B2f[mlp][oc].z, B2f[mlp][oc].w};
                d = __builtin_amdgcn_mfma_f32_16x16x32_bf16(AHf[mlp][oc], bh, d, 0, 0, 0);
                d = __builtin_amdgcn_mfma_f32_16x16x32_bf16(ALf[mlp][oc], bh, d, 0, 0, 0);
                d = __builtin_amdgcn_mfma_f32_16x16x32_bf16(AHf[mlp][oc], bl, d, 0, 0, 0);
                float w3v[4] = {W3f[mlp][oc].x, W3f[mlp][oc].y,
                                W3f[mlp][oc].z, W3f[mlp][oc].w};
                #pragma unroll
                for (int r = 0; r < 4; ++r)
                    acc = fmaf(fmaxf(d[r], 0.01f*d[r]), w3v[r], acc);
            }
            if (mlp == 0) res0 = acc; else res1 = acc;
        }
        res0 += __shfl_xor(res0, 16); res0 += __shfl_xor(res0, 32);
        res1 += __shfl_xor(res1, 16); res1 += __shfl_xor(res1, 32);
        if (lane < 16) {
            W2h[(size_t)n*T2 + m]      = (short)f2bf(res0 + bias0);
            W2h[(size_t)n*T2 + NT + m] = (short)f2bf(res1 + bias1);
        }
    }
}

// ====================== phase bodies (verified numerics) ====================
__device__ void body_apply(int tgrp, int b,
    const float* __restrict__ xy, const float* __restrict__ g0,
    const float* __restrict__ b0, const float* __restrict__ lnpart,
    short* __restrict__ Vbh, short* __restrict__ Vbl,
    short* __restrict__ Vbth, short* __restrict__ Vbtl,
    float* __restrict__ spartV, SMem& S)
{
    float s = 0.f, q = 0.f;
    for (int i = 0; i < 25; ++i) {
        s += lnpart[((size_t)b*25 + i)*2 + 0];
        q += lnpart[((size_t)b*25 + i)*2 + 1];
    }
    float mu = s * (1.0f/409600.0f);
    float rs = rsqrtf(q * (1.0f/409600.0f) - mu*mu + EPS);
    float (*T)[132] = (float(*)[132])S.buf;
    int tid = threadIdx.x;
    int r = tid >> 2, qd = tid & 3;
    int f2 = tid >> 1, half = tid & 1;
    #pragma unroll
    for (int p = 0; p < 2; ++p) {
        int t0 = tgrp*128 + p*64;
        {
            int t = t0 + r;
            const float* xp = xy + ((size_t)b*T2 + t)*F + qd*32;
            const float* gp = g0 + (size_t)t*F + qd*32;
            const float* bp = b0 + (size_t)t*F + qd*32;
            unsigned ph[16], pl[16];
            #pragma unroll
            for (int i = 0; i < 32; i += 4) {
                float4 x = *(const float4*)&xp[i];
                float4 g = *(const float4*)&gp[i];
                float4 bb = *(const float4*)&bp[i];
                float o0 = (x.x - mu)*rs*g.x + bb.x;
                float o1 = (x.y - mu)*rs*g.y + bb.y;
                float o2 = (x.z - mu)*rs*g.z + bb.z;
                float o3 = (x.w - mu)*rs*g.w + bb.w;
                T[r][qd*32+i] = o0; T[r][qd*32+i+1] = o1;
                T[r][qd*32+i+2] = o2; T[r][qd*32+i+3] = o3;
                pack_hl(o0, o1, ph[i>>1], pl[i>>1]);
                pack_hl(o2, o3, ph[(i>>1)+1], pl[(i>>1)+1]);
            }
            size_t ob = ((size_t)b*T2 + t)*F + qd*32;
            store16u(&Vbh[ob], ph);
            store16u(&Vbl[ob], pl);
        }
        __syncthreads();
        {
            float sacc = 0.f;
            unsigned ph[16], pl[16];
            #pragma unroll
            for (int i = 0; i < 32; i += 2) {
                float v0 = T[half*32 + i][f2];
                float v1 = T[half*32 + i + 1][f2];
                sacc += v0 + v1;
                pack_hl(v0, v1, ph[i>>1], pl[i>>1]);
            }
            size_t ob = ((size_t)b*F + f2)*T2 + t0 + half*32;
            store16u(&Vbth[ob], ph);
            store16u(&Vbtl[ob], pl);
            spartV[((size_t)b*100 + (tgrp*2+p)*2 + half)*128 + f2] = sacc;
        }
        __syncthreads();
    }
}

__device__ void body_xyt(int tgrp, int b,
    const float* __restrict__ xy,
    short* __restrict__ xyTh, short* __restrict__ xyTl,
    float* __restrict__ s2part, SMem& S)
{
    float (*T)[132] = (float(*)[132])S.buf;
    int tid = threadIdx.x;
    int r = tid >> 2, qd = tid & 3;
    int f2 = tid >> 1, half = tid & 1;
    int t0 = tgrp*64;
    {
        const float* xp = xy + ((size_t)b*T2 + t0 + r)*F + qd*32;
        #pragma unroll
        for (int i = 0; i < 32; i += 4)
            *(float4*)&T[r][qd*32+i] = *(const float4*)&xp[i];
    }
    __syncthreads();
    {
        float sacc = 0.f;
        unsigned ph[16], pl[16];
        #pragma unroll
        for (int i = 0; i < 32; i += 2) {
            float v0 = T[half*32 + i][f2];
            float v1 = T[half*32 + i + 1][f2];
            sacc += v0 + v1;
            pack_hl(v0, v1, ph[i>>1], pl[i>>1]);
        }
        size_t ob = ((size_t)b*F + f2)*1600 + t0 + half*32;
        store16u(&xyTh[ob], ph);
        store16u(&xyTl[ob], pl);
        s2part[((size_t)b*50 + tgrp*2 + half)*128 + f2] = sacc;
    }
}

__device__ void body_gsym(int split, int b,
    const short* __restrict__ Xh, const short* __restrict__ Xl,
    float* __restrict__ Gpart, SMem& Smem)
{
    int t0 = split*128;
    GSymS& S = *(GSymS*)Smem.buf;
    int tid = threadIdx.x;
    int lane = tid & 63, wid = tid >> 6;
    int wr = wid >> 1, wc = wid & 1;
    int r16 = lane & 15, kg = lane >> 4;
    int sf = tid >> 1, th = tid & 1;

    const short* ph_ = Xh + ((size_t)b*F + sf)*T2 + t0 + th*16;
    const short* pl_ = Xl + ((size_t)b*F + sf)*T2 + t0 + th*16;

    f32x4 acc[4][4];
    #pragma unroll
    for (int i = 0; i < 4; ++i)
        #pragma unroll
        for (int j2 = 0; j2 < 4; ++j2)
            acc[i][j2] = (f32x4){0.f,0.f,0.f,0.f};

    {
        uint4v h0 = *(const uint4v*)ph_,      h1 = *(const uint4v*)(ph_ + 8);
        uint4v l0 = *(const uint4v*)pl_,      l1 = *(const uint4v*)(pl_ + 8);
        *(uint4v*)&S.Sh[0][sf][th*16]     = h0; *(uint4v*)&S.Sh[0][sf][th*16+8] = h1;
        *(uint4v*)&S.Sl[0][sf][th*16]     = l0; *(uint4v*)&S.Sl[0][sf][th*16+8] = l1;
    }
    #pragma unroll
    for (int ks = 0; ks < 4; ++ks) {
        int cur = ks & 1;
        uint4v h0, h1, l0, l1;
        if (ks < 3) {
            int ko = (ks+1)*32;
            h0 = *(const uint4v*)(ph_ + ko); h1 = *(const uint4v*)(ph_ + ko + 8);
            l0 = *(const uint4v*)(pl_ + ko); l1 = *(const uint4v*)(pl_ + ko + 8);
        }
        __syncthreads();
        bf16x8 ah[4], al[4], bh[4], bl[4];
        #pragma unroll
        for (int i = 0; i < 4; ++i) {
            ah[i] = *(const bf16x8*)&S.Sh[cur][wr*64 + i*16 + r16][kg*8];
            al[i] = *(const bf16x8*)&S.Sl[cur][wr*64 + i*16 + r16][kg*8];
            bh[i] = *(const bf16x8*)&S.Sh[cur][wc*64 + i*16 + r16][kg*8];
            bl[i] = *(const bf16x8*)&S.Sl[cur][wc*64 + i*16 + r16][kg*8];
        }
        #pragma unroll
        for (int i = 0; i < 4; ++i)
            #pragma unroll
            for (int j2 = 0; j2 < 4; ++j2) {
                acc[i][j2] = __builtin_amdgcn_mfma_f32_16x16x32_bf16(ah[i], bh[j2], acc[i][j2], 0,0,0);
                acc[i][j2] = __builtin_amdgcn_mfma_f32_16x16x32_bf16(al[i], bh[j2], acc[i][j2], 0,0,0);
                acc[i][j2] = __builtin_amdgcn_mfma_f32_16x16x32_bf16(ah[i], bl[j2], acc[i][j2], 0,0,0);
            }
        if (ks < 3) {
            int nb = cur ^ 1;
            *(uint4v*)&S.Sh[nb][sf][th*16]     = h0; *(uint4v*)&S.Sh[nb][sf][th*16+8] = h1;
            *(uint4v*)&S.Sl[nb][sf][th*16]     = l0; *(uint4v*)&S.Sl[nb][sf][th*16+8] = l1;
        }
    }
    __syncthreads();
    size_t gb = ((size_t)b*25 + split)*16384;
    #pragma unroll
    for (int i = 0; i < 4; ++i)
        #pragma unroll
        for (int j2 = 0; j2 < 4; ++j2)
            #pragma unroll
            for (int reg = 0; reg < 4; ++reg)
                Gpart[gb + (size_t)(wr*64 + i*16 + kg*4 + reg)*128 + wc*64 + j2*16 + r16]
                    = acc[i][j2][reg];
}

__device__ void body_gasym2(int split, int b, int nks,
    const short* __restrict__ Ah_, const short* __restrict__ Al_,
    const short* __restrict__ Bh_, const short* __restrict__ Bl_,
    float* __restrict__ Gpart, SMem& Smem)
{
    int t0 = split*128;
    GAs2S& S = *(GAs2S*)Smem.buf;
    int tid = threadIdx.x;
    int lane = tid & 63, wid = tid >> 6;
    int wr = wid >> 1, wc = wid & 1;
    int r16 = lane & 15, kg = lane >> 4;
    int sf = tid >> 1, th = tid & 1;

    const short* pah = Ah_ + ((size_t)b*F + sf)*1600 + t0 + th*16;
    const short* pal = Al_ + ((size_t)b*F + sf)*1600 + t0 + th*16;
    const short* pbh = Bh_ + ((size_t)b*F + sf)*T2   + t0 + th*16;
    const short* pbl = Bl_ + ((size_t)b*F + sf)*T2   + t0 + th*16;

    f32x4 acc[4][4];
    #pragma unroll
    for (int i = 0; i < 4; ++i)
        #pragma unroll
        for (int j2 = 0; j2 < 4; ++j2)
            acc[i][j2] = (f32x4){0.f,0.f,0.f,0.f};

    for (int ks = 0; ks < nks; ++ks) {
        int ko = ks*32;
        __syncthreads();
        *(uint4v*)&S.Ahs[sf][th*16]   = *(const uint4v*)(pah + ko);
        *(uint4v*)&S.Ahs[sf][th*16+8] = *(const uint4v*)(pah + ko + 8);
        *(uint4v*)&S.Als[sf][th*16]   = *(const uint4v*)(pal + ko);
        *(uint4v*)&S.Als[sf][th*16+8] = *(const uint4v*)(pal + ko + 8);
        *(uint4v*)&S.Bhs[sf][th*16]   = *(const uint4v*)(pbh + ko);
        *(uint4v*)&S.Bhs[sf][th*16+8] = *(const uint4v*)(pbh + ko + 8);
        *(uint4v*)&S.Bls[sf][th*16]   = *(const uint4v*)(pbl + ko);
        *(uint4v*)&S.Bls[sf][th*16+8] = *(const uint4v*)(pbl + ko + 8);
        __syncthreads();
        bf16x8 ah[4], al[4], bh[4], bl[4];
        #pragma unroll
        for (int i = 0; i < 4; ++i) {
            ah[i] = *(const bf16x8*)&S.Ahs[wr*64 + i*16 + r16][kg*8];
            al[i] = *(const bf16x8*)&S.Als[wr*64 + i*16 + r16][kg*8];
            bh[i] = *(const bf16x8*)&S.Bhs[wc*64 + i*16 + r16][kg*8];
            bl[i] = *(const bf16x8*)&S.Bls[wc*64 + i*16 + r16][kg*8];
        }
        #pragma unroll
        for (int i = 0; i < 4; ++i)
            #pragma unroll
            for (int j2 = 0; j2 < 4; ++j2) {
                acc[i][j2] = __builtin_amdgcn_mfma_f32_16x16x32_bf16(ah[i], bh[j2], acc[i][j2], 0,0,0);
                acc[i][j2] = __builtin_amdgcn_mfma_f32_16x16x32_bf16(al[i], bh[j2], acc[i][j2], 0,0,0);
                acc[i][j2] = __builtin_amdgcn_mfma_f32_16x16x32_bf16(ah[i], bl[j2], acc[i][j2], 0,0,0);
            }
    }
    __syncthreads();
    size_t gb = ((size_t)b*25 + split)*16384;
    #pragma unroll
    for (int i = 0; i < 4; ++i)
        #pragma unroll
        for (int j2 = 0; j2 < 4; ++j2)
            #pragma unroll
            for (int reg = 0; reg < 4; ++reg)
                Gpart[gb + (size_t)(wr*64 + i*16 + kg*4 + reg)*128 + wc*64 + j2*16 + r16]
                    = acc[i][j2][reg];
}

__device__ void body_gred(int job, int np2,
    const float* __restrict__ Gpart, const float* __restrict__ wj,
    short* __restrict__ Gbh, short* __restrict__ Gbl, float* __restrict__ rpart)
{
    int part = job % 8, b = job / 8;
    int tid = threadIdx.x;
    int e0 = part*2048 + tid*8;
    float a[8] = {0,0,0,0,0,0,0,0};
    for (int i = 0; i < np2; ++i) {
        const float* p = Gpart + ((size_t)b*25 + i)*16384 + e0;
        float4 x0 = *(const float4*)p;
        float4 x1 = *(const float4*)(p + 4);
        a[0] += x0.x; a[1] += x0.y; a[2] += x0.z; a[3] += x0.w;
        a[4] += x1.x; a[5] += x1.y; a[6] += x1.z; a[7] += x1.w;
    }
    unsigned ph[4], pl[4];
    #pragma unroll
    for (int i = 0; i < 8; i += 2) pack_hl(a[i], a[i+1], ph[i>>1], pl[i>>1]);
    uint4v vh = {ph[0],ph[1],ph[2],ph[3]};
    uint4v vl = {pl[0],pl[1],pl[2],pl[3]};
    *(uint4v*)&Gbh[(size_t)b*16384 + e0] = vh;
    *(uint4v*)&Gbl[(size_t)b*16384 + e0] = vl;

    int c0 = e0 & 127;
    float4 w0 = *(const float4*)&wj[c0];
    float4 w1 = *(const float4*)&wj[c0 + 4];
    float pr = a[0]*w0.x + a[1]*w0.y + a[2]*w0.z + a[3]*w0.w
             + a[4]*w1.x + a[5]*w1.y + a[6]*w1.z + a[7]*w1.w;
    pr += __shfl_xor(pr, 1); pr += __shfl_xor(pr, 2);
    pr += __shfl_xor(pr, 4); pr += __shfl_xor(pr, 8);
    if ((tid & 15) == 0) rpart[b*128 + (e0 >> 7)] = pr;
}

__device__ void body_computeM(int job,
    const short* __restrict__ Gbh, const short* __restrict__ Gbl,
    const float* __restrict__ spart, int np,
    const short* __restrict__ Pjh, const short* __restrict__ Pjl,
    const float* __restrict__ uj, const float* __restrict__ cj,
    const float* __restrict__ rpart,
    short* __restrict__ Mth, short* __restrict__ Mtl, float* __restrict__ rm,
    SMem& Smem)
{
    int kh = job % 2, b = job / 2;
    CMS& S = *(CMS*)Smem.buf;
    float (*T)[132] = (float(*)[132])Smem.buf;
    float* sv = Smem.sv;

    int tid = threadIdx.x;
    int lane = tid & 63, wid = tid >> 6;
    int wr = wid >> 1, wc = wid & 1;
    int r16 = lane & 15, kg = lane >> 4;
    int st = tid >> 2, sq = tid & 3;
    int sf = tid >> 1, sh2 = tid & 1;

    if (tid < 128) {
        float s = 0.f;
        for (int i = 0; i < np; ++i) s += spart[((size_t)b*np + i)*128 + tid];
        sv[tid] = s;
        if (kh == 0) rm[b*128 + tid] = SCALE*(rpart[b*128 + tid] + cj[0]*s);
    }

    const short* pah = Pjh + (size_t)(kh*64 + st)*128 + sq*8;
    const short* pal = Pjl + (size_t)(kh*64 + st)*128 + sq*8;
    const short* pbh = Gbh + ((size_t)b*F + sf)*128 + sh2*16;
    const short* pbl = Gbl + ((size_t)b*F + sf)*128 + sh2*16;

    f32x4 acc[2][4];
    #pragma unroll
    for (int i = 0; i < 2; ++i)
        #pragma unroll
        for (int j2 = 0; j2 < 4; ++j2)
            acc[i][j2] = (f32x4){0.f,0.f,0.f,0.f};

    {
        *(uint4v*)&S.Psh[0][st][sq*8]      = *(const uint4v*)pah;
        *(uint4v*)&S.Psl[0][st][sq*8]      = *(const uint4v*)pal;
        *(uint4v*)&S.Bsh[0][sf][sh2*16]    = *(const uint4v*)pbh;
        *(uint4v*)&S.Bsh[0][sf][sh2*16+8]  = *(const uint4v*)(pbh + 8);
        *(uint4v*)&S.Bsl[0][sf][sh2*16]    = *(const uint4v*)pbl;
        *(uint4v*)&S.Bsl[0][sf][sh2*16+8]  = *(const uint4v*)(pbl + 8);
    }
    #pragma unroll
    for (int ks = 0; ks < 4; ++ks) {
        int cur = ks & 1;
        uint4v a0, a1, b0, b1, b2, b3;
        if (ks < 3) {
            int ko = (ks+1)*32;
            a0 = *(const uint4v*)(pah + ko); a1 = *(const uint4v*)(pal + ko);
            b0 = *(const uint4v*)(pbh + ko); b1 = *(const uint4v*)(pbh + ko + 8);
            b2 = *(const uint4v*)(pbl + ko); b3 = *(const uint4v*)(pbl + ko + 8);
        }
        __syncthreads();
        bf16x8 ah[2], al[2], bh[4], bl[4];
        #pragma unroll
        for (int i = 0; i < 2; ++i) {
            ah[i] = *(const bf16x8*)&S.Psh[cur][wr*32 + i*16 + r16][kg*8];
            al[i] = *(const bf16x8*)&S.Psl[cur][wr*32 + i*16 + r16][kg*8];
        }
        #pragma unroll
        for (int j2 = 0; j2 < 4; ++j2) {
            bh[j2] = *(const bf16x8*)&S.Bsh[cur][wc*64 + j2*16 + r16][kg*8];
            bl[j2] = *(const bf16x8*)&S.Bsl[cur][wc*64 + j2*16 + r16][kg*8];
        }
        #pragma unroll
        for (int i = 0; i < 2; ++i)
            #pragma unroll
            for (int j2 = 0; j2 < 4; ++j2) {
                acc[i][j2] = __builtin_amdgcn_mfma_f32_16x16x32_bf16(ah[i], bh[j2], acc[i][j2], 0,0,0);
                acc[i][j2] = __builtin_amdgcn_mfma_f32_16x16x32_bf16(al[i], bh[j2], acc[i][j2], 0,0,0);
                acc[i][j2] = __builtin_amdgcn_mfma_f32_16x16x32_bf16(ah[i], bl[j2], acc[i][j2], 0,0,0);
            }
        if (ks < 3) {
            int nb = cur ^ 1;
            *(uint4v*)&S.Psh[nb][st][sq*8]     = a0;
            *(uint4v*)&S.Psl[nb][st][sq*8]     = a1;
            *(uint4v*)&S.Bsh[nb][sf][sh2*16]   = b0;
            *(uint4v*)&S.Bsh[nb][sf][sh2*16+8] = b1;
            *(uint4v*)&S.Bsl[nb][sf][sh2*16]   = b2;
            *(uint4v*)&S.Bsl[nb][sf][sh2*16+8] = b3;
        }
    }
    float uval[2][4], svv[4];
    #pragma unroll
    for (int i = 0; i < 2; ++i)
        #pragma unroll
        for (int reg = 0; reg < 4; ++reg)
            uval[i][reg] = uj[kh*64 + wr*32 + i*16 + kg*4 + reg];
    #pragma unroll
    for (int j2 = 0; j2 < 4; ++j2) svv[j2] = sv[wc*64 + j2*16 + r16];
    __syncthreads();
    #pragma unroll
    for (int i = 0; i < 2; ++i)
        #pragma unroll
        for (int j2 = 0; j2 < 4; ++j2)
            #pragma unroll
            for (int reg = 0; reg < 4; ++reg)
                T[wr*32 + i*16 + kg*4 + reg][wc*64 + j2*16 + r16]
                    = SCALE*(acc[i][j2][reg] + uval[i][reg]*svv[j2]);
    __syncthreads();
    {
        int f2 = tid >> 1, half = tid & 1;
        unsigned ph[16], pl[16];
        #pragma unroll
        for (int i = 0; i < 32; i += 2) {
            float v0 = T[half*32 + i][f2];
            float v1 = T[half*32 + i + 1][f2];
            pack_hl(v0, v1, ph[i>>1], pl[i>>1]);
        }
        size_t ob = ((size_t)b*F + f2)*F + kh*64 + half*32;
        store16u(&Mth[ob], ph);
        store16u(&Mtl[ob], pl);
    }
}

__device__ void body_mid(int tblk, int b,
    short* __restrict__ Vbh, short* __restrict__ Vbl,
    const short* __restrict__ Mth, const short* __restrict__ Mtl,
    const float* __restrict__ rm,
    const float* __restrict__ glj, const float* __restrict__ blj, int doLN,
    short* __restrict__ OTh, short* __restrict__ OTl,
    float* __restrict__ spartN, SMem& Smem)
{
    int t0 = tblk * 64;
    MidS& S = *(MidS*)Smem.buf;
    float (*T)[132] = (float(*)[132])Smem.buf;

    int tid = threadIdx.x;
    int lane = tid & 63, wid = tid >> 6;
    int wr = wid >> 1, wc = wid & 1;
    int r16 = lane & 15, kg = lane >> 4;
    int st = tid >> 2, sq = tid & 3;
    int sf = tid >> 1, sh2 = tid & 1;

    const short* pah = Vbh + ((size_t)b*T2 + t0 + st)*F + sq*8;
    const short* pal = Vbl + ((size_t)b*T2 + t0 + st)*F + sq*8;
    const short* pbh = Mth + ((size_t)b*F + sf)*F + sh2*16;
    const short* pbl = Mtl + ((size_t)b*F + sf)*F + sh2*16;

    f32x4 acc[2][4];
    #pragma unroll
    for (int i = 0; i < 2; ++i)
        #pragma unroll
        for (int j2 = 0; j2 < 4; ++j2)
            acc[i][j2] = (f32x4){0.f,0.f,0.f,0.f};

    {
        *(uint4v*)&S.Ash[0][st][sq*8]      = *(const uint4v*)pah;
        *(uint4v*)&S.Asl[0][st][sq*8]      = *(const uint4v*)pal;
        *(uint4v*)&S.Bsh[0][sf][sh2*16]    = *(const uint4v*)pbh;
        *(uint4v*)&S.Bsh[0][sf][sh2*16+8]  = *(const uint4v*)(pbh + 8);
        *(uint4v*)&S.Bsl[0][sf][sh2*16]    = *(const uint4v*)pbl;
        *(uint4v*)&S.Bsl[0][sf][sh2*16+8]  = *(const uint4v*)(pbl + 8);
    }
    #pragma unroll
    for (int ks = 0; ks < 4; ++ks) {
        int cur = ks & 1;
        uint4v a0, a1, b0, b1, b2, b3;
        if (ks < 3) {
            int ko = (ks+1)*32;
            a0 = *(const uint4v*)(pah + ko); a1 = *(const uint4v*)(pal + ko);
            b0 = *(const uint4v*)(pbh + ko); b1 = *(const uint4v*)(pbh + ko + 8);
            b2 = *(const uint4v*)(pbl + ko); b3 = *(const uint4v*)(pbl + ko + 8);
        }
        __syncthreads();
        bf16x8 ah[2], al[2], bh[4], bl[4];
        #pragma unroll
        for (int i = 0; i < 2; ++i) {
            ah[i] = *(const bf16x8*)&S.Ash[cur][wr*32 + i*16 + r16][kg*8];
            al[i] = *(const bf16x8*)&S.Asl[cur][wr*32 + i*16 + r16][kg*8];
        }
        #pragma unroll
        for (int j2 = 0; j2 < 4; ++j2) {
            bh[j2] = *(const bf16x8*)&S.Bsh[cur][wc*64 + j2*16 + r16][kg*8];
            bl[j2] = *(const bf16x8*)&S.Bsl[cur][wc*64 + j2*16 + r16][kg*8];
        }
        #pragma unroll
        for (int i = 0; i < 2; ++i)
            #pragma unroll
            for (int j2 = 0; j2 < 4; ++j2) {
                acc[i][j2] = __builtin_amdgcn_mfma_f32_16x16x32_bf16(ah[i], bh[j2], acc[i][j2], 0,0,0);
                acc[i][j2] = __builtin_amdgcn_mfma_f32_16x16x32_bf16(al[i], bh[j2], acc[i][j2], 0,0,0);
                acc[i][j2] = __builtin_amdgcn_mfma_f32_16x16x32_bf16(ah[i], bl[j2], acc[i][j2], 0,0,0);
            }
        if (ks < 3) {
            int nb = cur ^ 1;
            *(uint4v*)&S.Ash[nb][st][sq*8]     = a0;
            *(uint4v*)&S.Asl[nb][st][sq*8]     = a1;
            *(uint4v*)&S.Bsh[nb][sf][sh2*16]   = b0;
            *(uint4v*)&S.Bsh[nb][sf][sh2*16+8] = b1;
            *(uint4v*)&S.Bsl[nb][sf][sh2*16]   = b2;
            *(uint4v*)&S.Bsl[nb][sf][sh2*16+8] = b3;
        }
    }
    float rv[4];
    #pragma unroll
    for (int j2 = 0; j2 < 4; ++j2) rv[j2] = rm[b*F + wc*64 + j2*16 + r16];
    __syncthreads();
    #pragma unroll
    for (int i = 0; i < 2; ++i)
        #pragma unroll
        for (int j2 = 0; j2 < 4; ++j2)
            #pragma unroll
            for (int reg = 0; reg < 4; ++reg)
                T[wr*32 + i*16 + kg*4 + reg][wc*64 + j2*16 + r16]
                    = acc[i][j2][reg] + rv[j2];
    __syncthreads();

    if (doLN) {
        int r = tid >> 2, qd = tid & 3;
        float v[32];
        #pragma unroll
        for (int i = 0; i < 32; i += 4)
            *(float4*)&v[i] = *(const float4*)&T[r][qd*32 + i];
        float s = 0.f;
        #pragma unroll
        for (int i = 0; i < 32; ++i) s += v[i];
        s += __shfl_xor(s, 1); s += __shfl_xor(s, 2);
        float mu = s * (1.0f/128.0f);
        float dv = 0.f;
        #pragma unroll
        for (int i = 0; i < 32; ++i) { float d = v[i] - mu; dv = fmaf(d, d, dv); }
        dv += __shfl_xor(dv, 1); dv += __shfl_xor(dv, 2);
        float rs = rsqrtf(dv * (1.0f/128.0f) + EPS);

        short hb[32], lb[32];
        {
            const short* rh = Vbh + ((size_t)b*T2 + t0 + r)*F + qd*32;
            const short* rl = Vbl + ((size_t)b*T2 + t0 + r)*F + qd*32;
            #pragma unroll
            for (int i = 0; i < 32; i += 8) {
                *(uint4v*)&hb[i] = *(const uint4v*)(rh + i);
                *(uint4v*)&lb[i] = *(const uint4v*)(rl + i);
            }
        }
        float gv[32], bv2[32];
        #pragma unroll
        for (int i = 0; i < 32; i += 4) {
            *(float4*)&gv[i]  = *(const float4*)&glj[qd*32 + i];
            *(float4*)&bv2[i] = *(const float4*)&blj[qd*32 + i];
        }
        unsigned ph[16], pl[16];
        #pragma unroll
        for (int i = 0; i < 32; i += 2) {
            float res0 = bf2f((unsigned short)hb[i])   + bf2f((unsigned short)lb[i]);
            float res1 = bf2f((unsigned short)hb[i+1]) + bf2f((unsigned short)lb[i+1]);
            float o0 = (v[i]   - mu)*rs*gv[i]   + bv2[i]   + res0;
            float o1 = (v[i+1] - mu)*rs*gv[i+1] + bv2[i+1] + res1;
            T[r][qd*32+i] = o0; T[r][qd*32+i+1] = o1;
            pack_hl(o0, o1, ph[i>>1], pl[i>>1]);
        }
        size_t ob = ((size_t)b*T2 + t0 + r)*F + qd*32;
        store16u(&Vbh[ob], ph);
        store16u(&Vbl[ob], pl);
        __syncthreads();
    }
    {
        int f2 = tid >> 1, half = tid & 1;
        float sacc = 0.f;
        unsigned ph[16], pl[16];
        #pragma unroll
        for (int i = 0; i < 32; i += 2) {
            float v0 = T[half*32 + i][f2];
            float v1 = T[half*32 + i + 1][f2];
            sacc += v0 + v1;
            pack_hl(v0, v1, ph[i>>1], pl[i>>1]);
        }
        size_t ob = ((size_t)b*F + f2)*T2 + t0 + half*32;
        store16u(&OTh[ob], ph);
        store16u(&OTl[ob], pl);
        if (doLN)
            spartN[((size_t)b*100 + tblk*2 + half)*128 + f2] = sacc;
    }
}

// =================== merged kernels (real work + MLP helpers) ==============
__global__ __launch_bounds__(256, 2) void k_apply_gsym(
    const float* xy, const float* g0, const float* b0, const float* lnpart,
    short* Vbh, short* Vbl, short* Vbth, short* Vbtl,
    short* xyTh, short* xyTl, float* spartV, float* s2part, float* Gpart,
    int tile0,
    const float* uv, const float* kb2, const float* kW3, const float* kb3,
    const float* fb2, const float* fW3, const float* fb3,
    const short* AhF, const short* AlF, short* W2h)
{
    __shared__ SMem S;
    int jb = blockIdx.x;
    if (jb >= 400) {
        body_mlp(tile0 + (jb - 400)*20, uv, kb2, kW3, kb3, fb2, fW3, fb3,
                 AhF, AlF, W2h);
        return;
    }
    if (jb < 200) {
        int tgrp = jb % 25, b = jb / 25;
        body_apply(tgrp, b, xy, g0, b0, lnpart, Vbh, Vbl, Vbth, Vbtl, spartV, S);
        __syncthreads();
        body_gsym(tgrp, b, Vbth, Vbtl, Gpart, S);
    } else {
        int t = jb - 200;
        body_xyt(t % 25, t / 25, xy, xyTh, xyTl, s2part, S);
    }
}

__global__ __launch_bounds__(256, 2) void k_gred_m(
    const float* Gpart, int np2, const float* wj,
    short* Gbh, short* Gbl, float* rpart,
    int tile0,
    const float* uv, const float* kb2, const float* kW3, const float* kb3,
    const float* fb2, const float* fW3, const float* fb3,
    const short* AhF, const short* AlF, short* W2h)
{
    int bid = blockIdx.x;
    if (bid >= 64) {
        body_mlp(tile0 + (bid - 64)*20, uv, kb2, kW3, kb3, fb2, fW3, fb3,
                 AhF, AlF, W2h);
        return;
    }
    body_gred(bid, np2, Gpart, wj, Gbh, Gbl, rpart);
}

__global__ __launch_bounds__(256, 2) void k_cm_m(
    const short* Gbh, const short* Gbl, const float* spart, int np,
    const short* Pjh, const short* Pjl, const float* uj, const float* cj,
    const float* rpart, short* Mth, short* Mtl, float* rm,
    int tile0,
    const float* uv, const float* kb2, const float* kW3, const float* kb3,
    const float* fb2, const float* fW3, const float* fb3,
    const short* AhF, const short* AlF, short* W2h)
{
    __shared__ SMem S;
    int bid = blockIdx.x;
    if (bid >= 16) {
        body_mlp(tile0 + (bid - 16)*20, uv, kb2, kW3, kb3, fb2, fW3, fb3,
                 AhF, AlF, W2h);
        return;
    }
    body_computeM(bid, Gbh, Gbl, spart, np, Pjh, Pjl, uj, cj, rpart,
                  Mth, Mtl, rm, S);
}

// mode: 0 = gsym after mid, 1 = gasym (j==2->3), 2 = none (final mid)
__global__ __launch_bounds__(256, 2) void k_mid_gsym(
    short* Vbh, short* Vbl, const short* Mth, const short* Mtl,
    const float* rm, const float* glj, const float* blj, int doLN,
    short* OTh, short* OTl, float* spartN,
    int mode, const short* xyTh, const short* xyTl, float* Gpart,
    int tile0,
    const float* uv, const float* kb2, const float* kW3, const float* kb3,
    const float* fb2, const float* fW3, const float* fb3,
    const short* AhF, const short* AlF, short* W2h)
{
    __shared__ SMem S;
    int bid = blockIdx.x;
    if (bid >= 200) {
        body_mlp(tile0 + (bid - 200)*20, uv, kb2, kW3, kb3, fb2, fW3, fb3,
                 AhF, AlF, W2h);
        return;
    }
    int s = bid % 25, b = bid / 25;
    #pragma unroll
    for (int pass = 0; pass < 2; ++pass) {
        body_mid(s*2 + pass, b, Vbh, Vbl, Mth, Mtl, rm, glj, blj, doLN,
                 OTh, OTl, spartN, S);
        __syncthreads();
    }
    if (mode == 0) {
        body_gsym(s, b, OTh, OTl, Gpart, S);
    } else if (mode == 1) {
        int nks = (s < 12) ? 4 : ((s == 12) ? 2 : 0);
        if (nks) body_gasym2(s, b, nks, xyTh, xyTl, OTh, OTl, Gpart, S);
    }
}

// ------------- out = DXDY * W2(bf16) @ U(bf16 h/l), MFMA -------------------
__global__ __launch_bounds__(256) void k_gout(
    const short* __restrict__ W2h,
    const short* __restrict__ Uth, const short* __restrict__ Utl,
    float* __restrict__ out)
{
    int job = blockIdx.x;
    int nt = job % 25, b = job / 25;
    int n0 = nt * 64;
    __shared__ GOutS S;

    int tid = threadIdx.x;
    int lane = tid & 63, wid = tid >> 6;
    int wr = wid >> 1, wc = wid & 1;
    int r16 = lane & 15, kg = lane >> 4;
    int srow = tid >> 2, sq2 = tid & 3;
    int sf = tid >> 1, sh2 = tid & 1;

    const short* ap  = W2h + (size_t)(n0 + srow)*T2 + sq2*8;
    const short* bhp = Uth + ((size_t)b*F + sf)*T2 + sh2*16;
    const short* blp = Utl + ((size_t)b*F + sf)*T2 + sh2*16;

    f32x4 acc[2][4];
    #pragma unroll
    for (int i = 0; i < 2; ++i)
        #pragma unroll
        for (int j2 = 0; j2 < 4; ++j2)
            acc[i][j2] = (f32x4){0.f,0.f,0.f,0.f};

    {
        *(uint4v*)&S.As[0][srow][sq2*8]  = *(const uint4v*)ap;
        *(uint4v*)&S.Bh[0][sf][sh2*16]   = *(const uint4v*)bhp;
        *(uint4v*)&S.Bh[0][sf][sh2*16+8] = *(const uint4v*)(bhp + 8);
        *(uint4v*)&S.Bl[0][sf][sh2*16]   = *(const uint4v*)blp;
        *(uint4v*)&S.Bl[0][sf][sh2*16+8] = *(const uint4v*)(blp + 8);
    }
    for (int it = 0; it < 100; ++it) {
        int cur = it & 1;
        uint4v ra, b0, b1, b2, b3;
        if (it < 99) {
            int ko = (it + 1) * 32;
            ra = *(const uint4v*)(ap + ko);
            b0 = *(const uint4v*)(bhp + ko); b1 = *(const uint4v*)(bhp + ko + 8);
            b2 = *(const uint4v*)(blp + ko); b3 = *(const uint4v*)(blp + ko + 8);
        }
        __syncthreads();
        bf16x8 ah[2], bh[4], bl[4];
        #pragma unroll
        for (int i = 0; i < 2; ++i)
            ah[i] = *(const bf16x8*)&S.As[cur][wr*32 + i*16 + r16][kg*8];
        #pragma unroll
        for (int j2 = 0; j2 < 4; ++j2) {
            bh[j2] = *(const bf16x8*)&S.Bh[cur][wc*64 + j2*16 + r16][kg*8];
            bl[j2] = *(const bf16x8*)&S.Bl[cur][wc*64 + j2*16 + r16][kg*8];
        }
        #pragma unroll
        for (int i = 0; i < 2; ++i)
            #pragma unroll
            for (int j2 = 0; j2 < 4; ++j2) {
                acc[i][j2] = __builtin_amdgcn_mfma_f32_16x16x32_bf16(ah[i], bh[j2], acc[i][j2], 0,0,0);
                acc[i][j2] = __builtin_amdgcn_mfma_f32_16x16x32_bf16(ah[i], bl[j2], acc[i][j2], 0,0,0);
            }
        if (it < 99) {
            int nb = cur ^ 1;
            *(uint4v*)&S.As[nb][srow][sq2*8]  = ra;
            *(uint4v*)&S.Bh[nb][sf][sh2*16]   = b0;
            *(uint4v*)&S.Bh[nb][sf][sh2*16+8] = b1;
            *(uint4v*)&S.Bl[nb][sf][sh2*16]   = b2;
            *(uint4v*)&S.Bl[nb][sf][sh2*16+8] = b3;
        }
    }
    #pragma unroll
    for (int i = 0; i < 2; ++i)
        #pragma unroll
        for (int j2 = 0; j2 < 4; ++j2)
            #pragma unroll
            for (int reg = 0; reg < 4; ++reg) {
                int n_out = n0 + wr*32 + i*16 + kg*4 + reg;
                int f_out = wc*64 + j2*16 + r16;
                out[((size_t)b*NT + n_out)*F + f_out] = DXDY * acc[i][j2][reg];
            }
}

// =============================== launcher ==================================
extern "C" void kernel_launch(void* const* d_in, const int* in_sizes, int n_in,
                              void* d_out, int out_size, void* d_ws, size_t ws_size,
                              hipStream_t stream)
{
    const float* xy  = (const float*)d_in[0];
    const float* kW1 = (const float*)d_in[1];
    const float* kb1 = (const float*)d_in[2];
    const float* kW2 = (const float*)d_in[3];
    const float* kb2 = (const float*)d_in[4];
    const float* kW3 = (const float*)d_in[5];
    const float* kb3 = (const float*)d_in[6];
    const float* fW1 = (const float*)d_in[7];
    const float* fb1 = (const float*)d_in[8];
    const float* fW2 = (const float*)d_in[9];
    const float* fb2 = (const float*)d_in[10];
    const float* fW3 = (const float*)d_in[11];
    const float* fb3 = (const float*)d_in[12];
    const float* Wq  = (const float*)d_in[13];
    const float* bq  = (const float*)d_in[14];
    const float* Wk  = (const float*)d_in[15];
    const float* bk  = (const float*)d_in[16];
    const float* g0  = (const float*)d_in[17];
    const float* b0  = (const float*)d_in[18];
    const float* gl  = (const float*)d_in[19];
    const float* bl  = (const float*)d_in[20];
    float* out = (float*)d_out;

    short* W2h  = (short*)d_ws;                 // 5,120,000
    short* Vbh  = W2h  + 5120000;               // 3,276,800
    short* Vbl  = Vbh  + 3276800;
    short* Vbth = Vbl  + 3276800;
    short* Vbtl = Vbth + 3276800;
    short* xyTh = Vbtl + 3276800;               // 1,638,400
    short* xyTl = xyTh + 1638400;
    short* Uth  = xyTl + 1638400;               // 3,276,800
    short* Utl  = Uth  + 3276800;
    short* Pnh  = Utl  + 3276800;               // 65,536
    short* Pnl  = Pnh  + 65536;
    short* Mth  = Pnl  + 65536;                 // 131,072
    short* Mtl  = Mth  + 131072;
    short* Gbh  = Mtl  + 131072;                // 131,072
    short* Gbl  = Gbh  + 131072;
    short* AhF  = Gbl  + 131072;                // 4,096
    short* AlF  = AhF  + 4096;
    float* Gpart  = (float*)(AlF + 4096);       // 3,276,800 f
    float* uB     = Gpart + 3276800;            // 512
    float* wB     = uB + 512;                   // 512
    float* cB     = wB + 512;                   // 4
    float* lnpart = cB + 4;                     // 400
    float* rpart  = lnpart + 400;               // 1024
    float* rm     = rpart + 1024;               // 1024
    float* spartV = rm + 1024;                  // 102,400
    float* s2part = spartV + 102400;            // 51,200
    float* uvT    = s2part + 51200;             // 204,800

    k_prep<<<dim3(433), 256, 0, stream>>>(kW2, fW2, AhF, AlF,
                                          kW1, kb1, fW1, fb1, uvT,
                                          xy, lnpart,
                                          Wq, bq, Wk, bk, Pnh, Pnl, uB, wB, cB);

    // MLP tile budget: apply 800 blocks (16,000 tiles);
    // per layer: gred 400 (8,000), cm 400 (8,000), mid 1000 (20,000)
    k_apply_gsym<<<dim3(1200), 256, 0, stream>>>(
        xy, g0, b0, lnpart, Vbh, Vbl, Vbth, Vbtl,
        xyTh, xyTl, spartV, s2part, Gpart,
        /*tile0=*/0,
        uvT, kb2, kW3, kb3, fb2, fW3, fb3, AhF, AlF, W2h);

    for (int j = 0; j < 4; ++j) {
        int np2  = (j < 3) ? 25 : 13;
        int np_s = (j < 3) ? 100 : 50;
        const float* sp = (j < 3) ? spartV : s2part;
        int base = 16000 + j*36000;

        k_gred_m<<<dim3(464), 256, 0, stream>>>(
            Gpart, np2, wB + j*128, Gbh, Gbl, rpart,
            base,
            uvT, kb2, kW3, kb3, fb2, fW3, fb3, AhF, AlF, W2h);

        k_cm_m<<<dim3(416), 256, 0, stream>>>(
            Gbh, Gbl, sp, np_s,
            Pnh + (size_t)j*16384, Pnl + (size_t)j*16384,
            uB + j*128, cB + j, rpart, Mth, Mtl, rm,
            base + 8000,
            uvT, kb2, kW3, kb3, fb2, fW3, fb3, AhF, AlF, W2h);

        if (j < 2) {
            k_mid_gsym<<<dim3(1200), 256, 0, stream>>>(
                Vbh, Vbl, Mth, Mtl, rm, gl + j*128, bl + j*128, 1,
                Vbth, Vbtl, spartV, 0, xyTh, xyTl, Gpart,
                base + 16000,
                uvT, kb2, kW3, kb3, fb2, fW3, fb3, AhF, AlF, W2h);
        } else if (j == 2) {
            k_mid_gsym<<<dim3(1200), 256, 0, stream>>>(
                Vbh, Vbl, Mth, Mtl, rm, gl + j*128, bl + j*128, 1,
                Vbth, Vbtl, spartV, 1, xyTh, xyTl, Gpart,
                base + 16000,
                uvT, kb2, kW3, kb3, fb2, fW3, fb3, AhF, AlF, W2h);
        } else {
            k_mid_gsym<<<dim3(1200), 256, 0, stream>>>(
                Vbh, Vbl, Mth, Mtl, rm, gl, bl, 0,
                Uth, Utl, spartV, 2, xyTh, xyTl, Gpart,
                base + 16000,
                uvT, kb2, kW3, kb3, fb2, fW3, fb3, AhF, AlF, W2h);
        }
    }

    k_gout<<<dim3(200), 256, 0, stream>>>(W2h, Uth, Utl, out);
}

// Round 11
// 447.580 us; speedup vs baseline: 2.4467x; 1.1631x over previous
//
#include <hip/hip_runtime.h>
#include <math.h>

#define NGRID 40
#define NT    1600
#define T2    3200
#define F     128
#define NB    8
#define EPS   1e-5f

__device__ __constant__ const float kINV39 = 1.0f/39.0f;
constexpr float DXDY  = (1.0f/39.0f)*(1.0f/39.0f);
constexpr float SCALE = DXDY * 0.125f;   // DXDY / sqrt(64)

typedef __attribute__((ext_vector_type(8))) short bf16x8;
typedef __attribute__((ext_vector_type(4))) float f32x4;
typedef __attribute__((ext_vector_type(4))) unsigned uint4v;

__device__ __forceinline__ unsigned bitu(float f){ return __builtin_bit_cast(unsigned,f); }
__device__ __forceinline__ float bitf(unsigned u){ return __builtin_bit_cast(float,u); }
__device__ __forceinline__ unsigned short f2bf(float f) {
    unsigned u = bitu(f);
    unsigned r = u + 0x7FFFu + ((u >> 16) & 1u);
    return (unsigned short)(r >> 16);
}
__device__ __forceinline__ float bf2f(unsigned short h) { return bitf(((unsigned)h) << 16); }

__device__ __forceinline__ void pack_hl(float a, float b, unsigned &h, unsigned &l) {
    unsigned ua = bitu(a), ub = bitu(b);
    h = __builtin_amdgcn_perm(ub, ua, 0x07060302u);
    float ra = a - bitf(ua & 0xffff0000u);
    float rb = b - bitf(ub & 0xffff0000u);
    l = __builtin_amdgcn_perm(bitu(rb), bitu(ra), 0x07060302u);
}
__device__ __forceinline__ void store8u(short* dst, const unsigned* p) {
    uint4v v0 = {p[0], p[1], p[2], p[3]};
    uint4v v1 = {p[4], p[5], p[6], p[7]};
    *(uint4v*)dst = v0;
    *(uint4v*)(dst + 8) = v1;
}
__device__ __forceinline__ void store16u(short* dst, const unsigned* p) {
    store8u(dst, p);
    store8u(dst + 16, p + 8);
}

// shared-memory union
struct SMem {
    __align__(16) char buf[61440];
    float sv[128];
};
struct GSymS  { short Sh[2][128][40], Sl[2][128][40]; };
struct GAs2S  { short Ahs[128][40], Als[128][40], Bhs[128][40], Bls[128][40]; };
struct CMS    { short Psh[2][64][40], Psl[2][64][40], Bsh[2][128][40], Bsl[2][128][40]; };
struct MidS   { short Ash[2][64][40], Asl[2][64][40], Bsh[2][128][40], Bsl[2][128][40]; };
struct GOutS  { short As[2][64][40], Bh[2][128][40], Bl[2][128][40]; };

// =================== fused prep: uv | ln0_part | P | uwc | frag ============
// P spread over 256 blocks (16x16 tile each, 1 output/thread); FMA order
// identical to original (h outer, d ascending) -> bit-identical results.
__global__ __launch_bounds__(256) void k_prep(
    const float* __restrict__ kW2, const float* __restrict__ fW2,
    short* __restrict__ Ah, short* __restrict__ Al,
    const float* __restrict__ kW1, const float* __restrict__ kb1,
    const float* __restrict__ fW1, const float* __restrict__ fb1,
    float* __restrict__ uv,
    const float* __restrict__ xy, float* __restrict__ lnpart,
    const float* __restrict__ Wq, const float* __restrict__ bq,
    const float* __restrict__ Wk, const float* __restrict__ bk,
    short* __restrict__ Pnh, short* __restrict__ Pnl,
    float* __restrict__ uB, float* __restrict__ wB, float* __restrict__ cB)
{
    __shared__ float ss[4], qs[4];
    int job = blockIdx.x;
    int tid = threadIdx.x;
    if (job < 200) {                       // ---- uv tables
        int idx = job * 256 + tid;
        int node = idx >> 5, o = idx & 31;
        float x0 = (float)(node / NGRID) * kINV39;
        float x1 = (float)(node % NGRID) * kINV39;
        uv[idx]          = fmaf(kW1[o], x0, fmaf(kW1[32+o], x1, kb1[o]));
        uv[51200 + idx]  = fmaf(kW1[64+o], x0, kW1[96+o]*x1);
        uv[102400 + idx] = fmaf(fW1[o], x0, fmaf(fW1[32+o], x1, fb1[o]));
        uv[153600 + idx] = fmaf(fW1[64+o], x0, fW1[96+o]*x1);
        return;
    }
    if (job < 400) {                       // ---- ln0 partial sums
        int t = job - 200;
        int b = t & 7, blk = t >> 3;
        const float4* p = (const float4*)xy + (size_t)b*102400 + blk*4096 + tid;
        float s = 0.f, q = 0.f;
        #pragma unroll
        for (int i = 0; i < 16; ++i) {
            float4 v = p[i*256];
            s += (v.x + v.y) + (v.z + v.w);
            q += (v.x*v.x + v.y*v.y) + (v.z*v.z + v.w*v.w);
        }
        #pragma unroll
        for (int off = 32; off >= 1; off >>= 1) {
            s += __shfl_xor(s, off);
            q += __shfl_xor(q, off);
        }
        int wid = tid >> 6;
        if ((tid & 63) == 0) { ss[wid] = s; qs[wid] = q; }
        __syncthreads();
        if (tid == 0) {
            lnpart[((size_t)b*25 + blk)*2 + 0] = ss[0]+ss[1]+ss[2]+ss[3];
            lnpart[((size_t)b*25 + blk)*2 + 1] = qs[0]+qs[1]+qs[2]+qs[3];
        }
        return;
    }
    if (job < 656) {                       // ---- P tile: 16x16 outputs/block
        int t = job - 400;                 // 256 blocks: [j(4)][rem(64)]
        int j = t >> 6;
        int rem = t & 63;
        int kp8 = rem >> 3, k8 = rem & 7;
        int ki = tid >> 4, kpi = tid & 15;
        int k  = k8*16 + ki;
        int kp = kp8*16 + kpi;
        const float* wq = Wq + (size_t)j*8*F*64;
        const float* wk = Wk + (size_t)j*8*F*64;
        float acc = 0.f;
        for (int h = 0; h < 8; ++h) {
            const float* qrow = wq + ((size_t)h*F + k)*64;
            const float* krow = wk + ((size_t)h*F + kp)*64;
            #pragma unroll
            for (int d = 0; d < 64; d += 4) {
                float4 a = *(const float4*)&qrow[d];
                float4 bv = *(const float4*)&krow[d];
                acc = fmaf(a.x, bv.x, acc);
                acc = fmaf(a.y, bv.y, acc);
                acc = fmaf(a.z, bv.z, acc);
                acc = fmaf(a.w, bv.w, acc);
            }
        }
        short hs = (short)(bitu(acc) >> 16);
        float rem2 = acc - bitf(bitu(acc) & 0xffff0000u);
        short ls = (short)(bitu(rem2) >> 16);
        Pnh[((size_t)j*128 + k)*128 + kp] = hs;
        Pnl[((size_t)j*128 + k)*128 + kp] = ls;
        return;
    }
    if (job < 660) {                       // ---- u, w, c per layer
        int j = job - 656;
        const float* wq = Wq + (size_t)j*8*F*64;
        const float* wk = Wk + (size_t)j*8*F*64;
        const float* bqj = bq + j*512;
        const float* bkj = bk + j*512;
        if (tid < 128) {
            int k = tid; float a = 0.f;
            for (int h = 0; h < 8; ++h) {
                const float* row = wq + ((size_t)h*F + k)*64;
                const float* bb = bkj + h*64;
                #pragma unroll
                for (int d = 0; d < 64; d += 4) {
                    float4 v = *(const float4*)&row[d];
                    a = fmaf(v.x, bb[d],   a);
                    a = fmaf(v.y, bb[d+1], a);
                    a = fmaf(v.z, bb[d+2], a);
                    a = fmaf(v.w, bb[d+3], a);
                }
            }
            uB[j*128 + k] = a;
        } else {
            int k = tid - 128; float a = 0.f;
            for (int h = 0; h < 8; ++h) {
                const float* row = wk + ((size_t)h*F + k)*64;
                const float* bb = bqj + h*64;
                #pragma unroll
                for (int d = 0; d < 64; d += 4) {
                    float4 v = *(const float4*)&row[d];
                    a = fmaf(v.x, bb[d],   a);
                    a = fmaf(v.y, bb[d+1], a);
                    a = fmaf(v.z, bb[d+2], a);
                    a = fmaf(v.w, bb[d+3], a);
                }
            }
            wB[j*128 + k] = a;
        }
        if (tid == 0) {
            float a = 0.f;
            for (int i = 0; i < 512; ++i) a = fmaf(bqj[i], bkj[i], a);
            cB[j] = a;
        }
        return;
    }
    {                                      // ---- MLP W2-layer fragments
        int oc = tid >> 6, lane = tid & 63;
        int row = lane & 15;
        int k0 = (lane >> 4) * 8;
        #pragma unroll
        for (int mlp = 0; mlp < 2; ++mlp) {
            const float* W2 = mlp ? fW2 : kW2;
            #pragma unroll
            for (int i = 0; i < 8; ++i) {
                float w = W2[(size_t)(k0 + i) * 64 + oc * 16 + row];
                unsigned short h = f2bf(w);
                Ah[((mlp*4 + oc)*64 + lane)*8 + i] = (short)h;
                Al[((mlp*4 + oc)*64 + lane)*8 + i] = (short)f2bf(w - bf2f(h));
            }
        }
    }
}

// ============ MLP helper body: 20 tiles per block (5 per wave) =============
__device__ void body_mlp(int tile0,
    const float* __restrict__ uv,
    const float* __restrict__ kb2, const float* __restrict__ kW3,
    const float* __restrict__ kb3,
    const float* __restrict__ fb2, const float* __restrict__ fW3,
    const float* __restrict__ fb3,
    const short* __restrict__ Ah, const short* __restrict__ Al,
    short* __restrict__ W2h)
{
    int tid = threadIdx.x;
    int wid = tid >> 6, lane = tid & 63;
    int c = lane & 15, kg = lane >> 4;
    int k0 = kg * 8;

    bf16x8 AHf[2][4], ALf[2][4];
    float4 B2f[2][4], W3f[2][4];
    #pragma unroll
    for (int mlp = 0; mlp < 2; ++mlp) {
        const float* b2p = mlp ? fb2 : kb2;
        const float* w3p = mlp ? fW3 : kW3;
        #pragma unroll
        for (int oc = 0; oc < 4; ++oc) {
            AHf[mlp][oc] = *(const bf16x8*)&Ah[((mlp*4 + oc)*64 + lane)*8];
            ALf[mlp][oc] = *(const bf16x8*)&Al[((mlp*4 + oc)*64 + lane)*8];
            B2f[mlp][oc] = *(const float4*)&b2p[oc*16 + kg*4];
            W3f[mlp][oc] = *(const float4*)&w3p[oc*16 + kg*4];
        }
    }
    float bias0 = kb3[0], bias1 = fb3[0];

    int t = tile0 + wid*5;
    for (int it = 0; it < 5; ++it, ++t) {
        int n = t / 100;
        int mt = t - n*100;
        int m = mt*16 + c;
        float res0, res1;
        #pragma unroll
        for (int mlp = 0; mlp < 2; ++mlp) {
            const float* up = uv + mlp*102400 + n*32 + k0;
            const float* vp = uv + mlp*102400 + 51200 + m*32 + k0;
            float4 ua = *(const float4*)up;
            float4 ub = *(const float4*)(up + 4);
            float4 va = *(const float4*)vp;
            float4 vb = *(const float4*)(vp + 4);
            float h[8] = {ua.x+va.x, ua.y+va.y, ua.z+va.z, ua.w+va.w,
                          ub.x+vb.x, ub.y+vb.y, ub.z+vb.z, ub.w+vb.w};
            #pragma unroll
            for (int i = 0; i < 8; ++i) h[i] = fmaxf(h[i], 0.01f*h[i]);
            unsigned bhp[4], blp[4];
            #pragma unroll
            for (int p = 0; p < 4; ++p)
                pack_hl(h[2*p], h[2*p+1], bhp[p], blp[p]);
            uint4v bhv = {bhp[0], bhp[1], bhp[2], bhp[3]};
            uint4v blv = {blp[0], blp[1], blp[2], blp[3]};
            bf16x8 bh = __builtin_bit_cast(bf16x8, bhv);
            bf16x8 bl = __builtin_bit_cast(bf16x8, blv);
            float acc = 0.f;
            #pragma unroll
            for (int oc = 0; oc < 4; ++oc) {
                f32x4 d = {B2f[mlp][oc].x, B2f[mlp][oc].y,
                           B2f[mlp][oc].z, B2f[mlp][oc].w};
                d = __builtin_amdgcn_mfma_f32_16x16x32_bf16(AHf[mlp][oc], bh, d, 0, 0, 0);
                d = __builtin_amdgcn_mfma_f32_16x16x32_bf16(ALf[mlp][oc], bh, d, 0, 0, 0);
                d = __builtin_amdgcn_mfma_f32_16x16x32_bf16(AHf[mlp][oc], bl, d, 0, 0, 0);
                float w3v[4] = {W3f[mlp][oc].x, W3f[mlp][oc].y,
                                W3f[mlp][oc].z, W3f[mlp][oc].w};
                #pragma unroll
                for (int r = 0; r < 4; ++r)
                    acc = fmaf(fmaxf(d[r], 0.01f*d[r]), w3v[r], acc);
            }
            if (mlp == 0) res0 = acc; else res1 = acc;
        }
        res0 += __shfl_xor(res0, 16); res0 += __shfl_xor(res0, 32);
        res1 += __shfl_xor(res1, 16); res1 += __shfl_xor(res1, 32);
        if (lane < 16) {
            W2h[(size_t)n*T2 + m]      = (short)f2bf(res0 + bias0);
            W2h[(size_t)n*T2 + NT + m] = (short)f2bf(res1 + bias1);
        }
    }
}

// ====================== phase bodies (verified numerics) ====================
__device__ void body_apply(int tgrp, int b,
    const float* __restrict__ xy, const float* __restrict__ g0,
    const float* __restrict__ b0, const float* __restrict__ lnpart,
    short* __restrict__ Vbh, short* __restrict__ Vbl,
    short* __restrict__ Vbth, short* __restrict__ Vbtl,
    float* __restrict__ spartV, SMem& S)
{
    float s = 0.f, q = 0.f;
    for (int i = 0; i < 25; ++i) {
        s += lnpart[((size_t)b*25 + i)*2 + 0];
        q += lnpart[((size_t)b*25 + i)*2 + 1];
    }
    float mu = s * (1.0f/409600.0f);
    float rs = rsqrtf(q * (1.0f/409600.0f) - mu*mu + EPS);
    float (*T)[132] = (float(*)[132])S.buf;
    int tid = threadIdx.x;
    int r = tid >> 2, qd = tid & 3;
    int f2 = tid >> 1, half = tid & 1;
    #pragma unroll
    for (int p = 0; p < 2; ++p) {
        int t0 = tgrp*128 + p*64;
        {
            int t = t0 + r;
            const float* xp = xy + ((size_t)b*T2 + t)*F + qd*32;
            const float* gp = g0 + (size_t)t*F + qd*32;
            const float* bp = b0 + (size_t)t*F + qd*32;
            unsigned ph[16], pl[16];
            #pragma unroll
            for (int i = 0; i < 32; i += 4) {
                float4 x = *(const float4*)&xp[i];
                float4 g = *(const float4*)&gp[i];
                float4 bb = *(const float4*)&bp[i];
                float o0 = (x.x - mu)*rs*g.x + bb.x;
                float o1 = (x.y - mu)*rs*g.y + bb.y;
                float o2 = (x.z - mu)*rs*g.z + bb.z;
                float o3 = (x.w - mu)*rs*g.w + bb.w;
                T[r][qd*32+i] = o0; T[r][qd*32+i+1] = o1;
                T[r][qd*32+i+2] = o2; T[r][qd*32+i+3] = o3;
                pack_hl(o0, o1, ph[i>>1], pl[i>>1]);
                pack_hl(o2, o3, ph[(i>>1)+1], pl[(i>>1)+1]);
            }
            size_t ob = ((size_t)b*T2 + t)*F + qd*32;
            store16u(&Vbh[ob], ph);
            store16u(&Vbl[ob], pl);
        }
        __syncthreads();
        {
            float sacc = 0.f;
            unsigned ph[16], pl[16];
            #pragma unroll
            for (int i = 0; i < 32; i += 2) {
                float v0 = T[half*32 + i][f2];
                float v1 = T[half*32 + i + 1][f2];
                sacc += v0 + v1;
                pack_hl(v0, v1, ph[i>>1], pl[i>>1]);
            }
            size_t ob = ((size_t)b*F + f2)*T2 + t0 + half*32;
            store16u(&Vbth[ob], ph);
            store16u(&Vbtl[ob], pl);
            spartV[((size_t)b*100 + (tgrp*2+p)*2 + half)*128 + f2] = sacc;
        }
        __syncthreads();
    }
}

__device__ void body_xyt(int tgrp, int b,
    const float* __restrict__ xy,
    short* __restrict__ xyTh, short* __restrict__ xyTl,
    float* __restrict__ s2part, SMem& S)
{
    float (*T)[132] = (float(*)[132])S.buf;
    int tid = threadIdx.x;
    int r = tid >> 2, qd = tid & 3;
    int f2 = tid >> 1, half = tid & 1;
    int t0 = tgrp*64;
    {
        const float* xp = xy + ((size_t)b*T2 + t0 + r)*F + qd*32;
        #pragma unroll
        for (int i = 0; i < 32; i += 4)
            *(float4*)&T[r][qd*32+i] = *(const float4*)&xp[i];
    }
    __syncthreads();
    {
        float sacc = 0.f;
        unsigned ph[16], pl[16];
        #pragma unroll
        for (int i = 0; i < 32; i += 2) {
            float v0 = T[half*32 + i][f2];
            float v1 = T[half*32 + i + 1][f2];
            sacc += v0 + v1;
            pack_hl(v0, v1, ph[i>>1], pl[i>>1]);
        }
        size_t ob = ((size_t)b*F + f2)*1600 + t0 + half*32;
        store16u(&xyTh[ob], ph);
        store16u(&xyTl[ob], pl);
        s2part[((size_t)b*50 + tgrp*2 + half)*128 + f2] = sacc;
    }
}

__device__ void body_gsym(int split, int b,
    const short* __restrict__ Xh, const short* __restrict__ Xl,
    float* __restrict__ Gpart, SMem& Smem)
{
    int t0 = split*128;
    GSymS& S = *(GSymS*)Smem.buf;
    int tid = threadIdx.x;
    int lane = tid & 63, wid = tid >> 6;
    int wr = wid >> 1, wc = wid & 1;
    int r16 = lane & 15, kg = lane >> 4;
    int sf = tid >> 1, th = tid & 1;

    const short* ph_ = Xh + ((size_t)b*F + sf)*T2 + t0 + th*16;
    const short* pl_ = Xl + ((size_t)b*F + sf)*T2 + t0 + th*16;

    f32x4 acc[4][4];
    #pragma unroll
    for (int i = 0; i < 4; ++i)
        #pragma unroll
        for (int j2 = 0; j2 < 4; ++j2)
            acc[i][j2] = (f32x4){0.f,0.f,0.f,0.f};

    {
        uint4v h0 = *(const uint4v*)ph_,      h1 = *(const uint4v*)(ph_ + 8);
        uint4v l0 = *(const uint4v*)pl_,      l1 = *(const uint4v*)(pl_ + 8);
        *(uint4v*)&S.Sh[0][sf][th*16]     = h0; *(uint4v*)&S.Sh[0][sf][th*16+8] = h1;
        *(uint4v*)&S.Sl[0][sf][th*16]     = l0; *(uint4v*)&S.Sl[0][sf][th*16+8] = l1;
    }
    #pragma unroll
    for (int ks = 0; ks < 4; ++ks) {
        int cur = ks & 1;
        uint4v h0, h1, l0, l1;
        if (ks < 3) {
            int ko = (ks+1)*32;
            h0 = *(const uint4v*)(ph_ + ko); h1 = *(const uint4v*)(ph_ + ko + 8);
            l0 = *(const uint4v*)(pl_ + ko); l1 = *(const uint4v*)(pl_ + ko + 8);
        }
        __syncthreads();
        bf16x8 ah[4], al[4], bh[4], bl[4];
        #pragma unroll
        for (int i = 0; i < 4; ++i) {
            ah[i] = *(const bf16x8*)&S.Sh[cur][wr*64 + i*16 + r16][kg*8];
            al[i] = *(const bf16x8*)&S.Sl[cur][wr*64 + i*16 + r16][kg*8];
            bh[i] = *(const bf16x8*)&S.Sh[cur][wc*64 + i*16 + r16][kg*8];
            bl[i] = *(const bf16x8*)&S.Sl[cur][wc*64 + i*16 + r16][kg*8];
        }
        #pragma unroll
        for (int i = 0; i < 4; ++i)
            #pragma unroll
            for (int j2 = 0; j2 < 4; ++j2) {
                acc[i][j2] = __builtin_amdgcn_mfma_f32_16x16x32_bf16(ah[i], bh[j2], acc[i][j2], 0,0,0);
                acc[i][j2] = __builtin_amdgcn_mfma_f32_16x16x32_bf16(al[i], bh[j2], acc[i][j2], 0,0,0);
                acc[i][j2] = __builtin_amdgcn_mfma_f32_16x16x32_bf16(ah[i], bl[j2], acc[i][j2], 0,0,0);
            }
        if (ks < 3) {
            int nb = cur ^ 1;
            *(uint4v*)&S.Sh[nb][sf][th*16]     = h0; *(uint4v*)&S.Sh[nb][sf][th*16+8] = h1;
            *(uint4v*)&S.Sl[nb][sf][th*16]     = l0; *(uint4v*)&S.Sl[nb][sf][th*16+8] = l1;
        }
    }
    __syncthreads();
    size_t gb = ((size_t)b*25 + split)*16384;
    #pragma unroll
    for (int i = 0; i < 4; ++i)
        #pragma unroll
        for (int j2 = 0; j2 < 4; ++j2)
            #pragma unroll
            for (int reg = 0; reg < 4; ++reg)
                Gpart[gb + (size_t)(wr*64 + i*16 + kg*4 + reg)*128 + wc*64 + j2*16 + r16]
                    = acc[i][j2][reg];
}

__device__ void body_gasym2(int split, int b, int nks,
    const short* __restrict__ Ah_, const short* __restrict__ Al_,
    const short* __restrict__ Bh_, const short* __restrict__ Bl_,
    float* __restrict__ Gpart, SMem& Smem)
{
    int t0 = split*128;
    GAs2S& S = *(GAs2S*)Smem.buf;
    int tid = threadIdx.x;
    int lane = tid & 63, wid = tid >> 6;
    int wr = wid >> 1, wc = wid & 1;
    int r16 = lane & 15, kg = lane >> 4;
    int sf = tid >> 1, th = tid & 1;

    const short* pah = Ah_ + ((size_t)b*F + sf)*1600 + t0 + th*16;
    const short* pal = Al_ + ((size_t)b*F + sf)*1600 + t0 + th*16;
    const short* pbh = Bh_ + ((size_t)b*F + sf)*T2   + t0 + th*16;
    const short* pbl = Bl_ + ((size_t)b*F + sf)*T2   + t0 + th*16;

    f32x4 acc[4][4];
    #pragma unroll
    for (int i = 0; i < 4; ++i)
        #pragma unroll
        for (int j2 = 0; j2 < 4; ++j2)
            acc[i][j2] = (f32x4){0.f,0.f,0.f,0.f};

    for (int ks = 0; ks < nks; ++ks) {
        int ko = ks*32;
        __syncthreads();
        *(uint4v*)&S.Ahs[sf][th*16]   = *(const uint4v*)(pah + ko);
        *(uint4v*)&S.Ahs[sf][th*16+8] = *(const uint4v*)(pah + ko + 8);
        *(uint4v*)&S.Als[sf][th*16]   = *(const uint4v*)(pal + ko);
        *(uint4v*)&S.Als[sf][th*16+8] = *(const uint4v*)(pal + ko + 8);
        *(uint4v*)&S.Bhs[sf][th*16]   = *(const uint4v*)(pbh + ko);
        *(uint4v*)&S.Bhs[sf][th*16+8] = *(const uint4v*)(pbh + ko + 8);
        *(uint4v*)&S.Bls[sf][th*16]   = *(const uint4v*)(pbl + ko);
        *(uint4v*)&S.Bls[sf][th*16+8] = *(const uint4v*)(pbl + ko + 8);
        __syncthreads();
        bf16x8 ah[4], al[4], bh[4], bl[4];
        #pragma unroll
        for (int i = 0; i < 4; ++i) {
            ah[i] = *(const bf16x8*)&S.Ahs[wr*64 + i*16 + r16][kg*8];
            al[i] = *(const bf16x8*)&S.Als[wr*64 + i*16 + r16][kg*8];
            bh[i] = *(const bf16x8*)&S.Bhs[wc*64 + i*16 + r16][kg*8];
            bl[i] = *(const bf16x8*)&S.Bls[wc*64 + i*16 + r16][kg*8];
        }
        #pragma unroll
        for (int i = 0; i < 4; ++i)
            #pragma unroll
            for (int j2 = 0; j2 < 4; ++j2) {
                acc[i][j2] = __builtin_amdgcn_mfma_f32_16x16x32_bf16(ah[i], bh[j2], acc[i][j2], 0,0,0);
                acc[i][j2] = __builtin_amdgcn_mfma_f32_16x16x32_bf16(al[i], bh[j2], acc[i][j2], 0,0,0);
                acc[i][j2] = __builtin_amdgcn_mfma_f32_16x16x32_bf16(ah[i], bl[j2], acc[i][j2], 0,0,0);
            }
    }
    __syncthreads();
    size_t gb = ((size_t)b*25 + split)*16384;
    #pragma unroll
    for (int i = 0; i < 4; ++i)
        #pragma unroll
        for (int j2 = 0; j2 < 4; ++j2)
            #pragma unroll
            for (int reg = 0; reg < 4; ++reg)
                Gpart[gb + (size_t)(wr*64 + i*16 + kg*4 + reg)*128 + wc*64 + j2*16 + r16]
                    = acc[i][j2][reg];
}

__device__ void body_gred(int job, int np2,
    const float* __restrict__ Gpart, const float* __restrict__ wj,
    short* __restrict__ Gbh, short* __restrict__ Gbl, float* __restrict__ rpart)
{
    int part = job % 8, b = job / 8;
    int tid = threadIdx.x;
    int e0 = part*2048 + tid*8;
    float a[8] = {0,0,0,0,0,0,0,0};
    for (int i = 0; i < np2; ++i) {
        const float* p = Gpart + ((size_t)b*25 + i)*16384 + e0;
        float4 x0 = *(const float4*)p;
        float4 x1 = *(const float4*)(p + 4);
        a[0] += x0.x; a[1] += x0.y; a[2] += x0.z; a[3] += x0.w;
        a[4] += x1.x; a[5] += x1.y; a[6] += x1.z; a[7] += x1.w;
    }
    unsigned ph[4], pl[4];
    #pragma unroll
    for (int i = 0; i < 8; i += 2) pack_hl(a[i], a[i+1], ph[i>>1], pl[i>>1]);
    uint4v vh = {ph[0],ph[1],ph[2],ph[3]};
    uint4v vl = {pl[0],pl[1],pl[2],pl[3]};
    *(uint4v*)&Gbh[(size_t)b*16384 + e0] = vh;
    *(uint4v*)&Gbl[(size_t)b*16384 + e0] = vl;

    int c0 = e0 & 127;
    float4 w0 = *(const float4*)&wj[c0];
    float4 w1 = *(const float4*)&wj[c0 + 4];
    float pr = a[0]*w0.x + a[1]*w0.y + a[2]*w0.z + a[3]*w0.w
             + a[4]*w1.x + a[5]*w1.y + a[6]*w1.z + a[7]*w1.w;
    pr += __shfl_xor(pr, 1); pr += __shfl_xor(pr, 2);
    pr += __shfl_xor(pr, 4); pr += __shfl_xor(pr, 8);
    if ((tid & 15) == 0) rpart[b*128 + (e0 >> 7)] = pr;
}

__device__ void body_computeM(int job,
    const short* __restrict__ Gbh, const short* __restrict__ Gbl,
    const float* __restrict__ spart, int np,
    const short* __restrict__ Pjh, const short* __restrict__ Pjl,
    const float* __restrict__ uj, const float* __restrict__ cj,
    const float* __restrict__ rpart,
    short* __restrict__ Mth, short* __restrict__ Mtl, float* __restrict__ rm,
    SMem& Smem)
{
    int kh = job % 2, b = job / 2;
    CMS& S = *(CMS*)Smem.buf;
    float (*T)[132] = (float(*)[132])Smem.buf;
    float* sv = Smem.sv;

    int tid = threadIdx.x;
    int lane = tid & 63, wid = tid >> 6;
    int wr = wid >> 1, wc = wid & 1;
    int r16 = lane & 15, kg = lane >> 4;
    int st = tid >> 2, sq = tid & 3;
    int sf = tid >> 1, sh2 = tid & 1;

    if (tid < 128) {
        float s = 0.f;
        for (int i = 0; i < np; ++i) s += spart[((size_t)b*np + i)*128 + tid];
        sv[tid] = s;
        if (kh == 0) rm[b*128 + tid] = SCALE*(rpart[b*128 + tid] + cj[0]*s);
    }

    const short* pah = Pjh + (size_t)(kh*64 + st)*128 + sq*8;
    const short* pal = Pjl + (size_t)(kh*64 + st)*128 + sq*8;
    const short* pbh = Gbh + ((size_t)b*F + sf)*128 + sh2*16;
    const short* pbl = Gbl + ((size_t)b*F + sf)*128 + sh2*16;

    f32x4 acc[2][4];
    #pragma unroll
    for (int i = 0; i < 2; ++i)
        #pragma unroll
        for (int j2 = 0; j2 < 4; ++j2)
            acc[i][j2] = (f32x4){0.f,0.f,0.f,0.f};

    {
        *(uint4v*)&S.Psh[0][st][sq*8]      = *(const uint4v*)pah;
        *(uint4v*)&S.Psl[0][st][sq*8]      = *(const uint4v*)pal;
        *(uint4v*)&S.Bsh[0][sf][sh2*16]    = *(const uint4v*)pbh;
        *(uint4v*)&S.Bsh[0][sf][sh2*16+8]  = *(const uint4v*)(pbh + 8);
        *(uint4v*)&S.Bsl[0][sf][sh2*16]    = *(const uint4v*)pbl;
        *(uint4v*)&S.Bsl[0][sf][sh2*16+8]  = *(const uint4v*)(pbl + 8);
    }
    #pragma unroll
    for (int ks = 0; ks < 4; ++ks) {
        int cur = ks & 1;
        uint4v a0, a1, b0, b1, b2, b3;
        if (ks < 3) {
            int ko = (ks+1)*32;
            a0 = *(const uint4v*)(pah + ko); a1 = *(const uint4v*)(pal + ko);
            b0 = *(const uint4v*)(pbh + ko); b1 = *(const uint4v*)(pbh + ko + 8);
            b2 = *(const uint4v*)(pbl + ko); b3 = *(const uint4v*)(pbl + ko + 8);
        }
        __syncthreads();
        bf16x8 ah[2], al[2], bh[4], bl[4];
        #pragma unroll
        for (int i = 0; i < 2; ++i) {
            ah[i] = *(const bf16x8*)&S.Psh[cur][wr*32 + i*16 + r16][kg*8];
            al[i] = *(const bf16x8*)&S.Psl[cur][wr*32 + i*16 + r16][kg*8];
        }
        #pragma unroll
        for (int j2 = 0; j2 < 4; ++j2) {
            bh[j2] = *(const bf16x8*)&S.Bsh[cur][wc*64 + j2*16 + r16][kg*8];
            bl[j2] = *(const bf16x8*)&S.Bsl[cur][wc*64 + j2*16 + r16][kg*8];
        }
        #pragma unroll
        for (int i = 0; i < 2; ++i)
            #pragma unroll
            for (int j2 = 0; j2 < 4; ++j2) {
                acc[i][j2] = __builtin_amdgcn_mfma_f32_16x16x32_bf16(ah[i], bh[j2], acc[i][j2], 0,0,0);
                acc[i][j2] = __builtin_amdgcn_mfma_f32_16x16x32_bf16(al[i], bh[j2], acc[i][j2], 0,0,0);
                acc[i][j2] = __builtin_amdgcn_mfma_f32_16x16x32_bf16(ah[i], bl[j2], acc[i][j2], 0,0,0);
            }
        if (ks < 3) {
            int nb = cur ^ 1;
            *(uint4v*)&S.Psh[nb][st][sq*8]     = a0;
            *(uint4v*)&S.Psl[nb][st][sq*8]     = a1;
            *(uint4v*)&S.Bsh[nb][sf][sh2*16]   = b0;
            *(uint4v*)&S.Bsh[nb][sf][sh2*16+8] = b1;
            *(uint4v*)&S.Bsl[nb][sf][sh2*16]   = b2;
            *(uint4v*)&S.Bsl[nb][sf][sh2*16+8] = b3;
        }
    }
    float uval[2][4], svv[4];
    #pragma unroll
    for (int i = 0; i < 2; ++i)
        #pragma unroll
        for (int reg = 0; reg < 4; ++reg)
            uval[i][reg] = uj[kh*64 + wr*32 + i*16 + kg*4 + reg];
    #pragma unroll
    for (int j2 = 0; j2 < 4; ++j2) svv[j2] = sv[wc*64 + j2*16 + r16];
    __syncthreads();
    #pragma unroll
    for (int i = 0; i < 2; ++i)
        #pragma unroll
        for (int j2 = 0; j2 < 4; ++j2)
            #pragma unroll
            for (int reg = 0; reg < 4; ++reg)
                T[wr*32 + i*16 + kg*4 + reg][wc*64 + j2*16 + r16]
                    = SCALE*(acc[i][j2][reg] + uval[i][reg]*svv[j2]);
    __syncthreads();
    {
        int f2 = tid >> 1, half = tid & 1;
        unsigned ph[16], pl[16];
        #pragma unroll
        for (int i = 0; i < 32; i += 2) {
            float v0 = T[half*32 + i][f2];
            float v1 = T[half*32 + i + 1][f2];
            pack_hl(v0, v1, ph[i>>1], pl[i>>1]);
        }
        size_t ob = ((size_t)b*F + f2)*F + kh*64 + half*32;
        store16u(&Mth[ob], ph);
        store16u(&Mtl[ob], pl);
    }
}

__device__ void body_mid(int tblk, int b,
    short* __restrict__ Vbh, short* __restrict__ Vbl,
    const short* __restrict__ Mth, const short* __restrict__ Mtl,
    const float* __restrict__ rm,
    const float* __restrict__ glj, const float* __restrict__ blj, int doLN,
    short* __restrict__ OTh, short* __restrict__ OTl,
    float* __restrict__ spartN, SMem& Smem)
{
    int t0 = tblk * 64;
    MidS& S = *(MidS*)Smem.buf;
    float (*T)[132] = (float(*)[132])Smem.buf;

    int tid = threadIdx.x;
    int lane = tid & 63, wid = tid >> 6;
    int wr = wid >> 1, wc = wid & 1;
    int r16 = lane & 15, kg = lane >> 4;
    int st = tid >> 2, sq = tid & 3;
    int sf = tid >> 1, sh2 = tid & 1;

    const short* pah = Vbh + ((size_t)b*T2 + t0 + st)*F + sq*8;
    const short* pal = Vbl + ((size_t)b*T2 + t0 + st)*F + sq*8;
    const short* pbh = Mth + ((size_t)b*F + sf)*F + sh2*16;
    const short* pbl = Mtl + ((size_t)b*F + sf)*F + sh2*16;

    f32x4 acc[2][4];
    #pragma unroll
    for (int i = 0; i < 2; ++i)
        #pragma unroll
        for (int j2 = 0; j2 < 4; ++j2)
            acc[i][j2] = (f32x4){0.f,0.f,0.f,0.f};

    {
        *(uint4v*)&S.Ash[0][st][sq*8]      = *(const uint4v*)pah;
        *(uint4v*)&S.Asl[0][st][sq*8]      = *(const uint4v*)pal;
        *(uint4v*)&S.Bsh[0][sf][sh2*16]    = *(const uint4v*)pbh;
        *(uint4v*)&S.Bsh[0][sf][sh2*16+8]  = *(const uint4v*)(pbh + 8);
        *(uint4v*)&S.Bsl[0][sf][sh2*16]    = *(const uint4v*)pbl;
        *(uint4v*)&S.Bsl[0][sf][sh2*16+8]  = *(const uint4v*)(pbl + 8);
    }
    #pragma unroll
    for (int ks = 0; ks < 4; ++ks) {
        int cur = ks & 1;
        uint4v a0, a1, b0, b1, b2, b3;
        if (ks < 3) {
            int ko = (ks+1)*32;
            a0 = *(const uint4v*)(pah + ko); a1 = *(const uint4v*)(pal + ko);
            b0 = *(const uint4v*)(pbh + ko); b1 = *(const uint4v*)(pbh + ko + 8);
            b2 = *(const uint4v*)(pbl + ko); b3 = *(const uint4v*)(pbl + ko + 8);
        }
        __syncthreads();
        bf16x8 ah[2], al[2], bh[4], bl[4];
        #pragma unroll
        for (int i = 0; i < 2; ++i) {
            ah[i] = *(const bf16x8*)&S.Ash[cur][wr*32 + i*16 + r16][kg*8];
            al[i] = *(const bf16x8*)&S.Asl[cur][wr*32 + i*16 + r16][kg*8];
        }
        #pragma unroll
        for (int j2 = 0; j2 < 4; ++j2) {
            bh[j2] = *(const bf16x8*)&S.Bsh[cur][wc*64 + j2*16 + r16][kg*8];
            bl[j2] = *(const bf16x8*)&S.Bsl[cur][wc*64 + j2*16 + r16][kg*8];
        }
        #pragma unroll
        for (int i = 0; i < 2; ++i)
            #pragma unroll
            for (int j2 = 0; j2 < 4; ++j2) {
                acc[i][j2] = __builtin_amdgcn_mfma_f32_16x16x32_bf16(ah[i], bh[j2], acc[i][j2], 0,0,0);
                acc[i][j2] = __builtin_amdgcn_mfma_f32_16x16x32_bf16(al[i], bh[j2], acc[i][j2], 0,0,0);
                acc[i][j2] = __builtin_amdgcn_mfma_f32_16x16x32_bf16(ah[i], bl[j2], acc[i][j2], 0,0,0);
            }
        if (ks < 3) {
            int nb = cur ^ 1;
            *(uint4v*)&S.Ash[nb][st][sq*8]     = a0;
            *(uint4v*)&S.Asl[nb][st][sq*8]     = a1;
            *(uint4v*)&S.Bsh[nb][sf][sh2*16]   = b0;
            *(uint4v*)&S.Bsh[nb][sf][sh2*16+8] = b1;
            *(uint4v*)&S.Bsl[nb][sf][sh2*16]   = b2;
            *(uint4v*)&S.Bsl[nb][sf][sh2*16+8] = b3;
        }
    }
    float rv[4];
    #pragma unroll
    for (int j2 = 0; j2 < 4; ++j2) rv[j2] = rm[b*F + wc*64 + j2*16 + r16];
    __syncthreads();
    #pragma unroll
    for (int i = 0; i < 2; ++i)
        #pragma unroll
        for (int j2 = 0; j2 < 4; ++j2)
            #pragma unroll
            for (int reg = 0; reg < 4; ++reg)
                T[wr*32 + i*16 + kg*4 + reg][wc*64 + j2*16 + r16]
                    = acc[i][j2][reg] + rv[j2];
    __syncthreads();

    if (doLN) {
        int r = tid >> 2, qd = tid & 3;
        float v[32];
        #pragma unroll
        for (int i = 0; i < 32; i += 4)
            *(float4*)&v[i] = *(const float4*)&T[r][qd*32 + i];
        float s = 0.f;
        #pragma unroll
        for (int i = 0; i < 32; ++i) s += v[i];
        s += __shfl_xor(s, 1); s += __shfl_xor(s, 2);
        float mu = s * (1.0f/128.0f);
        float dv = 0.f;
        #pragma unroll
        for (int i = 0; i < 32; ++i) { float d = v[i] - mu; dv = fmaf(d, d, dv); }
        dv += __shfl_xor(dv, 1); dv += __shfl_xor(dv, 2);
        float rs = rsqrtf(dv * (1.0f/128.0f) + EPS);

        short hb[32], lb[32];
        {
            const short* rh = Vbh + ((size_t)b*T2 + t0 + r)*F + qd*32;
            const short* rl = Vbl + ((size_t)b*T2 + t0 + r)*F + qd*32;
            #pragma unroll
            for (int i = 0; i < 32; i += 8) {
                *(uint4v*)&hb[i] = *(const uint4v*)(rh + i);
                *(uint4v*)&lb[i] = *(const uint4v*)(rl + i);
            }
        }
        float gv[32], bv2[32];
        #pragma unroll
        for (int i = 0; i < 32; i += 4) {
            *(float4*)&gv[i]  = *(const float4*)&glj[qd*32 + i];
            *(float4*)&bv2[i] = *(const float4*)&blj[qd*32 + i];
        }
        unsigned ph[16], pl[16];
        #pragma unroll
        for (int i = 0; i < 32; i += 2) {
            float res0 = bf2f((unsigned short)hb[i])   + bf2f((unsigned short)lb[i]);
            float res1 = bf2f((unsigned short)hb[i+1]) + bf2f((unsigned short)lb[i+1]);
            float o0 = (v[i]   - mu)*rs*gv[i]   + bv2[i]   + res0;
            float o1 = (v[i+1] - mu)*rs*gv[i+1] + bv2[i+1] + res1;
            T[r][qd*32+i] = o0; T[r][qd*32+i+1] = o1;
            pack_hl(o0, o1, ph[i>>1], pl[i>>1]);
        }
        size_t ob = ((size_t)b*T2 + t0 + r)*F + qd*32;
        store16u(&Vbh[ob], ph);
        store16u(&Vbl[ob], pl);
        __syncthreads();
    }
    {
        int f2 = tid >> 1, half = tid & 1;
        float sacc = 0.f;
        unsigned ph[16], pl[16];
        #pragma unroll
        for (int i = 0; i < 32; i += 2) {
            float v0 = T[half*32 + i][f2];
            float v1 = T[half*32 + i + 1][f2];
            sacc += v0 + v1;
            pack_hl(v0, v1, ph[i>>1], pl[i>>1]);
        }
        size_t ob = ((size_t)b*F + f2)*T2 + t0 + half*32;
        store16u(&OTh[ob], ph);
        store16u(&OTl[ob], pl);
        if (doLN)
            spartN[((size_t)b*100 + tblk*2 + half)*128 + f2] = sacc;
    }
}

// =================== merged kernels (real work + MLP helpers) ==============
__global__ __launch_bounds__(256, 2) void k_apply_gsym(
    const float* xy, const float* g0, const float* b0, const float* lnpart,
    short* Vbh, short* Vbl, short* Vbth, short* Vbtl,
    short* xyTh, short* xyTl, float* spartV, float* s2part, float* Gpart,
    int tile0,
    const float* uv, const float* kb2, const float* kW3, const float* kb3,
    const float* fb2, const float* fW3, const float* fb3,
    const short* AhF, const short* AlF, short* W2h)
{
    __shared__ SMem S;
    int jb = blockIdx.x;
    if (jb >= 400) {
        body_mlp(tile0 + (jb - 400)*20, uv, kb2, kW3, kb3, fb2, fW3, fb3,
                 AhF, AlF, W2h);
        return;
    }
    if (jb < 200) {
        int tgrp = jb % 25, b = jb / 25;
        body_apply(tgrp, b, xy, g0, b0, lnpart, Vbh, Vbl, Vbth, Vbtl, spartV, S);
        __syncthreads();
        body_gsym(tgrp, b, Vbth, Vbtl, Gpart, S);
    } else {
        int t = jb - 200;
        body_xyt(t % 25, t / 25, xy, xyTh, xyTl, s2part, S);
    }
}

__global__ __launch_bounds__(256, 2) void k_gred_m(
    const float* Gpart, int np2, const float* wj,
    short* Gbh, short* Gbl, float* rpart,
    int tile0,
    const float* uv, const float* kb2, const float* kW3, const float* kb3,
    const float* fb2, const float* fW3, const float* fb3,
    const short* AhF, const short* AlF, short* W2h)
{
    int bid = blockIdx.x;
    if (bid >= 64) {
        body_mlp(tile0 + (bid - 64)*20, uv, kb2, kW3, kb3, fb2, fW3, fb3,
                 AhF, AlF, W2h);
        return;
    }
    body_gred(bid, np2, Gpart, wj, Gbh, Gbl, rpart);
}

__global__ __launch_bounds__(256, 2) void k_cm_m(
    const short* Gbh, const short* Gbl, const float* spart, int np,
    const short* Pjh, const short* Pjl, const float* uj, const float* cj,
    const float* rpart, short* Mth, short* Mtl, float* rm,
    int tile0,
    const float* uv, const float* kb2, const float* kW3, const float* kb3,
    const float* fb2, const float* fW3, const float* fb3,
    const short* AhF, const short* AlF, short* W2h)
{
    __shared__ SMem S;
    int bid = blockIdx.x;
    if (bid >= 16) {
        body_mlp(tile0 + (bid - 16)*20, uv, kb2, kW3, kb3, fb2, fW3, fb3,
                 AhF, AlF, W2h);
        return;
    }
    body_computeM(bid, Gbh, Gbl, spart, np, Pjh, Pjl, uj, cj, rpart,
                  Mth, Mtl, rm, S);
}

// mode: 0 = gsym after mid, 1 = gasym (j==2->3), 2 = none (final mid)
__global__ __launch_bounds__(256, 2) void k_mid_gsym(
    short* Vbh, short* Vbl, const short* Mth, const short* Mtl,
    const float* rm, const float* glj, const float* blj, int doLN,
    short* OTh, short* OTl, float* spartN,
    int mode, const short* xyTh, const short* xyTl, float* Gpart,
    int tile0,
    const float* uv, const float* kb2, const float* kW3, const float* kb3,
    const float* fb2, const float* fW3, const float* fb3,
    const short* AhF, const short* AlF, short* W2h)
{
    __shared__ SMem S;
    int bid = blockIdx.x;
    if (bid >= 200) {
        body_mlp(tile0 + (bid - 200)*20, uv, kb2, kW3, kb3, fb2, fW3, fb3,
                 AhF, AlF, W2h);
        return;
    }
    int s = bid % 25, b = bid / 25;
    #pragma unroll
    for (int pass = 0; pass < 2; ++pass) {
        body_mid(s*2 + pass, b, Vbh, Vbl, Mth, Mtl, rm, glj, blj, doLN,
                 OTh, OTl, spartN, S);
        __syncthreads();
    }
    if (mode == 0) {
        body_gsym(s, b, OTh, OTl, Gpart, S);
    } else if (mode == 1) {
        int nks = (s < 12) ? 4 : ((s == 12) ? 2 : 0);
        if (nks) body_gasym2(s, b, nks, xyTh, xyTl, OTh, OTl, Gpart, S);
    }
}

// ------------- out = DXDY * W2(bf16) @ U(bf16 h/l), MFMA -------------------
__global__ __launch_bounds__(256) void k_gout(
    const short* __restrict__ W2h,
    const short* __restrict__ Uth, const short* __restrict__ Utl,
    float* __restrict__ out)
{
    int job = blockIdx.x;
    int nt = job % 25, b = job / 25;
    int n0 = nt * 64;
    __shared__ GOutS S;

    int tid = threadIdx.x;
    int lane = tid & 63, wid = tid >> 6;
    int wr = wid >> 1, wc = wid & 1;
    int r16 = lane & 15, kg = lane >> 4;
    int srow = tid >> 2, sq2 = tid & 3;
    int sf = tid >> 1, sh2 = tid & 1;

    const short* ap  = W2h + (size_t)(n0 + srow)*T2 + sq2*8;
    const short* bhp = Uth + ((size_t)b*F + sf)*T2 + sh2*16;
    const short* blp = Utl + ((size_t)b*F + sf)*T2 + sh2*16;

    f32x4 acc[2][4];
    #pragma unroll
    for (int i = 0; i < 2; ++i)
        #pragma unroll
        for (int j2 = 0; j2 < 4; ++j2)
            acc[i][j2] = (f32x4){0.f,0.f,0.f,0.f};

    {
        *(uint4v*)&S.As[0][srow][sq2*8]  = *(const uint4v*)ap;
        *(uint4v*)&S.Bh[0][sf][sh2*16]   = *(const uint4v*)bhp;
        *(uint4v*)&S.Bh[0][sf][sh2*16+8] = *(const uint4v*)(bhp + 8);
        *(uint4v*)&S.Bl[0][sf][sh2*16]   = *(const uint4v*)blp;
        *(uint4v*)&S.Bl[0][sf][sh2*16+8] = *(const uint4v*)(blp + 8);
    }
    for (int it = 0; it < 100; ++it) {
        int cur = it & 1;
        uint4v ra, b0, b1, b2, b3;
        if (it < 99) {
            int ko = (it + 1) * 32;
            ra = *(const uint4v*)(ap + ko);
            b0 = *(const uint4v*)(bhp + ko); b1 = *(const uint4v*)(bhp + ko + 8);
            b2 = *(const uint4v*)(blp + ko); b3 = *(const uint4v*)(blp + ko + 8);
        }
        __syncthreads();
        bf16x8 ah[2], bh[4], bl[4];
        #pragma unroll
        for (int i = 0; i < 2; ++i)
            ah[i] = *(const bf16x8*)&S.As[cur][wr*32 + i*16 + r16][kg*8];
        #pragma unroll
        for (int j2 = 0; j2 < 4; ++j2) {
            bh[j2] = *(const bf16x8*)&S.Bh[cur][wc*64 + j2*16 + r16][kg*8];
            bl[j2] = *(const bf16x8*)&S.Bl[cur][wc*64 + j2*16 + r16][kg*8];
        }
        #pragma unroll
        for (int i = 0; i < 2; ++i)
            #pragma unroll
            for (int j2 = 0; j2 < 4; ++j2) {
                acc[i][j2] = __builtin_amdgcn_mfma_f32_16x16x32_bf16(ah[i], bh[j2], acc[i][j2], 0,0,0);
                acc[i][j2] = __builtin_amdgcn_mfma_f32_16x16x32_bf16(ah[i], bl[j2], acc[i][j2], 0,0,0);
            }
        if (it < 99) {
            int nb = cur ^ 1;
            *(uint4v*)&S.As[nb][srow][sq2*8]  = ra;
            *(uint4v*)&S.Bh[nb][sf][sh2*16]   = b0;
            *(uint4v*)&S.Bh[nb][sf][sh2*16+8] = b1;
            *(uint4v*)&S.Bl[nb][sf][sh2*16]   = b2;
            *(uint4v*)&S.Bl[nb][sf][sh2*16+8] = b3;
        }
    }
    #pragma unroll
    for (int i = 0; i < 2; ++i)
        #pragma unroll
        for (int j2 = 0; j2 < 4; ++j2)
            #pragma unroll
            for (int reg = 0; reg < 4; ++reg) {
                int n_out = n0 + wr*32 + i*16 + kg*4 + reg;
                int f_out = wc*64 + j2*16 + r16;
                out[((size_t)b*NT + n_out)*F + f_out] = DXDY * acc[i][j2][reg];
            }
}

// =============================== launcher ==================================
extern "C" void kernel_launch(void* const* d_in, const int* in_sizes, int n_in,
                              void* d_out, int out_size, void* d_ws, size_t ws_size,
                              hipStream_t stream)
{
    const float* xy  = (const float*)d_in[0];
    const float* kW1 = (const float*)d_in[1];
    const float* kb1 = (const float*)d_in[2];
    const float* kW2 = (const float*)d_in[3];
    const float* kb2 = (const float*)d_in[4];
    const float* kW3 = (const float*)d_in[5];
    const float* kb3 = (const float*)d_in[6];
    const float* fW1 = (const float*)d_in[7];
    const float* fb1 = (const float*)d_in[8];
    const float* fW2 = (const float*)d_in[9];
    const float* fb2 = (const float*)d_in[10];
    const float* fW3 = (const float*)d_in[11];
    const float* fb3 = (const float*)d_in[12];
    const float* Wq  = (const float*)d_in[13];
    const float* bq  = (const float*)d_in[14];
    const float* Wk  = (const float*)d_in[15];
    const float* bk  = (const float*)d_in[16];
    const float* g0  = (const float*)d_in[17];
    const float* b0  = (const float*)d_in[18];
    const float* gl  = (const float*)d_in[19];
    const float* bl  = (const float*)d_in[20];
    float* out = (float*)d_out;

    short* W2h  = (short*)d_ws;                 // 5,120,000
    short* Vbh  = W2h  + 5120000;               // 3,276,800
    short* Vbl  = Vbh  + 3276800;
    short* Vbth = Vbl  + 3276800;
    short* Vbtl = Vbth + 3276800;
    short* xyTh = Vbtl + 3276800;               // 1,638,400
    short* xyTl = xyTh + 1638400;
    short* Uth  = xyTl + 1638400;               // 3,276,800
    short* Utl  = Uth  + 3276800;
    short* Pnh  = Utl  + 3276800;               // 65,536
    short* Pnl  = Pnh  + 65536;
    short* Mth  = Pnl  + 65536;                 // 131,072
    short* Mtl  = Mth  + 131072;
    short* Gbh  = Mtl  + 131072;                // 131,072
    short* Gbl  = Gbh  + 131072;
    short* AhF  = Gbl  + 131072;                // 4,096
    short* AlF  = AhF  + 4096;
    float* Gpart  = (float*)(AlF + 4096);       // 3,276,800 f
    float* uB     = Gpart + 3276800;            // 512
    float* wB     = uB + 512;                   // 512
    float* cB     = wB + 512;                   // 4
    float* lnpart = cB + 4;                     // 400
    float* rpart  = lnpart + 400;               // 1024
    float* rm     = rpart + 1024;               // 1024
    float* spartV = rm + 1024;                  // 102,400
    float* s2part = spartV + 102400;            // 51,200
    float* uvT    = s2part + 51200;             // 204,800

    k_prep<<<dim3(661), 256, 0, stream>>>(kW2, fW2, AhF, AlF,
                                          kW1, kb1, fW1, fb1, uvT,
                                          xy, lnpart,
                                          Wq, bq, Wk, bk, Pnh, Pnl, uB, wB, cB);

    // MLP tile budget: apply 800 blocks (16,000 tiles);
    // per layer: gred 400 (8,000), cm 400 (8,000), mid 1000 (20,000)
    k_apply_gsym<<<dim3(1200), 256, 0, stream>>>(
        xy, g0, b0, lnpart, Vbh, Vbl, Vbth, Vbtl,
        xyTh, xyTl, spartV, s2part, Gpart,
        /*tile0=*/0,
        uvT, kb2, kW3, kb3, fb2, fW3, fb3, AhF, AlF, W2h);

    for (int j = 0; j < 4; ++j) {
        int np2  = (j < 3) ? 25 : 13;
        int np_s = (j < 3) ? 100 : 50;
        const float* sp = (j < 3) ? spartV : s2part;
        int base = 16000 + j*36000;

        k_gred_m<<<dim3(464), 256, 0, stream>>>(
            Gpart, np2, wB + j*128, Gbh, Gbl, rpart,
            base,
            uvT, kb2, kW3, kb3, fb2, fW3, fb3, AhF, AlF, W2h);

        k_cm_m<<<dim3(416), 256, 0, stream>>>(
            Gbh, Gbl, sp, np_s,
            Pnh + (size_t)j*16384, Pnl + (size_t)j*16384,
            uB + j*128, cB + j, rpart, Mth, Mtl, rm,
            base + 8000,
            uvT, kb2, kW3, kb3, fb2, fW3, fb3, AhF, AlF, W2h);

        if (j < 2) {
            k_mid_gsym<<<dim3(1200), 256, 0, stream>>>(
                Vbh, Vbl, Mth, Mtl, rm, gl + j*128, bl + j*128, 1,
                Vbth, Vbtl, spartV, 0, xyTh, xyTl, Gpart,
                base + 16000,
                uvT, kb2, kW3, kb3, fb2, fW3, fb3, AhF, AlF, W2h);
        } else if (j == 2) {
            k_mid_gsym<<<dim3(1200), 256, 0, stream>>>(
                Vbh, Vbl, Mth, Mtl, rm, gl + j*128, bl + j*128, 1,
                Vbth, Vbtl, spartV, 1, xyTh, xyTl, Gpart,
                base + 16000,
                uvT, kb2, kW3, kb3, fb2, fW3, fb3, AhF, AlF, W2h);
        } else {
            k_mid_gsym<<<dim3(1200), 256, 0, stream>>>(
                Vbh, Vbl, Mth, Mtl, rm, gl, bl, 0,
                Uth, Utl, spartV, 2, xyTh, xyTl, Gpart,
                base + 16000,
                uvT, kb2, kW3, kb3, fb2, fW3, fb3, AhF, AlF, W2h);
        }
    }

    k_gout<<<dim3(200), 256, 0, stream>>>(W2h, Uth, Utl, out);
}